// Round 4
// baseline (46461.301 us; speedup 1.0000x reference)
//
#include <hip/hip_runtime.h>
#include <hip/hip_fp16.h>
#include <cstdint>
#include <cstddef>

#define B_  256
#define S_  96
#define T_  40
#define V_  256
#define E_  512
#define H_  1024
#define C_  128
#define G3H 3072   // 3*H

__device__ __forceinline__ float sigmoidf_(float x) { return 1.0f / (1.0f + expf(-x)); }

// ---------------- generic tiled GEMM: C[m,n] = act(sum_k a(m,k)*W[n,k] + bias[n])
// AMODE: 0 = A[m*lda+k]
//        1 = A[gidx[m*S_+gt]*lda + k]              (embedding gather)
//        2 = cond concat [h_f | h_b | mode | tense | person]   (K=2432)
//        3 = k-permuted view of predin [h2|ctx|emb]: k<512 -> emb, else ctx
// CMODE: 0 = f32 store (optional tanh)
//        1 = fp16 store
//        2 = GRU-gh split: n<2H -> C[m*ldc+n] += v ; else C2[m*H_+n-2H] = v
struct GA {
  const float* A; int lda;
  const float* W; int ldw;
  const float* bias;
  float* C; int ldc;
  __half* Ch;
  float* C2;
  const int* gidx; int gt;
  const float *hf, *hb, *mE, *tE, *pE;
  const int *mi, *ti, *pi;
};

template<int AMODE, int CMODE>
__global__ __launch_bounds__(256)
void gemm_k(GA a0, GA a1, int M, int N, int K, int act)
{
  GA g = (blockIdx.z == 0) ? a0 : a1;
  __shared__ float As[16][65];
  __shared__ float Ws[16][65];
  __shared__ int rows[64];
  const int tid = threadIdx.x;
  const int tx = tid & 15, ty = tid >> 4;
  const int m0 = blockIdx.y * 64, n0 = blockIdx.x * 64;
  if (AMODE == 1) {
    if (tid < 64) rows[tid] = g.gidx[(size_t)(m0 + tid) * S_ + g.gt];
    __syncthreads();
  }
  float acc[4][4] = {};
  for (int k0 = 0; k0 < K; k0 += 16) {
#pragma unroll
    for (int i = 0; i < 4; ++i) {
      int idx = tid + i * 256;          // 0..1023
      int m = idx >> 4, kk = (idx & 15) + k0;
      int mg = m0 + m;
      float av;
      if (AMODE == 0) {
        av = g.A[(size_t)mg * g.lda + kk];
      } else if (AMODE == 1) {
        av = g.A[(size_t)rows[m] * g.lda + kk];
      } else if (AMODE == 2) {
        if (kk < 1024)      av = g.hf[(size_t)mg * H_ + kk];
        else if (kk < 2048) av = g.hb[(size_t)mg * H_ + kk - 1024];
        else if (kk < 2176) av = g.mE[(size_t)g.mi[mg] * C_ + kk - 2048];
        else if (kk < 2304) av = g.tE[(size_t)g.ti[mg] * C_ + kk - 2176];
        else                av = g.pE[(size_t)g.pi[mg] * C_ + kk - 2304];
      } else {   // AMODE 3: predin [h2(1024)|ctx(2048)|emb(512)] -> rnn_in [emb|ctx]
        int off = (kk < 512) ? (3072 + kk) : (512 + kk);
        av = g.A[(size_t)mg * 3584 + off];
      }
      As[kk - k0][m] = av;
    }
#pragma unroll
    for (int i = 0; i < 4; ++i) {
      int idx = tid + i * 256;
      int n = idx >> 4, kk = idx & 15;
      Ws[kk][n] = g.W[(size_t)(n0 + n) * g.ldw + k0 + kk];
    }
    __syncthreads();
#pragma unroll
    for (int k = 0; k < 16; ++k) {
      float a[4], b[4];
#pragma unroll
      for (int i = 0; i < 4; ++i) a[i] = As[k][ty * 4 + i];
#pragma unroll
      for (int j = 0; j < 4; ++j) b[j] = Ws[k][tx * 4 + j];
#pragma unroll
      for (int i = 0; i < 4; ++i)
#pragma unroll
        for (int j = 0; j < 4; ++j)
          acc[i][j] += a[i] * b[j];
    }
    __syncthreads();
  }
#pragma unroll
  for (int i = 0; i < 4; ++i) {
    int m = m0 + ty * 4 + i;
#pragma unroll
    for (int j = 0; j < 4; ++j) {
      int n = n0 + tx * 4 + j;
      float v = acc[i][j];
      if (g.bias) v += g.bias[n];
      if (CMODE == 0) {
        if (act == 1) v = tanhf(v);
        g.C[(size_t)m * g.ldc + n] = v;
      } else if (CMODE == 1) {
        g.Ch[(size_t)m * g.ldc + n] = __float2half(v);
      } else {   // CMODE 2
        if (n < 2 * H_) g.C[(size_t)m * g.ldc + n] += v;      // r,z pre-sum into gi
        else            g.C2[(size_t)m * H_ + n - 2 * H_] = v; // h_n separate
      }
    }
  }
}

// ---------------- small utility kernels ----------------
__global__ void sentinel_k(float* out, float v) { out[threadIdx.x] = v; }

__global__ void zero_k(float* __restrict__ p, int n)
{
  int i = blockIdx.x * 256 + threadIdx.x;
  if (i < n) p[i] = 0.0f;
}

__global__ void tok_init_k(const int* __restrict__ tgt, int* __restrict__ tok)
{
  int b = threadIdx.x;
  if (b < B_) tok[b] = tgt[(size_t)b * T_];
}

// gi holds [r_pre | z_pre | i_n], ghn holds h_n
__global__ __launch_bounds__(256)
void enc_gate_k(const float* __restrict__ gi_f, const float* __restrict__ ghn_f,
                const float* __restrict__ gi_b, const float* __restrict__ ghn_b,
                float* __restrict__ h_f, float* __restrict__ h_b,
                float* __restrict__ enc_out, int t)
{
  int idx = blockIdx.x * 256 + threadIdx.x;      // over 2*B*H
  int dir = idx / (B_ * H_);
  int r_ = idx % (B_ * H_);
  int b = r_ / H_, k = r_ % H_;
  const float* gi = dir ? gi_b : gi_f;
  const float* ghn = dir ? ghn_b : ghn_f;
  float* h = dir ? h_b : h_f;
  size_t gb = (size_t)b * G3H;
  float rr = sigmoidf_(gi[gb + k]);
  float zz = sigmoidf_(gi[gb + H_ + k]);
  float nn = tanhf(gi[gb + 2 * H_ + k] + rr * ghn[(size_t)b * H_ + k]);
  float hold = h[r_];
  float hnew = (1.0f - zz) * nn + zz * hold;
  h[r_] = hnew;
  int s = dir ? (S_ - 1 - t) : t;
  enc_out[((size_t)b * S_ + s) * (2 * H_) + dir * H_ + k] = hnew;
}

__global__ __launch_bounds__(256)
void attn_score_k(const float* __restrict__ q, const __half* __restrict__ proj,
                  const float* __restrict__ va, const int* __restrict__ src,
                  float* __restrict__ scores)
{
  int s = blockIdx.x, b = blockIdx.y, tid = threadIdx.x;
  const __half* p = proj + ((size_t)b * S_ + s) * H_;
  const float* qb = q + (size_t)b * H_;
  float part = 0.0f;
  for (int h = tid; h < H_; h += 256)
    part += va[h] * tanhf(qb[h] + __half2float(p[h]));
  for (int off = 32; off > 0; off >>= 1) part += __shfl_down(part, off);
  __shared__ float wsum[4];
  if ((tid & 63) == 0) wsum[tid >> 6] = part;
  __syncthreads();
  if (tid == 0) {
    float tot = wsum[0] + wsum[1] + wsum[2] + wsum[3];
    scores[b * S_ + s] = (src[b * S_ + s] == 0) ? -1.0e9f : tot;
  }
}

__global__ __launch_bounds__(128)
void softmax_k(const float* __restrict__ scores, float* __restrict__ w)
{
  int b = blockIdx.x, tid = threadIdx.x;
  __shared__ float sm[128];
  float v = (tid < S_) ? scores[b * S_ + tid] : -3.0e38f;
  sm[tid] = v; __syncthreads();
  for (int s = 64; s > 0; s >>= 1) { if (tid < s) sm[tid] = fmaxf(sm[tid], sm[tid + s]); __syncthreads(); }
  float mx = sm[0]; __syncthreads();
  float e = (tid < S_) ? expf(v - mx) : 0.0f;
  sm[tid] = e; __syncthreads();
  for (int s = 64; s > 0; s >>= 1) { if (tid < s) sm[tid] += sm[tid + s]; __syncthreads(); }
  if (tid < S_) w[b * S_ + tid] = e / sm[0];
}

__global__ __launch_bounds__(256)
void ctx_k(const float* __restrict__ w, const float* __restrict__ enc_out,
           float* __restrict__ predin)
{
  int d = blockIdx.x * 256 + threadIdx.x;   // 0..2047
  int b = blockIdx.y;
  const float* eb = enc_out + (size_t)b * S_ * (2 * H_);
  float acc = 0.0f;
  for (int s = 0; s < S_; ++s)
    acc += w[b * S_ + s] * eb[(size_t)s * (2 * H_) + d];
  predin[(size_t)b * 3584 + H_ + d] = acc;
}

__global__ void emb_k(const int* __restrict__ tok, const float* __restrict__ dec_emb,
                      float* __restrict__ predin)
{
  int b = blockIdx.x, tid = threadIdx.x;
  int tk = tok[b];
  for (int e = tid; e < E_; e += 256)
    predin[(size_t)b * 3584 + 3 * H_ + e] = dec_emb[(size_t)tk * E_ + e];
}

__global__ __launch_bounds__(256)
void dec_gate_k(const float* __restrict__ gi, const float* __restrict__ ghn,
                float* __restrict__ h, float* __restrict__ predin)
{
  int idx = blockIdx.x * 256 + threadIdx.x;   // over B*H
  int b = idx / H_, k = idx % H_;
  size_t gb = (size_t)b * G3H;
  float rr = sigmoidf_(gi[gb + k]);
  float zz = sigmoidf_(gi[gb + H_ + k]);
  float nn = tanhf(gi[gb + 2 * H_ + k] + rr * ghn[(size_t)b * H_ + k]);
  float hold = h[idx];
  float hnew = (1.0f - zz) * nn + zz * hold;
  h[idx] = hnew;
  predin[(size_t)b * 3584 + k] = hnew;
}

// argmax over V=256 logits (read from out slice written by pred GEMM)
__global__ __launch_bounds__(256)
void argmax_k(const float* __restrict__ pred, int* __restrict__ tok)
{
  int b = blockIdx.x, tid = threadIdx.x;
  float v = pred[(size_t)b * ((T_ - 1) * V_) + tid];
  __shared__ float sv[256];
  __shared__ int   si[256];
  sv[tid] = v;
  si[tid] = tid;
  __syncthreads();
  for (int s = 128; s > 0; s >>= 1) {
    if (tid < s) {
      if (sv[tid + s] > sv[tid]) { sv[tid] = sv[tid + s]; si[tid] = si[tid + s]; }
    }
    __syncthreads();
  }
  if (tid == 0) tok[b] = si[0];
}

// ---------------- host orchestration ----------------
template<int AMODE, int CMODE>
static inline void launch_gemm(const GA& a0, const GA& a1, int nz, int M, int N, int K,
                               int act, hipStream_t stream)
{
  dim3 grid(N / 64, M / 64, nz), block(256);
  hipLaunchKernelGGL((gemm_k<AMODE, CMODE>), grid, block, 0, stream, a0, a1, M, N, K, act);
}

extern "C" void kernel_launch(void* const* d_in, const int* in_sizes, int n_in,
                              void* d_out, int out_size, void* d_ws, size_t ws_size,
                              hipStream_t stream)
{
  const int*   src        = (const int*)d_in[0];
  const int*   tgt        = (const int*)d_in[1];
  const int*   mode_idx   = (const int*)d_in[2];
  const int*   tense_idx  = (const int*)d_in[3];
  const int*   person_idx = (const int*)d_in[4];
  const float* enc_emb    = (const float*)d_in[5];
  const float* eWih_f     = (const float*)d_in[6];
  const float* eWhh_f     = (const float*)d_in[7];
  const float* ebih_f     = (const float*)d_in[8];
  const float* ebhh_f     = (const float*)d_in[9];
  const float* eWih_b     = (const float*)d_in[10];
  const float* eWhh_b     = (const float*)d_in[11];
  const float* ebih_b     = (const float*)d_in[12];
  const float* ebhh_b     = (const float*)d_in[13];
  const float* Wa         = (const float*)d_in[14];
  const float* va         = (const float*)d_in[15];
  const float* dec_emb    = (const float*)d_in[16];
  const float* dWih       = (const float*)d_in[17];
  const float* dWhh       = (const float*)d_in[18];
  const float* dbih       = (const float*)d_in[19];
  const float* dbhh       = (const float*)d_in[20];
  const float* Wfc        = (const float*)d_in[21];
  const float* bfc        = (const float*)d_in[22];
  const float* mode_E     = (const float*)d_in[23];
  const float* tense_E    = (const float*)d_in[24];
  const float* person_E   = (const float*)d_in[25];
  const float* Wbr        = (const float*)d_in[26];
  const float* bbr        = (const float*)d_in[27];
  float* out = (float*)d_out;

  // ---- workspace carve: f32 everywhere except proj (fp16). ~255.7 MiB ----
  char* base = (char*)d_ws;
  size_t off = 0;
  auto alloc = [&](size_t bytes) { char* r = base + off; off = (off + bytes + 255) & ~(size_t)255; return r; };
  float*  enc_out = (float*)alloc(4ull * B_ * S_ * 2 * H_);   // 201.3 MB
  __half* proj    = (__half*)alloc(2ull * B_ * S_ * H_);      // 50.3 MB
  float* h_fb   = (float*)alloc(4ull * 2 * B_ * H_);          // h_f|h_b contiguous
  float* h_f    = h_fb;
  float* h_b    = h_fb + (size_t)B_ * H_;
  float* h_d    = (float*)alloc(4ull * B_ * H_);
  float* gi_f   = (float*)alloc(4ull * B_ * G3H);
  float* gi_b   = (float*)alloc(4ull * B_ * G3H);
  float* ghn_f  = (float*)alloc(4ull * B_ * H_);
  float* ghn_b  = (float*)alloc(4ull * B_ * H_);
  float* q      = (float*)alloc(4ull * B_ * H_);
  float* scores = (float*)alloc(4ull * B_ * S_);
  float* wts    = (float*)alloc(4ull * B_ * S_);
  float* predin = (float*)alloc(4ull * B_ * 3584);            // [h2|ctx|emb]
  int*   tok    = (int*)alloc(4ull * B_);
  if (off > ws_size) {   // encode ws_size in the failure signature
    float v = 1000.0f + (float)(ws_size >> 20);
    hipLaunchKernelGGL(sentinel_k, dim3(1), dim3(256), 0, stream, out, v);
    return;
  }

  GA Z{};   // zero-init template

  // ---- setup ----
  hipLaunchKernelGGL(zero_k, dim3((2 * B_ * H_) / 256), dim3(256), 0, stream, h_fb, 2 * B_ * H_);
  hipLaunchKernelGGL(tok_init_k, dim3(1), dim3(256), 0, stream, tgt, tok);

  // ---- bidirectional encoder: 96 sequential steps ----
  for (int t = 0; t < S_; ++t) {
    GA gi0 = Z; gi0.A = enc_emb; gi0.lda = E_; gi0.W = eWih_f; gi0.ldw = E_;
    gi0.bias = ebih_f; gi0.C = gi_f; gi0.ldc = G3H; gi0.gidx = src; gi0.gt = t;
    GA gi1 = Z; gi1.A = enc_emb; gi1.lda = E_; gi1.W = eWih_b; gi1.ldw = E_;
    gi1.bias = ebih_b; gi1.C = gi_b; gi1.ldc = G3H; gi1.gidx = src; gi1.gt = S_ - 1 - t;
    launch_gemm<1, 0>(gi0, gi1, 2, B_, G3H, E_, 0, stream);

    GA gh0 = Z; gh0.A = h_f; gh0.lda = H_; gh0.W = eWhh_f; gh0.ldw = H_;
    gh0.bias = ebhh_f; gh0.C = gi_f; gh0.ldc = G3H; gh0.C2 = ghn_f;
    GA gh1 = Z; gh1.A = h_b; gh1.lda = H_; gh1.W = eWhh_b; gh1.ldw = H_;
    gh1.bias = ebhh_b; gh1.C = gi_b; gh1.ldc = G3H; gh1.C2 = ghn_b;
    launch_gemm<0, 2>(gh0, gh1, 2, B_, G3H, H_, 0, stream);

    hipLaunchKernelGGL(enc_gate_k, dim3((2 * B_ * H_) / 256), dim3(256), 0, stream,
                       gi_f, ghn_f, gi_b, ghn_b, h_f, h_b, enc_out, t);
  }

  // ---- enc_proj = enc_out @ Wa_e.T  -> fp16 (24576 x 1024 x 2048) ----
  {
    GA ep = Z; ep.A = enc_out; ep.lda = 2 * H_; ep.W = Wa + H_; ep.ldw = G3H;
    ep.Ch = proj; ep.ldc = H_;
    launch_gemm<0, 1>(ep, ep, 1, B_ * S_, H_, 2 * H_, 0, stream);
  }

  // ---- dec_h0 = tanh(cond @ Wbr.T + bbr), cond fused into A-loader ----
  {
    GA br = Z; br.W = Wbr; br.ldw = 2432; br.bias = bbr; br.C = h_d; br.ldc = H_;
    br.hf = h_f; br.hb = h_b; br.mE = mode_E; br.tE = tense_E; br.pE = person_E;
    br.mi = mode_idx; br.ti = tense_idx; br.pi = person_idx;
    launch_gemm<2, 0>(br, br, 1, B_, H_, 2432, 1, stream);
  }

  // ---- decoder: 39 sequential steps ----
  float* gi_d = gi_f;
  float* ghn_d = ghn_f;
  for (int t = 0; t < T_ - 1; ++t) {
    GA qa = Z; qa.A = h_d; qa.lda = H_; qa.W = Wa; qa.ldw = G3H; qa.C = q; qa.ldc = H_;
    launch_gemm<0, 0>(qa, qa, 1, B_, H_, H_, 0, stream);
    hipLaunchKernelGGL(attn_score_k, dim3(S_, B_), dim3(256), 0, stream,
                       q, proj, va, src, scores);
    hipLaunchKernelGGL(softmax_k, dim3(B_), dim3(128), 0, stream, scores, wts);
    hipLaunchKernelGGL(ctx_k, dim3((2 * H_) / 256, B_), dim3(256), 0, stream,
                       wts, enc_out, predin);
    hipLaunchKernelGGL(emb_k, dim3(B_), dim3(256), 0, stream, tok, dec_emb, predin);

    GA gia = Z; gia.A = predin; gia.W = dWih; gia.ldw = 2560; gia.bias = dbih;
    gia.C = gi_d; gia.ldc = G3H;
    launch_gemm<3, 0>(gia, gia, 1, B_, G3H, 2560, 0, stream);

    GA gha = Z; gha.A = h_d; gha.lda = H_; gha.W = dWhh; gha.ldw = H_;
    gha.bias = dbhh; gha.C = gi_d; gha.ldc = G3H; gha.C2 = ghn_d;
    launch_gemm<0, 2>(gha, gha, 1, B_, G3H, H_, 0, stream);

    hipLaunchKernelGGL(dec_gate_k, dim3((B_ * H_) / 256), dim3(256), 0, stream,
                       gi_d, ghn_d, h_d, predin);

    GA pr = Z; pr.A = predin; pr.lda = 3584; pr.W = Wfc; pr.ldw = 3584; pr.bias = bfc;
    pr.C = out + (size_t)t * V_; pr.ldc = (T_ - 1) * V_;
    launch_gemm<0, 0>(pr, pr, 1, B_, V_, 3584, 0, stream);

    hipLaunchKernelGGL(argmax_k, dim3(B_), dim3(256), 0, stream, out + (size_t)t * V_, tok);
  }
}

// Round 5
// 40132.327 us; speedup vs baseline: 1.1577x; 1.1577x over previous
//
#include <hip/hip_runtime.h>
#include <hip/hip_fp16.h>
#include <cstdint>
#include <cstddef>

#define B_  256
#define S_  96
#define T_  40
#define V_  256
#define E_  512
#define H_  1024
#define C_  128

__device__ __forceinline__ float sigmoidf_(float x) { return 1.0f / (1.0f + expf(-x)); }

// =================== generic fp32 tiled GEMM ===================
// C[m,n] = act(sum_k a(m,k) * W[n,k] + bias[n])
// AMODE: 0 plain A[m*lda+k]
//        1 gather rows: A[gidx[m*gstride+goff]*lda + k]
//        2 cond concat [hf | hb | modeE | tenseE | personE] (K=2432)
//        3 k-permuted predin view: k<512 -> emb(3072+k), else ctx(512+k)
// CMODE: 0 f32 store (optional tanh), 1 fp16 store
struct GB {
  const float* A; int lda;
  const float* W; int ldw;
  const float* bias;
  float* C; int ldc;
  __half* Ch;
  int M, N, K, act;
  const int* gidx; int gstride, goff;
  const float *hf, *hb; int ldh;
  const float *mE, *tE, *pE;
  const int *mi, *ti, *pi;
};

template<int AMODE, int CMODE>
__global__ __launch_bounds__(256)
void gemm_k(GB g0, GB g1)
{
  GB g = blockIdx.z ? g1 : g0;
  const int m0 = blockIdx.y * 64, n0 = blockIdx.x * 64;
  if (m0 >= g.M || n0 >= g.N) return;
  __shared__ float As[16][68];
  __shared__ float Ws[16][68];
  __shared__ int rows[64];
  const int tid = threadIdx.x, tx = tid & 15, ty = tid >> 4;
  const int lm = tid >> 2, lk = (tid & 3) << 2;
  if (AMODE == 1) {
    if (tid < 64) rows[tid] = g.gidx[(size_t)(m0 + tid) * g.gstride + g.goff];
    __syncthreads();
  }
  float acc[4][4] = {};
  for (int k0 = 0; k0 < g.K; k0 += 16) {
    const int kk = k0 + lk;
    float4 av, wv;
    if (AMODE == 0) {
      av = *(const float4*)(g.A + (size_t)(m0 + lm) * g.lda + kk);
    } else if (AMODE == 1) {
      av = *(const float4*)(g.A + (size_t)rows[lm] * g.lda + kk);
    } else if (AMODE == 2) {
      const int mg = m0 + lm; const float* sp; size_t o;
      if (kk < 1024)      { sp = g.hf; o = (size_t)mg * g.ldh + kk; }
      else if (kk < 2048) { sp = g.hb; o = (size_t)mg * g.ldh + kk - 1024; }
      else if (kk < 2176) { sp = g.mE; o = (size_t)g.mi[mg] * C_ + kk - 2048; }
      else if (kk < 2304) { sp = g.tE; o = (size_t)g.ti[mg] * C_ + kk - 2176; }
      else                { sp = g.pE; o = (size_t)g.pi[mg] * C_ + kk - 2304; }
      av = *(const float4*)(sp + o);
    } else {  // AMODE 3
      const int off = (kk < 512) ? (3072 + kk) : (512 + kk);
      av = *(const float4*)(g.A + (size_t)(m0 + lm) * 3584 + off);
    }
    wv = *(const float4*)(g.W + (size_t)(n0 + lm) * g.ldw + kk);
    __syncthreads();
    As[lk + 0][lm] = av.x; As[lk + 1][lm] = av.y; As[lk + 2][lm] = av.z; As[lk + 3][lm] = av.w;
    Ws[lk + 0][lm] = wv.x; Ws[lk + 1][lm] = wv.y; Ws[lk + 2][lm] = wv.z; Ws[lk + 3][lm] = wv.w;
    __syncthreads();
#pragma unroll
    for (int k = 0; k < 16; ++k) {
      const float4 a4 = *(const float4*)&As[k][ty << 2];
      const float4 b4 = *(const float4*)&Ws[k][tx << 2];
      acc[0][0] += a4.x * b4.x; acc[0][1] += a4.x * b4.y; acc[0][2] += a4.x * b4.z; acc[0][3] += a4.x * b4.w;
      acc[1][0] += a4.y * b4.x; acc[1][1] += a4.y * b4.y; acc[1][2] += a4.y * b4.z; acc[1][3] += a4.y * b4.w;
      acc[2][0] += a4.z * b4.x; acc[2][1] += a4.z * b4.y; acc[2][2] += a4.z * b4.z; acc[2][3] += a4.z * b4.w;
      acc[3][0] += a4.w * b4.x; acc[3][1] += a4.w * b4.y; acc[3][2] += a4.w * b4.z; acc[3][3] += a4.w * b4.w;
    }
  }
  const int n = n0 + (tx << 2);
  float4 bb = make_float4(0.f, 0.f, 0.f, 0.f);
  if (g.bias) bb = *(const float4*)(g.bias + n);
#pragma unroll
  for (int i = 0; i < 4; ++i) {
    const int m = m0 + (ty << 2) + i;
    float4 v = make_float4(acc[i][0] + bb.x, acc[i][1] + bb.y, acc[i][2] + bb.z, acc[i][3] + bb.w);
    if (CMODE == 0) {
      if (g.act) { v.x = tanhf(v.x); v.y = tanhf(v.y); v.z = tanhf(v.z); v.w = tanhf(v.w); }
      *(float4*)(g.C + (size_t)m * g.ldc + n) = v;
    } else {
      __half2* cp = (__half2*)(g.Ch + (size_t)m * g.ldc + n);
      cp[0] = __floats2half2_rn(v.x, v.y);
      cp[1] = __floats2half2_rn(v.z, v.w);
    }
  }
}

// =================== fused h-GEMM + GRU gate ===================
// Computes gh = h @ Whh.T (+bhh) for all 3 gate thirds of a 64-wide k slice,
// combines with precomputed gi, applies the gate, writes h_new.
// ENC (DEC=0): per-dir (blockIdx.z), h double-buffered through enc_out slices.
// DEC (DEC=1): h_d ping-pong + predin[h2] write.
struct GG {
  const float* hsrc0; const float* hsrc1; int lda;  // per-dir h source (lda=0 -> zeros)
  const float* W0; const float* W1;                 // Whh (3H x H)
  const float* b0; const float* b1;                 // bhh
  const float* gi;                                  // gi (+ dir*B*3H for enc)
  float* hdst0; float* hdst1; int ldd;
  float* predin;
};

template<int DEC>
__global__ __launch_bounds__(256)
void ghgate_k(GG g)
{
  const int dir = DEC ? 0 : blockIdx.z;
  const int m0 = blockIdx.y * 64, q0 = blockIdx.x * 64;
  __shared__ float Hs[16][68], Wr[16][68], Wz[16][68], Wn[16][68];
  const int tid = threadIdx.x, tx = tid & 15, ty = tid >> 4;
  const int lm = tid >> 2, lk = (tid & 3) << 2;
  const float* A = dir ? g.hsrc1 : g.hsrc0;
  const float* W = dir ? g.W1 : g.W0;
  float ar[4][4] = {}, az[4][4] = {}, an[4][4] = {};
  for (int k0 = 0; k0 < H_; k0 += 16) {
    const int kk = k0 + lk;
    const float4 hv = *(const float4*)(A + (size_t)(m0 + lm) * g.lda + kk);
    const float4 r4 = *(const float4*)(W + (size_t)(q0 + lm) * H_ + kk);
    const float4 z4 = *(const float4*)(W + (size_t)(H_ + q0 + lm) * H_ + kk);
    const float4 n4 = *(const float4*)(W + (size_t)(2 * H_ + q0 + lm) * H_ + kk);
    __syncthreads();
    Hs[lk + 0][lm] = hv.x; Hs[lk + 1][lm] = hv.y; Hs[lk + 2][lm] = hv.z; Hs[lk + 3][lm] = hv.w;
    Wr[lk + 0][lm] = r4.x; Wr[lk + 1][lm] = r4.y; Wr[lk + 2][lm] = r4.z; Wr[lk + 3][lm] = r4.w;
    Wz[lk + 0][lm] = z4.x; Wz[lk + 1][lm] = z4.y; Wz[lk + 2][lm] = z4.z; Wz[lk + 3][lm] = z4.w;
    Wn[lk + 0][lm] = n4.x; Wn[lk + 1][lm] = n4.y; Wn[lk + 2][lm] = n4.z; Wn[lk + 3][lm] = n4.w;
    __syncthreads();
#pragma unroll
    for (int k = 0; k < 16; ++k) {
      const float4 a4 = *(const float4*)&Hs[k][ty << 2];
      const float4 br = *(const float4*)&Wr[k][tx << 2];
      const float4 bz = *(const float4*)&Wz[k][tx << 2];
      const float4 bn = *(const float4*)&Wn[k][tx << 2];
      const float am[4] = { a4.x, a4.y, a4.z, a4.w };
#pragma unroll
      for (int i = 0; i < 4; ++i) {
        ar[i][0] += am[i] * br.x; ar[i][1] += am[i] * br.y; ar[i][2] += am[i] * br.z; ar[i][3] += am[i] * br.w;
        az[i][0] += am[i] * bz.x; az[i][1] += am[i] * bz.y; az[i][2] += am[i] * bz.z; az[i][3] += am[i] * bz.w;
        an[i][0] += am[i] * bn.x; an[i][1] += am[i] * bn.y; an[i][2] += am[i] * bn.z; an[i][3] += am[i] * bn.w;
      }
    }
  }
  const float* bias = dir ? g.b1 : g.b0;
  const float* gi = g.gi + (DEC ? 0 : (size_t)dir * B_ * 3 * H_);
  float* D = dir ? g.hdst1 : g.hdst0;
  const int kn = q0 + (tx << 2);
  const float4 biasr = *(const float4*)(bias + kn);
  const float4 biasz = *(const float4*)(bias + H_ + kn);
  const float4 biasn = *(const float4*)(bias + 2 * H_ + kn);
#pragma unroll
  for (int i = 0; i < 4; ++i) {
    const int b = m0 + (ty << 2) + i;
    const float4 gir = *(const float4*)(gi + (size_t)b * 3 * H_ + kn);
    const float4 giz = *(const float4*)(gi + (size_t)b * 3 * H_ + H_ + kn);
    const float4 gin = *(const float4*)(gi + (size_t)b * 3 * H_ + 2 * H_ + kn);
    const float4 hold = *(const float4*)(A + (size_t)b * g.lda + kn);
    float4 hv;
    {
      float r = sigmoidf_(gir.x + ar[i][0] + biasr.x);
      float z = sigmoidf_(giz.x + az[i][0] + biasz.x);
      float nn = tanhf(gin.x + r * (an[i][0] + biasn.x));
      hv.x = (1.f - z) * nn + z * hold.x;
      r = sigmoidf_(gir.y + ar[i][1] + biasr.y);
      z = sigmoidf_(giz.y + az[i][1] + biasz.y);
      nn = tanhf(gin.y + r * (an[i][1] + biasn.y));
      hv.y = (1.f - z) * nn + z * hold.y;
      r = sigmoidf_(gir.z + ar[i][2] + biasr.z);
      z = sigmoidf_(giz.z + az[i][2] + biasz.z);
      nn = tanhf(gin.z + r * (an[i][2] + biasn.z));
      hv.z = (1.f - z) * nn + z * hold.z;
      r = sigmoidf_(gir.w + ar[i][3] + biasr.w);
      z = sigmoidf_(giz.w + az[i][3] + biasz.w);
      nn = tanhf(gin.w + r * (an[i][3] + biasn.w));
      hv.w = (1.f - z) * nn + z * hold.w;
    }
    *(float4*)(D + (size_t)b * g.ldd + kn) = hv;
    if (DEC) *(float4*)(g.predin + (size_t)b * 3584 + kn) = hv;
  }
}

// =================== fused decoder attention step ===================
// Per b (block, 1024 thr): argmax(prev logits)->tok, emb write, scores, softmax, ctx.
__global__ __launch_bounds__(1024)
void attn_k(const float* __restrict__ out, const int* __restrict__ tgt,
            const float* __restrict__ q, const __half* __restrict__ proj,
            const float* __restrict__ va, const int* __restrict__ src,
            const float* __restrict__ enc_out, const float* __restrict__ dec_emb,
            float* __restrict__ predin, int t)
{
  const int b = blockIdx.x, tid = threadIdx.x;
  const int lane = tid & 63, wv = tid >> 6;
  __shared__ float sm[128];
  __shared__ float tr[128];
  __shared__ float rv[16];
  __shared__ int ri[16];
  __shared__ int tok_s;
  if (t == 0) {
    if (tid == 0) tok_s = tgt[(size_t)b * T_];
  } else {
    if (tid < 256) {
      float av = out[((size_t)b * (T_ - 1) + (t - 1)) * V_ + tid];
      int ai = tid;
      for (int off = 32; off; off >>= 1) {
        const float ov = __shfl_down(av, off);
        const int   oi = __shfl_down(ai, off);
        if (ov > av) { av = ov; ai = oi; }   // strict >: first-max semantics
      }
      if (lane == 0) { rv[wv] = av; ri[wv] = ai; }
    }
    __syncthreads();
    if (tid == 0) {
      float bv = rv[0]; int bi = ri[0];
      for (int w = 1; w < 4; ++w) if (rv[w] > bv) { bv = rv[w]; bi = ri[w]; }
      tok_s = bi;
    }
  }
  __syncthreads();
  const int tok = tok_s;
  if (tid < E_) predin[(size_t)b * 3584 + 3072 + tid] = dec_emb[(size_t)tok * E_ + tid];
  // scores: wave wv owns s = wv*6 .. wv*6+5
  const float* qb = q + (size_t)b * H_;
  for (int s = wv * 6; s < wv * 6 + 6; ++s) {
    float part = 0.f;
#pragma unroll
    for (int jj = 0; jj < 16; ++jj) {
      const int h = lane + jj * 64;
      part += va[h] * tanhf(qb[h] + __half2float(proj[((size_t)b * S_ + s) * H_ + h]));
    }
    for (int off = 32; off; off >>= 1) part += __shfl_down(part, off);
    if (lane == 0)
      sm[s] = (src[(size_t)b * S_ + s] == 0) ? -1.0e9f : part;
  }
  __syncthreads();
  // softmax over 96
  if (tid < 128) tr[tid] = (tid < S_) ? sm[tid] : -3.0e38f;
  __syncthreads();
  for (int s2 = 64; s2 > 0; s2 >>= 1) { if (tid < s2) tr[tid] = fmaxf(tr[tid], tr[tid + s2]); __syncthreads(); }
  const float mx = tr[0];
  __syncthreads();
  if (tid < 128) tr[tid] = (tid < S_) ? expf(sm[tid] - mx) : 0.f;
  __syncthreads();
  for (int s2 = 64; s2 > 0; s2 >>= 1) { if (tid < s2) tr[tid] += tr[tid + s2]; __syncthreads(); }
  const float inv = 1.0f / tr[0];
  __syncthreads();
  if (tid < S_) sm[tid] = expf(sm[tid] - mx) * inv;
  __syncthreads();
  // ctx: 2 dims per thread
  const int d0 = tid * 2;
  const float* eb = enc_out + (size_t)b * S_ * 2 * H_;
  float c0 = 0.f, c1 = 0.f;
  for (int s = 0; s < S_; ++s) {
    const float w = sm[s];
    const float2 e2 = *(const float2*)(eb + (size_t)s * 2 * H_ + d0);
    c0 += w * e2.x; c1 += w * e2.y;
  }
  *(float2*)(predin + (size_t)b * 3584 + H_ + d0) = make_float2(c0, c1);
}

// =================== misc ===================
__global__ void zero_k(float* __restrict__ p, int n)
{
  const int i = blockIdx.x * 256 + threadIdx.x;
  if (i < n) p[i] = 0.0f;
}

__global__ void sentinel_k(float* out, float v) { out[threadIdx.x] = v; }

// =================== host orchestration ===================
extern "C" void kernel_launch(void* const* d_in, const int* in_sizes, int n_in,
                              void* d_out, int out_size, void* d_ws, size_t ws_size,
                              hipStream_t stream)
{
  const int*   src        = (const int*)d_in[0];
  const int*   tgt        = (const int*)d_in[1];
  const int*   mode_idx   = (const int*)d_in[2];
  const int*   tense_idx  = (const int*)d_in[3];
  const int*   person_idx = (const int*)d_in[4];
  const float* enc_emb    = (const float*)d_in[5];
  const float* eWih_f     = (const float*)d_in[6];
  const float* eWhh_f     = (const float*)d_in[7];
  const float* ebih_f     = (const float*)d_in[8];
  const float* ebhh_f     = (const float*)d_in[9];
  const float* eWih_b     = (const float*)d_in[10];
  const float* eWhh_b     = (const float*)d_in[11];
  const float* ebih_b     = (const float*)d_in[12];
  const float* ebhh_b     = (const float*)d_in[13];
  const float* Wa         = (const float*)d_in[14];
  const float* va         = (const float*)d_in[15];
  const float* dec_emb    = (const float*)d_in[16];
  const float* dWih       = (const float*)d_in[17];
  const float* dWhh       = (const float*)d_in[18];
  const float* dbih       = (const float*)d_in[19];
  const float* dbhh       = (const float*)d_in[20];
  const float* Wfc        = (const float*)d_in[21];
  const float* bfc        = (const float*)d_in[22];
  const float* mode_E     = (const float*)d_in[23];
  const float* tense_E    = (const float*)d_in[24];
  const float* person_E   = (const float*)d_in[25];
  const float* Wbr        = (const float*)d_in[26];
  const float* bbr        = (const float*)d_in[27];
  float* out = (float*)d_out;

  // ---- workspace carve (~267.9 MB, fits proven >=268.1 MB budget) ----
  char* base = (char*)d_ws;
  size_t off = 0;
  auto alloc = [&](size_t bytes) { char* r = base + off; off = (off + bytes + 255) & ~(size_t)255; return r; };
  float*  enc_out  = (float*)alloc(4ull * B_ * S_ * 2 * H_);   // 201.3 MB (doubles as h storage)
  __half* proj     = (__half*)alloc(2ull * B_ * S_ * H_);      // 50.3 MB
  float*  gi       = (float*)alloc(4ull * 2 * B_ * 3 * H_);    // 6.3 MB (both dirs)
  float*  gi_d     = (float*)alloc(4ull * B_ * 3 * H_);        // 3.1 MB
  float*  h_d0     = (float*)alloc(4ull * B_ * H_);
  float*  h_d1     = (float*)alloc(4ull * B_ * H_);
  float*  q        = (float*)alloc(4ull * B_ * H_);
  float*  predin   = (float*)alloc(4ull * B_ * 3584);          // [h2|ctx|emb]
  float*  zero_buf = (float*)alloc(4ull * 1024);
  if (off > ws_size) {
    hipLaunchKernelGGL(sentinel_k, dim3(1), dim3(256), 0, stream, out,
                       1000.0f + (float)(ws_size >> 20));
    return;
  }

  hipLaunchKernelGGL(zero_k, dim3(4), dim3(256), 0, stream, zero_buf, 1024);

  GB Z{};

  // ---- encoder: 96 steps x (gi GEMM nz=2, ghgate nz=2) ----
  for (int t = 0; t < S_; ++t) {
    GB g0 = Z, g1 = Z;
    g0.A = enc_emb; g0.lda = E_; g0.W = eWih_f; g0.ldw = E_; g0.bias = ebih_f;
    g0.C = gi; g0.ldc = 3 * H_; g0.M = B_; g0.N = 3 * H_; g0.K = E_;
    g0.gidx = src; g0.gstride = S_; g0.goff = t;
    g1 = g0; g1.W = eWih_b; g1.bias = ebih_b; g1.C = gi + (size_t)B_ * 3 * H_;
    g1.goff = S_ - 1 - t;
    hipLaunchKernelGGL((gemm_k<1, 0>), dim3(48, 4, 2), dim3(256), 0, stream, g0, g1);

    GG gg{};
    if (t == 0) { gg.hsrc0 = zero_buf; gg.hsrc1 = zero_buf; gg.lda = 0; }
    else {
      gg.hsrc0 = enc_out + (size_t)(t - 1) * 2 * H_;
      gg.hsrc1 = enc_out + (size_t)(S_ - t) * 2 * H_ + H_;
      gg.lda = S_ * 2 * H_;
    }
    gg.W0 = eWhh_f; gg.W1 = eWhh_b; gg.b0 = ebhh_f; gg.b1 = ebhh_b; gg.gi = gi;
    gg.hdst0 = enc_out + (size_t)t * 2 * H_;
    gg.hdst1 = enc_out + (size_t)(S_ - 1 - t) * 2 * H_ + H_;
    gg.ldd = S_ * 2 * H_;
    hipLaunchKernelGGL((ghgate_k<0>), dim3(16, 4, 2), dim3(256), 0, stream, gg);
  }

  // ---- enc_proj (fp16 out) ----
  {
    GB ep = Z;
    ep.A = enc_out; ep.lda = 2 * H_; ep.W = Wa + H_; ep.ldw = 3 * H_;
    ep.Ch = proj; ep.ldc = H_; ep.M = B_ * S_; ep.N = H_; ep.K = 2 * H_;
    hipLaunchKernelGGL((gemm_k<0, 1>), dim3(16, 384, 1), dim3(256), 0, stream, ep, ep);
  }

  // ---- dec_h0 = tanh(cond @ Wbr.T + bbr) ----
  {
    GB br = Z;
    br.W = Wbr; br.ldw = 2432; br.bias = bbr; br.C = h_d0; br.ldc = H_;
    br.M = B_; br.N = H_; br.K = 2432; br.act = 1;
    br.hf = enc_out + (size_t)(S_ - 1) * 2 * H_; br.hb = enc_out + H_; br.ldh = S_ * 2 * H_;
    br.mE = mode_E; br.tE = tense_E; br.pE = person_E;
    br.mi = mode_idx; br.ti = tense_idx; br.pi = person_idx;
    hipLaunchKernelGGL((gemm_k<2, 0>), dim3(16, 4, 1), dim3(256), 0, stream, br, br);
  }

  // ---- q(0) ----
  {
    GB qa = Z;
    qa.A = h_d0; qa.lda = H_; qa.W = Wa; qa.ldw = 3 * H_; qa.C = q; qa.ldc = H_;
    qa.M = B_; qa.N = H_; qa.K = H_;
    hipLaunchKernelGGL((gemm_k<0, 0>), dim3(16, 4, 1), dim3(256), 0, stream, qa, qa);
  }

  // ---- decoder: 39 steps x (attn, gia, ghgate, pred+qa) ----
  float* hd[2] = { h_d0, h_d1 };
  for (int t = 0; t < T_ - 1; ++t) {
    hipLaunchKernelGGL(attn_k, dim3(B_), dim3(1024), 0, stream,
                       out, tgt, q, proj, va, src, enc_out, dec_emb, predin, t);

    GB gia = Z;
    gia.A = predin; gia.W = dWih; gia.ldw = 2560; gia.bias = dbih;
    gia.C = gi_d; gia.ldc = 3 * H_; gia.M = B_; gia.N = 3 * H_; gia.K = 2560;
    hipLaunchKernelGGL((gemm_k<3, 0>), dim3(48, 4, 1), dim3(256), 0, stream, gia, gia);

    GG gd{};
    gd.hsrc0 = hd[t & 1]; gd.lda = H_;
    gd.W0 = dWhh; gd.b0 = dbhh; gd.gi = gi_d;
    gd.hdst0 = hd[(t + 1) & 1]; gd.ldd = H_;
    gd.predin = predin;
    hipLaunchKernelGGL((ghgate_k<1>), dim3(16, 4, 1), dim3(256), 0, stream, gd);

    GB pr = Z, qa = Z;
    pr.A = predin; pr.lda = 3584; pr.W = Wfc; pr.ldw = 3584; pr.bias = bfc;
    pr.C = out + (size_t)t * V_; pr.ldc = (T_ - 1) * V_;
    pr.M = B_; pr.N = V_; pr.K = 3584;
    qa.A = hd[(t + 1) & 1]; qa.lda = H_; qa.W = Wa; qa.ldw = 3 * H_;
    qa.C = q; qa.ldc = H_; qa.M = B_; qa.N = H_; qa.K = H_;
    hipLaunchKernelGGL((gemm_k<0, 0>), dim3(16, 4, 2), dim3(256), 0, stream, pr, qa);
  }
}

// Round 6
// 33678.619 us; speedup vs baseline: 1.3795x; 1.1916x over previous
//
#include <hip/hip_runtime.h>
#include <hip/hip_fp16.h>
#include <cstdint>
#include <cstddef>

#define B_  256
#define S_  96
#define T_  40
#define V_  256
#define E_  512
#define H_  1024
#define C_  128

__device__ __forceinline__ float sigmoidf_(float x) { return 1.0f / (1.0f + expf(-x)); }

// =================== fused RNN step: gi-GEMM + gh-GEMM + GRU gate ===================
// DEC=0 (encoder): z = dir (0 fwd, 1 bwd). Phase1 K=512, A = enc_emb[src[m,goff]].
//                  h double-buffered through enc_out slices.
// DEC=1 (decoder): Phase1 K=2560, A = k-permuted predin ([emb|ctx] view).
//                  h ping-pong + predin[h2] write.
// n-gate needs input/hidden parts separate: anI (phase1) and anH (phase2).
struct RS {
  const float* A1;                       // enc_emb (ENC) / predin (DEC)
  const int* gidx; int goff0, goff1;     // ENC gather (per dir)
  const float* h0; const float* h1; int ldh;
  const float* Wih0; const float* Wih1;  // [3H][K1]
  const float* Whh0; const float* Whh1;  // [3H][H]
  const float* bih0; const float* bih1;
  const float* bhh0; const float* bhh1;
  float* d0; float* d1; int ldd;
  float* predin;                         // DEC only
};

template<int DEC>
__global__ __launch_bounds__(256)
void rnnstep_k(RS g)
{
  constexpr int K1 = DEC ? 2560 : E_;
  constexpr int TM = DEC ? 32 : 64;      // batch-tile
  constexpr int RM = TM / 16;            // rows per thread
  const int dir = DEC ? 0 : blockIdx.z;
  const int m0 = blockIdx.y * TM, q0 = blockIdx.x * 32;
  __shared__ float As[32][TM + 4];
  __shared__ float Ws[3][32][36];
  __shared__ int rows[TM];
  const int tid = threadIdx.x;
  const int tx = tid & 15, ty = tid >> 4;
  const float* Wih = dir ? g.Wih1 : g.Wih0;
  const float* Whh = dir ? g.Whh1 : g.Whh0;
  const float* hsrc = dir ? g.h1 : g.h0;

  if (!DEC) {
    if (tid < TM)
      rows[tid] = g.gidx[(size_t)(m0 + tid) * S_ + (dir ? g.goff1 : g.goff0)];
    __syncthreads();
  }

  float ar[RM][2] = {}, az[RM][2] = {}, anI[RM][2] = {}, anH[RM][2] = {};
  const int wrow = tid >> 3, wkp = (tid & 7) << 2;

  // ---------- phase 1: input GEMM ----------
  for (int k0 = 0; k0 < K1; k0 += 32) {
    float4 av[TM / 32];
#pragma unroll
    for (int i = 0; i < TM / 32; ++i) {
      const int f = tid + i * 256;
      const int arow = f >> 3, kk = k0 + ((f & 7) << 2);
      if (!DEC) {
        av[i] = *(const float4*)(g.A1 + (size_t)rows[arow] * E_ + kk);
      } else {
        const int off = (kk < 512) ? (3072 + kk) : (512 + kk);
        av[i] = *(const float4*)(g.A1 + (size_t)(m0 + arow) * 3584 + off);
      }
    }
    float4 wv[3];
#pragma unroll
    for (int th = 0; th < 3; ++th)
      wv[th] = *(const float4*)(Wih + (size_t)(th * H_ + q0 + wrow) * K1 + k0 + wkp);
    __syncthreads();
#pragma unroll
    for (int i = 0; i < TM / 32; ++i) {
      const int f = tid + i * 256;
      const int arow = f >> 3, kp = (f & 7) << 2;
      As[kp + 0][arow] = av[i].x; As[kp + 1][arow] = av[i].y;
      As[kp + 2][arow] = av[i].z; As[kp + 3][arow] = av[i].w;
    }
#pragma unroll
    for (int th = 0; th < 3; ++th) {
      Ws[th][wkp + 0][wrow] = wv[th].x; Ws[th][wkp + 1][wrow] = wv[th].y;
      Ws[th][wkp + 2][wrow] = wv[th].z; Ws[th][wkp + 3][wrow] = wv[th].w;
    }
    __syncthreads();
#pragma unroll
    for (int k = 0; k < 32; ++k) {
      float am[RM];
      if constexpr (TM == 64) {
        const float4 a4 = *(const float4*)&As[k][ty << 2];
        am[0] = a4.x; am[1] = a4.y; am[2] = a4.z; am[3] = a4.w;
      } else {
        const float2 a2 = *(const float2*)&As[k][ty << 1];
        am[0] = a2.x; am[1] = a2.y;
      }
      const float2 wr = *(const float2*)&Ws[0][k][tx << 1];
      const float2 wz = *(const float2*)&Ws[1][k][tx << 1];
      const float2 wn = *(const float2*)&Ws[2][k][tx << 1];
#pragma unroll
      for (int i = 0; i < RM; ++i) {
        ar[i][0] += am[i] * wr.x; ar[i][1] += am[i] * wr.y;
        az[i][0] += am[i] * wz.x; az[i][1] += am[i] * wz.y;
        anI[i][0] += am[i] * wn.x; anI[i][1] += am[i] * wn.y;
      }
    }
    __syncthreads();
  }

  // ---------- phase 2: hidden GEMM ----------
  for (int k0 = 0; k0 < H_; k0 += 32) {
    float4 av[TM / 32];
#pragma unroll
    for (int i = 0; i < TM / 32; ++i) {
      const int f = tid + i * 256;
      const int arow = f >> 3, kk = k0 + ((f & 7) << 2);
      av[i] = *(const float4*)(hsrc + (size_t)(m0 + arow) * g.ldh + kk);
    }
    float4 wv[3];
#pragma unroll
    for (int th = 0; th < 3; ++th)
      wv[th] = *(const float4*)(Whh + (size_t)(th * H_ + q0 + wrow) * H_ + k0 + wkp);
    __syncthreads();
#pragma unroll
    for (int i = 0; i < TM / 32; ++i) {
      const int f = tid + i * 256;
      const int arow = f >> 3, kp = (f & 7) << 2;
      As[kp + 0][arow] = av[i].x; As[kp + 1][arow] = av[i].y;
      As[kp + 2][arow] = av[i].z; As[kp + 3][arow] = av[i].w;
    }
#pragma unroll
    for (int th = 0; th < 3; ++th) {
      Ws[th][wkp + 0][wrow] = wv[th].x; Ws[th][wkp + 1][wrow] = wv[th].y;
      Ws[th][wkp + 2][wrow] = wv[th].z; Ws[th][wkp + 3][wrow] = wv[th].w;
    }
    __syncthreads();
#pragma unroll
    for (int k = 0; k < 32; ++k) {
      float am[RM];
      if constexpr (TM == 64) {
        const float4 a4 = *(const float4*)&As[k][ty << 2];
        am[0] = a4.x; am[1] = a4.y; am[2] = a4.z; am[3] = a4.w;
      } else {
        const float2 a2 = *(const float2*)&As[k][ty << 1];
        am[0] = a2.x; am[1] = a2.y;
      }
      const float2 wr = *(const float2*)&Ws[0][k][tx << 1];
      const float2 wz = *(const float2*)&Ws[1][k][tx << 1];
      const float2 wn = *(const float2*)&Ws[2][k][tx << 1];
#pragma unroll
      for (int i = 0; i < RM; ++i) {
        ar[i][0] += am[i] * wr.x; ar[i][1] += am[i] * wr.y;
        az[i][0] += am[i] * wz.x; az[i][1] += am[i] * wz.y;
        anH[i][0] += am[i] * wn.x; anH[i][1] += am[i] * wn.y;
      }
    }
    __syncthreads();
  }

  // ---------- gate epilogue ----------
  const float* bih = dir ? g.bih1 : g.bih0;
  const float* bhh = dir ? g.bhh1 : g.bhh0;
  float* dst = dir ? g.d1 : g.d0;
  const int qq = q0 + (tx << 1);
  const float2 bir = *(const float2*)(bih + qq);
  const float2 biz = *(const float2*)(bih + H_ + qq);
  const float2 bin = *(const float2*)(bih + 2 * H_ + qq);
  const float2 bhr = *(const float2*)(bhh + qq);
  const float2 bhz = *(const float2*)(bhh + H_ + qq);
  const float2 bhn = *(const float2*)(bhh + 2 * H_ + qq);
#pragma unroll
  for (int i = 0; i < RM; ++i) {
    const int b = m0 + ty * RM + i;
    const float2 hold = *(const float2*)(hsrc + (size_t)b * g.ldh + qq);
    float2 hv;
    float r = sigmoidf_(ar[i][0] + bir.x + bhr.x);
    float z = sigmoidf_(az[i][0] + biz.x + bhz.x);
    float n = tanhf(anI[i][0] + bin.x + r * (anH[i][0] + bhn.x));
    hv.x = (1.f - z) * n + z * hold.x;
    r = sigmoidf_(ar[i][1] + bir.y + bhr.y);
    z = sigmoidf_(az[i][1] + biz.y + bhz.y);
    n = tanhf(anI[i][1] + bin.y + r * (anH[i][1] + bhn.y));
    hv.y = (1.f - z) * n + z * hold.y;
    *(float2*)(dst + (size_t)b * g.ldd + qq) = hv;
    if (DEC) *(float2*)(g.predin + (size_t)b * 3584 + qq) = hv;
  }
}

// =================== generic fp32 tiled GEMM (proj / br / q / pred) ===================
// AMODE: 0 plain, 2 cond concat [hf|hb|modeE|tenseE|personE] (K=2432)
// CMODE: 0 f32 (optional tanh), 1 fp16
struct GB {
  const float* A; int lda;
  const float* W; int ldw;
  const float* bias;
  float* C; int ldc;
  __half* Ch;
  int M, N, K, act;
  const float *hf, *hb; int ldh;
  const float *mE, *tE, *pE;
  const int *mi, *ti, *pi;
};

template<int AMODE, int CMODE>
__global__ __launch_bounds__(256)
void gemm_k(GB g0, GB g1)
{
  GB g = blockIdx.z ? g1 : g0;
  const int m0 = blockIdx.y * 64, n0 = blockIdx.x * 64;
  if (m0 >= g.M || n0 >= g.N) return;
  __shared__ float As[16][68];
  __shared__ float Ws[16][68];
  const int tid = threadIdx.x, tx = tid & 15, ty = tid >> 4;
  const int lm = tid >> 2, lk = (tid & 3) << 2;
  float acc[4][4] = {};
  for (int k0 = 0; k0 < g.K; k0 += 16) {
    const int kk = k0 + lk;
    float4 av, wv;
    if (AMODE == 0) {
      av = *(const float4*)(g.A + (size_t)(m0 + lm) * g.lda + kk);
    } else {  // AMODE 2
      const int mg = m0 + lm; const float* sp; size_t o;
      if (kk < 1024)      { sp = g.hf; o = (size_t)mg * g.ldh + kk; }
      else if (kk < 2048) { sp = g.hb; o = (size_t)mg * g.ldh + kk - 1024; }
      else if (kk < 2176) { sp = g.mE; o = (size_t)g.mi[mg] * C_ + kk - 2048; }
      else if (kk < 2304) { sp = g.tE; o = (size_t)g.ti[mg] * C_ + kk - 2176; }
      else                { sp = g.pE; o = (size_t)g.pi[mg] * C_ + kk - 2304; }
      av = *(const float4*)(sp + o);
    }
    wv = *(const float4*)(g.W + (size_t)(n0 + lm) * g.ldw + kk);
    __syncthreads();
    As[lk + 0][lm] = av.x; As[lk + 1][lm] = av.y; As[lk + 2][lm] = av.z; As[lk + 3][lm] = av.w;
    Ws[lk + 0][lm] = wv.x; Ws[lk + 1][lm] = wv.y; Ws[lk + 2][lm] = wv.z; Ws[lk + 3][lm] = wv.w;
    __syncthreads();
#pragma unroll
    for (int k = 0; k < 16; ++k) {
      const float4 a4 = *(const float4*)&As[k][ty << 2];
      const float4 b4 = *(const float4*)&Ws[k][tx << 2];
      acc[0][0] += a4.x * b4.x; acc[0][1] += a4.x * b4.y; acc[0][2] += a4.x * b4.z; acc[0][3] += a4.x * b4.w;
      acc[1][0] += a4.y * b4.x; acc[1][1] += a4.y * b4.y; acc[1][2] += a4.y * b4.z; acc[1][3] += a4.y * b4.w;
      acc[2][0] += a4.z * b4.x; acc[2][1] += a4.z * b4.y; acc[2][2] += a4.z * b4.z; acc[2][3] += a4.z * b4.w;
      acc[3][0] += a4.w * b4.x; acc[3][1] += a4.w * b4.y; acc[3][2] += a4.w * b4.z; acc[3][3] += a4.w * b4.w;
    }
  }
  const int n = n0 + (tx << 2);
  float4 bb = make_float4(0.f, 0.f, 0.f, 0.f);
  if (g.bias) bb = *(const float4*)(g.bias + n);
#pragma unroll
  for (int i = 0; i < 4; ++i) {
    const int m = m0 + (ty << 2) + i;
    float4 v = make_float4(acc[i][0] + bb.x, acc[i][1] + bb.y, acc[i][2] + bb.z, acc[i][3] + bb.w);
    if (CMODE == 0) {
      if (g.act) { v.x = tanhf(v.x); v.y = tanhf(v.y); v.z = tanhf(v.z); v.w = tanhf(v.w); }
      *(float4*)(g.C + (size_t)m * g.ldc + n) = v;
    } else {
      __half2* cp = (__half2*)(g.Ch + (size_t)m * g.ldc + n);
      cp[0] = __floats2half2_rn(v.x, v.y);
      cp[1] = __floats2half2_rn(v.z, v.w);
    }
  }
}

// =================== fused decoder attention step ===================
__global__ __launch_bounds__(1024)
void attn_k(const float* __restrict__ out, const int* __restrict__ tgt,
            const float* __restrict__ q, const __half* __restrict__ proj,
            const float* __restrict__ va, const int* __restrict__ src,
            const float* __restrict__ enc_out, const float* __restrict__ dec_emb,
            float* __restrict__ predin, int t)
{
  const int b = blockIdx.x, tid = threadIdx.x;
  const int lane = tid & 63, wv = tid >> 6;
  __shared__ float sm[128];
  __shared__ float tr[128];
  __shared__ float rv[16];
  __shared__ int ri[16];
  __shared__ int tok_s;
  if (t == 0) {
    if (tid == 0) tok_s = tgt[(size_t)b * T_];
  } else {
    if (tid < 256) {
      float av = out[((size_t)b * (T_ - 1) + (t - 1)) * V_ + tid];
      int ai = tid;
      for (int off = 32; off; off >>= 1) {
        const float ov = __shfl_down(av, off);
        const int   oi = __shfl_down(ai, off);
        if (ov > av) { av = ov; ai = oi; }
      }
      if (lane == 0) { rv[wv] = av; ri[wv] = ai; }
    }
    __syncthreads();
    if (tid == 0) {
      float bv = rv[0]; int bi = ri[0];
      for (int w = 1; w < 4; ++w) if (rv[w] > bv) { bv = rv[w]; bi = ri[w]; }
      tok_s = bi;
    }
  }
  __syncthreads();
  const int tok = tok_s;
  if (tid < E_) predin[(size_t)b * 3584 + 3072 + tid] = dec_emb[(size_t)tok * E_ + tid];
  const float* qb = q + (size_t)b * H_;
  for (int s = wv * 6; s < wv * 6 + 6; ++s) {
    float part = 0.f;
#pragma unroll
    for (int jj = 0; jj < 16; ++jj) {
      const int h = lane + jj * 64;
      part += va[h] * tanhf(qb[h] + __half2float(proj[((size_t)b * S_ + s) * H_ + h]));
    }
    for (int off = 32; off; off >>= 1) part += __shfl_down(part, off);
    if (lane == 0)
      sm[s] = (src[(size_t)b * S_ + s] == 0) ? -1.0e9f : part;
  }
  __syncthreads();
  if (tid < 128) tr[tid] = (tid < S_) ? sm[tid] : -3.0e38f;
  __syncthreads();
  for (int s2 = 64; s2 > 0; s2 >>= 1) { if (tid < s2) tr[tid] = fmaxf(tr[tid], tr[tid + s2]); __syncthreads(); }
  const float mx = tr[0];
  __syncthreads();
  if (tid < 128) tr[tid] = (tid < S_) ? expf(sm[tid] - mx) : 0.f;
  __syncthreads();
  for (int s2 = 64; s2 > 0; s2 >>= 1) { if (tid < s2) tr[tid] += tr[tid + s2]; __syncthreads(); }
  const float inv = 1.0f / tr[0];
  __syncthreads();
  if (tid < S_) sm[tid] = expf(sm[tid] - mx) * inv;
  __syncthreads();
  const int d0 = tid * 2;
  const float* eb = enc_out + (size_t)b * S_ * 2 * H_;
  float c0 = 0.f, c1 = 0.f;
  for (int s = 0; s < S_; ++s) {
    const float w = sm[s];
    const float2 e2 = *(const float2*)(eb + (size_t)s * 2 * H_ + d0);
    c0 += w * e2.x; c1 += w * e2.y;
  }
  *(float2*)(predin + (size_t)b * 3584 + H_ + d0) = make_float2(c0, c1);
}

// =================== misc ===================
__global__ void zero_k(float* __restrict__ p, int n)
{
  const int i = blockIdx.x * 256 + threadIdx.x;
  if (i < n) p[i] = 0.0f;
}

__global__ void sentinel_k(float* out, float v) { out[threadIdx.x] = v; }

// =================== host orchestration ===================
extern "C" void kernel_launch(void* const* d_in, const int* in_sizes, int n_in,
                              void* d_out, int out_size, void* d_ws, size_t ws_size,
                              hipStream_t stream)
{
  const int*   src        = (const int*)d_in[0];
  const int*   tgt        = (const int*)d_in[1];
  const int*   mode_idx   = (const int*)d_in[2];
  const int*   tense_idx  = (const int*)d_in[3];
  const int*   person_idx = (const int*)d_in[4];
  const float* enc_emb    = (const float*)d_in[5];
  const float* eWih_f     = (const float*)d_in[6];
  const float* eWhh_f     = (const float*)d_in[7];
  const float* ebih_f     = (const float*)d_in[8];
  const float* ebhh_f     = (const float*)d_in[9];
  const float* eWih_b     = (const float*)d_in[10];
  const float* eWhh_b     = (const float*)d_in[11];
  const float* ebih_b     = (const float*)d_in[12];
  const float* ebhh_b     = (const float*)d_in[13];
  const float* Wa         = (const float*)d_in[14];
  const float* va         = (const float*)d_in[15];
  const float* dec_emb    = (const float*)d_in[16];
  const float* dWih       = (const float*)d_in[17];
  const float* dWhh       = (const float*)d_in[18];
  const float* dbih       = (const float*)d_in[19];
  const float* dbhh       = (const float*)d_in[20];
  const float* Wfc        = (const float*)d_in[21];
  const float* bfc        = (const float*)d_in[22];
  const float* mode_E     = (const float*)d_in[23];
  const float* tense_E    = (const float*)d_in[24];
  const float* person_E   = (const float*)d_in[25];
  const float* Wbr        = (const float*)d_in[26];
  const float* bbr        = (const float*)d_in[27];
  float* out = (float*)d_out;

  // ---- workspace carve (~258 MB; proven budget >= 268 MB) ----
  char* base = (char*)d_ws;
  size_t off = 0;
  auto alloc = [&](size_t bytes) { char* r = base + off; off = (off + bytes + 255) & ~(size_t)255; return r; };
  float*  enc_out  = (float*)alloc(4ull * B_ * S_ * 2 * H_);   // 201.3 MB (doubles as enc h state)
  __half* proj     = (__half*)alloc(2ull * B_ * S_ * H_);      // 50.3 MB
  float*  h_d0     = (float*)alloc(4ull * B_ * H_);
  float*  h_d1     = (float*)alloc(4ull * B_ * H_);
  float*  q        = (float*)alloc(4ull * B_ * H_);
  float*  predin   = (float*)alloc(4ull * B_ * 3584);          // [h2|ctx|emb]
  float*  zero_buf = (float*)alloc(4ull * 1024);
  if (off > ws_size) {
    hipLaunchKernelGGL(sentinel_k, dim3(1), dim3(256), 0, stream, out,
                       1000.0f + (float)(ws_size >> 20));
    return;
  }

  hipLaunchKernelGGL(zero_k, dim3(4), dim3(256), 0, stream, zero_buf, 1024);

  // ---- encoder: 96 fused steps ----
  for (int t = 0; t < S_; ++t) {
    RS rs{};
    rs.A1 = enc_emb; rs.gidx = src; rs.goff0 = t; rs.goff1 = S_ - 1 - t;
    if (t == 0) { rs.h0 = zero_buf; rs.h1 = zero_buf; rs.ldh = 0; }
    else {
      rs.h0 = enc_out + (size_t)(t - 1) * 2 * H_;
      rs.h1 = enc_out + (size_t)(S_ - t) * 2 * H_ + H_;
      rs.ldh = S_ * 2 * H_;
    }
    rs.Wih0 = eWih_f; rs.Wih1 = eWih_b; rs.Whh0 = eWhh_f; rs.Whh1 = eWhh_b;
    rs.bih0 = ebih_f; rs.bih1 = ebih_b; rs.bhh0 = ebhh_f; rs.bhh1 = ebhh_b;
    rs.d0 = enc_out + (size_t)t * 2 * H_;
    rs.d1 = enc_out + (size_t)(S_ - 1 - t) * 2 * H_ + H_;
    rs.ldd = S_ * 2 * H_;
    hipLaunchKernelGGL((rnnstep_k<0>), dim3(32, 4, 2), dim3(256), 0, stream, rs);
  }

  GB Z{};

  // ---- enc_proj (fp16 out) ----
  {
    GB ep = Z;
    ep.A = enc_out; ep.lda = 2 * H_; ep.W = Wa + H_; ep.ldw = 3 * H_;
    ep.Ch = proj; ep.ldc = H_; ep.M = B_ * S_; ep.N = H_; ep.K = 2 * H_;
    hipLaunchKernelGGL((gemm_k<0, 1>), dim3(16, 384, 1), dim3(256), 0, stream, ep, ep);
  }

  // ---- dec_h0 = tanh(cond @ Wbr.T + bbr) ----
  {
    GB br = Z;
    br.W = Wbr; br.ldw = 2432; br.bias = bbr; br.C = h_d0; br.ldc = H_;
    br.M = B_; br.N = H_; br.K = 2432; br.act = 1;
    br.hf = enc_out + (size_t)(S_ - 1) * 2 * H_; br.hb = enc_out + H_; br.ldh = S_ * 2 * H_;
    br.mE = mode_E; br.tE = tense_E; br.pE = person_E;
    br.mi = mode_idx; br.ti = tense_idx; br.pi = person_idx;
    hipLaunchKernelGGL((gemm_k<2, 0>), dim3(16, 4, 1), dim3(256), 0, stream, br, br);
  }

  // ---- q(0) ----
  {
    GB qa = Z;
    qa.A = h_d0; qa.lda = H_; qa.W = Wa; qa.ldw = 3 * H_; qa.C = q; qa.ldc = H_;
    qa.M = B_; qa.N = H_; qa.K = H_;
    hipLaunchKernelGGL((gemm_k<0, 0>), dim3(16, 4, 1), dim3(256), 0, stream, qa, qa);
  }

  // ---- decoder: 39 steps x (attn, fused gia+gh+gate, pred+qa) ----
  float* hd[2] = { h_d0, h_d1 };
  for (int t = 0; t < T_ - 1; ++t) {
    hipLaunchKernelGGL(attn_k, dim3(B_), dim3(1024), 0, stream,
                       out, tgt, q, proj, va, src, enc_out, dec_emb, predin, t);

    RS rs{};
    rs.A1 = predin;
    rs.h0 = hd[t & 1]; rs.h1 = hd[t & 1]; rs.ldh = H_;
    rs.Wih0 = dWih; rs.Wih1 = dWih; rs.Whh0 = dWhh; rs.Whh1 = dWhh;
    rs.bih0 = dbih; rs.bih1 = dbih; rs.bhh0 = dbhh; rs.bhh1 = dbhh;
    rs.d0 = hd[(t + 1) & 1]; rs.d1 = hd[(t + 1) & 1]; rs.ldd = H_;
    rs.predin = predin;
    hipLaunchKernelGGL((rnnstep_k<1>), dim3(32, 8, 1), dim3(256), 0, stream, rs);

    GB pr = Z, qa = Z;
    pr.A = predin; pr.lda = 3584; pr.W = Wfc; pr.ldw = 3584; pr.bias = bfc;
    pr.C = out + (size_t)t * V_; pr.ldc = (T_ - 1) * V_;
    pr.M = B_; pr.N = V_; pr.K = 3584;
    qa.A = hd[(t + 1) & 1]; qa.lda = H_; qa.W = Wa; qa.ldw = 3 * H_;
    qa.C = q; qa.ldc = H_; qa.M = B_; qa.N = H_; qa.K = H_;
    hipLaunchKernelGGL((gemm_k<0, 0>), dim3(16, 4, 2), dim3(256), 0, stream, pr, qa);
  }
}

// Round 7
// 30536.752 us; speedup vs baseline: 1.5215x; 1.1029x over previous
//
#include <hip/hip_runtime.h>
#include <hip/hip_fp16.h>
#include <cstdint>
#include <cstddef>

#define B_  256
#define S_  96
#define T_  40
#define V_  256
#define E_  512
#define H_  1024
#define C_  128

__device__ __forceinline__ float sigmoidf_(float x) { return 1.0f / (1.0f + expf(-x)); }

// =================== fused RNN step (pipelined): gi-GEMM + gh-GEMM + GRU gate ===========
// Unified k-loop over [K1 input | H hidden] with register->LDS double buffering.
// DEC=0 (encoder): dir = blockIdx.z. Phase1 K=512, A = enc_emb[src[m,goff]].
//                  h double-buffered through enc_out slices.
// DEC=1 (decoder): Phase1 K=2560, A = k-permuted predin ([emb|ctx] view).
//                  h ping-pong + predin[h2] write.
struct RS {
  const float* A1;                       // enc_emb (ENC) / predin (DEC)
  const int* gidx; int goff0, goff1;     // ENC gather (per dir)
  const float* h0; const float* h1; int ldh;
  const float* Wih0; const float* Wih1;  // [3H][K1]
  const float* Whh0; const float* Whh1;  // [3H][H]
  const float* bih0; const float* bih1;
  const float* bhh0; const float* bhh1;
  float* d0; float* d1; int ldd;
  float* predin;                         // DEC only
};

template<int DEC>
__global__ __launch_bounds__(256)
void rnnstep_k(RS g)
{
  constexpr int K1 = DEC ? 2560 : E_;
  constexpr int TM = DEC ? 32 : 64;      // batch-tile
  constexpr int RM = TM / 16;            // rows per thread
  constexpr int NA = TM / 32;            // float4 A-stages per thread
  constexpr int NT = (K1 + H_) / 32;     // total k-tiles
  const int dir = DEC ? 0 : blockIdx.z;
  const int m0 = blockIdx.y * TM, q0 = blockIdx.x * 32;
  __shared__ float As[32][TM + 4];
  __shared__ float Ws[3][32][36];
  __shared__ int rows[TM];
  const int tid = threadIdx.x;
  const int tx = tid & 15, ty = tid >> 4;
  const int wrow = tid >> 3, wkp = (tid & 7) << 2;
  const float* Wih = dir ? g.Wih1 : g.Wih0;
  const float* Whh = dir ? g.Whh1 : g.Whh0;
  const float* hsrc = dir ? g.h1 : g.h0;

  if (!DEC) {
    if (tid < TM)
      rows[tid] = g.gidx[(size_t)(m0 + tid) * S_ + (dir ? g.goff1 : g.goff0)];
    __syncthreads();
  }

  float ar[RM][2] = {}, az[RM][2] = {}, anI[RM][2] = {}, anH[RM][2] = {};
  float4 av[NA], wv[3], av2[NA], wv2[3];

  // ---- tile loader (kb = global k base of tile) ----
  auto load_tile = [&](int kb, float4 (&AV)[NA], float4 (&WV)[3]) {
    if (kb < K1) {
#pragma unroll
      for (int i = 0; i < NA; ++i) {
        const int f = tid + i * 256;
        const int arow = f >> 3, kk = kb + ((f & 7) << 2);
        if (!DEC) {
          AV[i] = *(const float4*)(g.A1 + (size_t)rows[arow] * E_ + kk);
        } else {
          const int off = (kk < 512) ? (3072 + kk) : (512 + kk);
          AV[i] = *(const float4*)(g.A1 + (size_t)(m0 + arow) * 3584 + off);
        }
      }
#pragma unroll
      for (int th = 0; th < 3; ++th)
        WV[th] = *(const float4*)(Wih + (size_t)(th * H_ + q0 + wrow) * K1 + kb + wkp);
    } else {
      const int kb2 = kb - K1;
#pragma unroll
      for (int i = 0; i < NA; ++i) {
        const int f = tid + i * 256;
        const int arow = f >> 3, kk = kb2 + ((f & 7) << 2);
        AV[i] = *(const float4*)(hsrc + (size_t)(m0 + arow) * g.ldh + kk);
      }
#pragma unroll
      for (int th = 0; th < 3; ++th)
        WV[th] = *(const float4*)(Whh + (size_t)(th * H_ + q0 + wrow) * H_ + kb2 + wkp);
    }
  };

  auto compute_tile = [&](float (&an)[RM][2]) {
#pragma unroll
    for (int k = 0; k < 32; ++k) {
      float am[RM];
      if constexpr (TM == 64) {
        const float4 a4 = *(const float4*)&As[k][ty << 2];
        am[0] = a4.x; am[1] = a4.y; am[2] = a4.z; am[3] = a4.w;
      } else {
        const float2 a2 = *(const float2*)&As[k][ty << 1];
        am[0] = a2.x; am[1] = a2.y;
      }
      const float2 wr = *(const float2*)&Ws[0][k][tx << 1];
      const float2 wz = *(const float2*)&Ws[1][k][tx << 1];
      const float2 wn = *(const float2*)&Ws[2][k][tx << 1];
#pragma unroll
      for (int i = 0; i < RM; ++i) {
        ar[i][0] += am[i] * wr.x; ar[i][1] += am[i] * wr.y;
        az[i][0] += am[i] * wz.x; az[i][1] += am[i] * wz.y;
        an[i][0] += am[i] * wn.x; an[i][1] += am[i] * wn.y;
      }
    }
  };

  load_tile(0, av, wv);
  for (int kt = 0; kt < NT; ++kt) {
    __syncthreads();
#pragma unroll
    for (int i = 0; i < NA; ++i) {
      const int f = tid + i * 256;
      const int arow = f >> 3, kp = (f & 7) << 2;
      As[kp + 0][arow] = av[i].x; As[kp + 1][arow] = av[i].y;
      As[kp + 2][arow] = av[i].z; As[kp + 3][arow] = av[i].w;
    }
#pragma unroll
    for (int th = 0; th < 3; ++th) {
      Ws[th][wkp + 0][wrow] = wv[th].x; Ws[th][wkp + 1][wrow] = wv[th].y;
      Ws[th][wkp + 2][wrow] = wv[th].z; Ws[th][wkp + 3][wrow] = wv[th].w;
    }
    __syncthreads();
    if (kt + 1 < NT) load_tile((kt + 1) * 32, av2, wv2);
    if (kt * 32 < K1) compute_tile(anI); else compute_tile(anH);
#pragma unroll
    for (int i = 0; i < NA; ++i) av[i] = av2[i];
#pragma unroll
    for (int th = 0; th < 3; ++th) wv[th] = wv2[th];
  }

  // ---------- gate epilogue ----------
  const float* bih = dir ? g.bih1 : g.bih0;
  const float* bhh = dir ? g.bhh1 : g.bhh0;
  float* dst = dir ? g.d1 : g.d0;
  const int qq = q0 + (tx << 1);
  const float2 bir = *(const float2*)(bih + qq);
  const float2 biz = *(const float2*)(bih + H_ + qq);
  const float2 bin = *(const float2*)(bih + 2 * H_ + qq);
  const float2 bhr = *(const float2*)(bhh + qq);
  const float2 bhz = *(const float2*)(bhh + H_ + qq);
  const float2 bhn = *(const float2*)(bhh + 2 * H_ + qq);
#pragma unroll
  for (int i = 0; i < RM; ++i) {
    const int b = m0 + ty * RM + i;
    const float2 hold = *(const float2*)(hsrc + (size_t)b * g.ldh + qq);
    float2 hv;
    float r = sigmoidf_(ar[i][0] + bir.x + bhr.x);
    float z = sigmoidf_(az[i][0] + biz.x + bhz.x);
    float n = tanhf(anI[i][0] + bin.x + r * (anH[i][0] + bhn.x));
    hv.x = (1.f - z) * n + z * hold.x;
    r = sigmoidf_(ar[i][1] + bir.y + bhr.y);
    z = sigmoidf_(az[i][1] + biz.y + bhz.y);
    n = tanhf(anI[i][1] + bin.y + r * (anH[i][1] + bhn.y));
    hv.y = (1.f - z) * n + z * hold.y;
    *(float2*)(dst + (size_t)b * g.ldd + qq) = hv;
    if (DEC) *(float2*)(g.predin + (size_t)b * 3584 + qq) = hv;
  }
}

// =================== generic fp32 tiled GEMM (pipelined, 64x64, k-tile 32) ==============
// AMODE: 0 plain, 2 cond concat [hf|hb|modeE|tenseE|personE] (K=2432)
// CMODE: 0 f32 (optional tanh), 1 fp16
struct GB {
  const float* A; int lda;
  const float* W; int ldw;
  const float* bias;
  float* C; int ldc;
  __half* Ch;
  int M, N, K, act;
  const float *hf, *hb; int ldh;
  const float *mE, *tE, *pE;
  const int *mi, *ti, *pi;
};

template<int AMODE, int CMODE>
__global__ __launch_bounds__(256)
void gemm_k(GB g0, GB g1)
{
  GB g = blockIdx.z ? g1 : g0;
  const int m0 = blockIdx.y * 64, n0 = blockIdx.x * 64;
  if (m0 >= g.M || n0 >= g.N) return;
  __shared__ float As[32][68];
  __shared__ float Ws[32][68];
  const int tid = threadIdx.x, tx = tid & 15, ty = tid >> 4;
  const int lm = tid >> 3, lk = (tid & 7) << 2;   // 32 rows x 32 k halves via 2 chunks
  float acc[4][4] = {};
  float4 av[2], wv[2], av2[2], wv2[2];

  auto load_tile = [&](int k0, float4 (&AV)[2], float4 (&WV)[2]) {
#pragma unroll
    for (int i = 0; i < 2; ++i) {
      const int row = lm + i * 32;
      const int kk = k0 + lk;
      if (AMODE == 0) {
        AV[i] = *(const float4*)(g.A + (size_t)(m0 + row) * g.lda + kk);
      } else {
        const int mg = m0 + row; const float* sp; size_t o;
        if (kk < 1024)      { sp = g.hf; o = (size_t)mg * g.ldh + kk; }
        else if (kk < 2048) { sp = g.hb; o = (size_t)mg * g.ldh + kk - 1024; }
        else if (kk < 2176) { sp = g.mE; o = (size_t)g.mi[mg] * C_ + kk - 2048; }
        else if (kk < 2304) { sp = g.tE; o = (size_t)g.ti[mg] * C_ + kk - 2176; }
        else                { sp = g.pE; o = (size_t)g.pi[mg] * C_ + kk - 2304; }
        AV[i] = *(const float4*)(sp + o);
      }
      WV[i] = *(const float4*)(g.W + (size_t)(n0 + row) * g.ldw + kk);
    }
  };

  load_tile(0, av, wv);
  for (int k0 = 0; k0 < g.K; k0 += 32) {
    __syncthreads();
#pragma unroll
    for (int i = 0; i < 2; ++i) {
      const int row = lm + i * 32;
      As[lk + 0][row] = av[i].x; As[lk + 1][row] = av[i].y;
      As[lk + 2][row] = av[i].z; As[lk + 3][row] = av[i].w;
      Ws[lk + 0][row] = wv[i].x; Ws[lk + 1][row] = wv[i].y;
      Ws[lk + 2][row] = wv[i].z; Ws[lk + 3][row] = wv[i].w;
    }
    __syncthreads();
    if (k0 + 32 < g.K) load_tile(k0 + 32, av2, wv2);
#pragma unroll
    for (int k = 0; k < 32; ++k) {
      const float4 a4 = *(const float4*)&As[k][ty << 2];
      const float4 b4 = *(const float4*)&Ws[k][tx << 2];
      acc[0][0] += a4.x * b4.x; acc[0][1] += a4.x * b4.y; acc[0][2] += a4.x * b4.z; acc[0][3] += a4.x * b4.w;
      acc[1][0] += a4.y * b4.x; acc[1][1] += a4.y * b4.y; acc[1][2] += a4.y * b4.z; acc[1][3] += a4.y * b4.w;
      acc[2][0] += a4.z * b4.x; acc[2][1] += a4.z * b4.y; acc[2][2] += a4.z * b4.z; acc[2][3] += a4.z * b4.w;
      acc[3][0] += a4.w * b4.x; acc[3][1] += a4.w * b4.y; acc[3][2] += a4.w * b4.z; acc[3][3] += a4.w * b4.w;
    }
#pragma unroll
    for (int i = 0; i < 2; ++i) { av[i] = av2[i]; wv[i] = wv2[i]; }
  }
  const int n = n0 + (tx << 2);
  float4 bb = make_float4(0.f, 0.f, 0.f, 0.f);
  if (g.bias) bb = *(const float4*)(g.bias + n);
#pragma unroll
  for (int i = 0; i < 4; ++i) {
    const int m = m0 + (ty << 2) + i;
    float4 v = make_float4(acc[i][0] + bb.x, acc[i][1] + bb.y, acc[i][2] + bb.z, acc[i][3] + bb.w);
    if (CMODE == 0) {
      if (g.act) { v.x = tanhf(v.x); v.y = tanhf(v.y); v.z = tanhf(v.z); v.w = tanhf(v.w); }
      *(float4*)(g.C + (size_t)m * g.ldc + n) = v;
    } else {
      __half2* cp = (__half2*)(g.Ch + (size_t)m * g.ldc + n);
      cp[0] = __floats2half2_rn(v.x, v.y);
      cp[1] = __floats2half2_rn(v.z, v.w);
    }
  }
}

// =================== fused decoder attention step ===================
// grid (2, B): blockIdx.y = batch row, blockIdx.x = d-half for ctx.
__global__ __launch_bounds__(1024)
void attn_k(const float* __restrict__ out, const int* __restrict__ tgt,
            const float* __restrict__ q, const __half* __restrict__ proj,
            const float* __restrict__ va, const int* __restrict__ src,
            const float* __restrict__ enc_out, const float* __restrict__ dec_emb,
            float* __restrict__ predin, int t)
{
  const int b = blockIdx.y, tid = threadIdx.x;
  const int lane = tid & 63, wv = tid >> 6;
  __shared__ float sm[128];
  __shared__ float tr[128];
  __shared__ float rv[4];
  __shared__ int ri[4];
  __shared__ int tok_s;
  if (t == 0) {
    if (tid == 0) tok_s = tgt[(size_t)b * T_];
  } else {
    if (tid < 256) {
      float av = out[((size_t)b * (T_ - 1) + (t - 1)) * V_ + tid];
      int ai = tid;
      for (int off = 32; off; off >>= 1) {
        const float ov = __shfl_down(av, off);
        const int   oi = __shfl_down(ai, off);
        if (ov > av) { av = ov; ai = oi; }   // strict >: first-max semantics
      }
      if (lane == 0) { rv[wv] = av; ri[wv] = ai; }
    }
    __syncthreads();
    if (tid == 0) {
      float bv = rv[0]; int bi = ri[0];
      for (int w = 1; w < 4; ++w) if (rv[w] > bv) { bv = rv[w]; bi = ri[w]; }
      tok_s = bi;
    }
  }
  __syncthreads();
  const int tok = tok_s;
  if (blockIdx.x == 0 && tid < E_)
    predin[(size_t)b * 3584 + 3072 + tid] = dec_emb[(size_t)tok * E_ + tid];
  // scores: wave wv owns s = wv*6 .. wv*6+5
  const float* qb = q + (size_t)b * H_;
  for (int s = wv * 6; s < wv * 6 + 6; ++s) {
    float part = 0.f;
#pragma unroll
    for (int jj = 0; jj < 16; ++jj) {
      const int h = lane + jj * 64;
      part += va[h] * tanhf(qb[h] + __half2float(proj[((size_t)b * S_ + s) * H_ + h]));
    }
    for (int off = 32; off; off >>= 1) part += __shfl_down(part, off);
    if (lane == 0)
      sm[s] = (src[(size_t)b * S_ + s] == 0) ? -1.0e9f : part;
  }
  __syncthreads();
  // softmax over 96
  if (tid < 128) tr[tid] = (tid < S_) ? sm[tid] : -3.0e38f;
  __syncthreads();
  for (int s2 = 64; s2 > 0; s2 >>= 1) { if (tid < s2) tr[tid] = fmaxf(tr[tid], tr[tid + s2]); __syncthreads(); }
  const float mx = tr[0];
  __syncthreads();
  if (tid < 128) tr[tid] = (tid < S_) ? expf(sm[tid] - mx) : 0.f;
  __syncthreads();
  for (int s2 = 64; s2 > 0; s2 >>= 1) { if (tid < s2) tr[tid] += tr[tid + s2]; __syncthreads(); }
  const float inv = 1.0f / tr[0];
  __syncthreads();
  if (tid < S_) sm[tid] = expf(sm[tid] - mx) * inv;
  __syncthreads();
  // ctx: this block covers dims [blockIdx.x*1024, +1024), 1 dim/thread, s unrolled x8
  const int d = blockIdx.x * 1024 + tid;
  const float* eb = enc_out + (size_t)b * S_ * 2 * H_ + d;
  float acc = 0.f;
  for (int s0 = 0; s0 < S_; s0 += 8) {
    float v[8];
#pragma unroll
    for (int i = 0; i < 8; ++i) v[i] = eb[(size_t)(s0 + i) * (2 * H_)];
#pragma unroll
    for (int i = 0; i < 8; ++i) acc += sm[s0 + i] * v[i];
  }
  predin[(size_t)b * 3584 + H_ + d] = acc;
}

// =================== misc ===================
__global__ void zero_k(float* __restrict__ p, int n)
{
  const int i = blockIdx.x * 256 + threadIdx.x;
  if (i < n) p[i] = 0.0f;
}

__global__ void sentinel_k(float* out, float v) { out[threadIdx.x] = v; }

// =================== host orchestration ===================
extern "C" void kernel_launch(void* const* d_in, const int* in_sizes, int n_in,
                              void* d_out, int out_size, void* d_ws, size_t ws_size,
                              hipStream_t stream)
{
  const int*   src        = (const int*)d_in[0];
  const int*   tgt        = (const int*)d_in[1];
  const int*   mode_idx   = (const int*)d_in[2];
  const int*   tense_idx  = (const int*)d_in[3];
  const int*   person_idx = (const int*)d_in[4];
  const float* enc_emb    = (const float*)d_in[5];
  const float* eWih_f     = (const float*)d_in[6];
  const float* eWhh_f     = (const float*)d_in[7];
  const float* ebih_f     = (const float*)d_in[8];
  const float* ebhh_f     = (const float*)d_in[9];
  const float* eWih_b     = (const float*)d_in[10];
  const float* eWhh_b     = (const float*)d_in[11];
  const float* ebih_b     = (const float*)d_in[12];
  const float* ebhh_b     = (const float*)d_in[13];
  const float* Wa         = (const float*)d_in[14];
  const float* va         = (const float*)d_in[15];
  const float* dec_emb    = (const float*)d_in[16];
  const float* dWih       = (const float*)d_in[17];
  const float* dWhh       = (const float*)d_in[18];
  const float* dbih       = (const float*)d_in[19];
  const float* dbhh       = (const float*)d_in[20];
  const float* Wfc        = (const float*)d_in[21];
  const float* bfc        = (const float*)d_in[22];
  const float* mode_E     = (const float*)d_in[23];
  const float* tense_E    = (const float*)d_in[24];
  const float* person_E   = (const float*)d_in[25];
  const float* Wbr        = (const float*)d_in[26];
  const float* bbr        = (const float*)d_in[27];
  float* out = (float*)d_out;

  // ---- workspace carve (~258 MB; proven budget >= 268 MB) ----
  char* base = (char*)d_ws;
  size_t off = 0;
  auto alloc = [&](size_t bytes) { char* r = base + off; off = (off + bytes + 255) & ~(size_t)255; return r; };
  float*  enc_out  = (float*)alloc(4ull * B_ * S_ * 2 * H_);   // 201.3 MB (doubles as enc h state)
  __half* proj     = (__half*)alloc(2ull * B_ * S_ * H_);      // 50.3 MB
  float*  h_d0     = (float*)alloc(4ull * B_ * H_);
  float*  h_d1     = (float*)alloc(4ull * B_ * H_);
  float*  q        = (float*)alloc(4ull * B_ * H_);
  float*  predin   = (float*)alloc(4ull * B_ * 3584);          // [h2|ctx|emb]
  float*  zero_buf = (float*)alloc(4ull * 1024);
  if (off > ws_size) {
    hipLaunchKernelGGL(sentinel_k, dim3(1), dim3(256), 0, stream, out,
                       1000.0f + (float)(ws_size >> 20));
    return;
  }

  hipLaunchKernelGGL(zero_k, dim3(4), dim3(256), 0, stream, zero_buf, 1024);

  // ---- encoder: 96 fused pipelined steps ----
  for (int t = 0; t < S_; ++t) {
    RS rs{};
    rs.A1 = enc_emb; rs.gidx = src; rs.goff0 = t; rs.goff1 = S_ - 1 - t;
    if (t == 0) { rs.h0 = zero_buf; rs.h1 = zero_buf; rs.ldh = 0; }
    else {
      rs.h0 = enc_out + (size_t)(t - 1) * 2 * H_;
      rs.h1 = enc_out + (size_t)(S_ - t) * 2 * H_ + H_;
      rs.ldh = S_ * 2 * H_;
    }
    rs.Wih0 = eWih_f; rs.Wih1 = eWih_b; rs.Whh0 = eWhh_f; rs.Whh1 = eWhh_b;
    rs.bih0 = ebih_f; rs.bih1 = ebih_b; rs.bhh0 = ebhh_f; rs.bhh1 = ebhh_b;
    rs.d0 = enc_out + (size_t)t * 2 * H_;
    rs.d1 = enc_out + (size_t)(S_ - 1 - t) * 2 * H_ + H_;
    rs.ldd = S_ * 2 * H_;
    hipLaunchKernelGGL((rnnstep_k<0>), dim3(32, 4, 2), dim3(256), 0, stream, rs);
  }

  GB Z{};

  // ---- enc_proj (fp16 out) ----
  {
    GB ep = Z;
    ep.A = enc_out; ep.lda = 2 * H_; ep.W = Wa + H_; ep.ldw = 3 * H_;
    ep.Ch = proj; ep.ldc = H_; ep.M = B_ * S_; ep.N = H_; ep.K = 2 * H_;
    hipLaunchKernelGGL((gemm_k<0, 1>), dim3(16, 384, 1), dim3(256), 0, stream, ep, ep);
  }

  // ---- dec_h0 = tanh(cond @ Wbr.T + bbr) ----
  {
    GB br = Z;
    br.W = Wbr; br.ldw = 2432; br.bias = bbr; br.C = h_d0; br.ldc = H_;
    br.M = B_; br.N = H_; br.K = 2432; br.act = 1;
    br.hf = enc_out + (size_t)(S_ - 1) * 2 * H_; br.hb = enc_out + H_; br.ldh = S_ * 2 * H_;
    br.mE = mode_E; br.tE = tense_E; br.pE = person_E;
    br.mi = mode_idx; br.ti = tense_idx; br.pi = person_idx;
    hipLaunchKernelGGL((gemm_k<2, 0>), dim3(16, 4, 1), dim3(256), 0, stream, br, br);
  }

  // ---- q(0) ----
  {
    GB qa = Z;
    qa.A = h_d0; qa.lda = H_; qa.W = Wa; qa.ldw = 3 * H_; qa.C = q; qa.ldc = H_;
    qa.M = B_; qa.N = H_; qa.K = H_;
    hipLaunchKernelGGL((gemm_k<0, 0>), dim3(16, 4, 1), dim3(256), 0, stream, qa, qa);
  }

  // ---- decoder: 39 steps x (attn, fused gia+gh+gate, pred+qa) ----
  float* hd[2] = { h_d0, h_d1 };
  for (int t = 0; t < T_ - 1; ++t) {
    hipLaunchKernelGGL(attn_k, dim3(2, B_), dim3(1024), 0, stream,
                       out, tgt, q, proj, va, src, enc_out, dec_emb, predin, t);

    RS rs{};
    rs.A1 = predin;
    rs.h0 = hd[t & 1]; rs.h1 = hd[t & 1]; rs.ldh = H_;
    rs.Wih0 = dWih; rs.Wih1 = dWih; rs.Whh0 = dWhh; rs.Whh1 = dWhh;
    rs.bih0 = dbih; rs.bih1 = dbih; rs.bhh0 = dbhh; rs.bhh1 = dbhh;
    rs.d0 = hd[(t + 1) & 1]; rs.d1 = hd[(t + 1) & 1]; rs.ldd = H_;
    rs.predin = predin;
    hipLaunchKernelGGL((rnnstep_k<1>), dim3(32, 8, 1), dim3(256), 0, stream, rs);

    GB pr = Z, qa = Z;
    pr.A = predin; pr.lda = 3584; pr.W = Wfc; pr.ldw = 3584; pr.bias = bfc;
    pr.C = out + (size_t)t * V_; pr.ldc = (T_ - 1) * V_;
    pr.M = B_; pr.N = V_; pr.K = 3584;
    qa.A = hd[(t + 1) & 1]; qa.lda = H_; qa.W = Wa; qa.ldw = 3 * H_;
    qa.C = q; qa.ldc = H_; qa.M = B_; qa.N = H_; qa.K = H_;
    hipLaunchKernelGGL((gemm_k<0, 0>), dim3(16, 4, 2), dim3(256), 0, stream, pr, qa);
  }
}

// Round 8
// 27638.010 us; speedup vs baseline: 1.6811x; 1.1049x over previous
//
#include <hip/hip_runtime.h>
#include <hip/hip_fp16.h>
#include <cstdint>
#include <cstddef>

#define B_  256
#define S_  96
#define T_  40
#define V_  256
#define E_  512
#define H_  1024
#define C_  128

__device__ __forceinline__ float sigmoidf_(float x) { return 1.0f / (1.0f + expf(-x)); }

// =================== fused RNN step (pipelined + XCD-swizzled) ===================
// Unified k-loop over [K1 input | H hidden], register->LDS double buffer.
// ENC: dirs via decode. h recurrence in f32 ping-pong bufs; enc_out written fp16.
// DEC: predin k-permuted input; h f32 ping-pong + predin[h2] write.
struct RS {
  const float* A1;                       // enc_emb (ENC) / predin (DEC)
  const int* gidx; int goff0, goff1;     // ENC gather (per dir)
  const float* h0; const float* h1; int ldh;   // f32 h sources (ldh=0 -> zeros)
  const float* Wih0; const float* Wih1;  // [3H][K1]
  const float* Whh0; const float* Whh1;  // [3H][H]
  const float* bih0; const float* bih1;
  const float* bhh0; const float* bhh1;
  float* d0; float* d1; int ldd;         // f32 h dst
  __half* e0; __half* e1; int lde;       // ENC: fp16 enc_out slices (dir offset in base)
  float* predin;                         // DEC only
};

template<int DEC>
__global__ __launch_bounds__(256)
void rnnstep_k(RS g)
{
  constexpr int K1 = DEC ? 2560 : E_;
  constexpr int TM = DEC ? 32 : 64;      // batch-tile
  constexpr int RM = TM / 16;            // rows per thread
  constexpr int NA = TM / 32;            // float4 A-stages per thread
  constexpr int NT = (K1 + H_) / 32;     // k-tiles
  constexpr int NM = DEC ? 8 : 4;        // m-blocks
  constexpr int ND = DEC ? 1 : 2;        // dirs
  // XCD-chunked swizzle: m fastest, then dir, then q -> all m-blocks sharing a
  // weight slice land on one XCD (weight slice served from that XCD's L2).
  const int nblk = 32 * NM * ND, per = nblk >> 3;
  const int fid = (blockIdx.x & 7) * per + (blockIdx.x >> 3);
  const int m = fid % NM;
  const int r_ = fid / NM;
  const int dir = r_ % ND;
  const int q0 = (r_ / ND) * 32;
  const int m0 = m * TM;

  __shared__ float As[32][TM + 4];
  __shared__ float Ws[3][32][36];
  __shared__ int rows[TM];
  const int tid = threadIdx.x;
  const int tx = tid & 15, ty = tid >> 4;
  const int wrow = tid >> 3, wkp = (tid & 7) << 2;
  const float* Wih = dir ? g.Wih1 : g.Wih0;
  const float* Whh = dir ? g.Whh1 : g.Whh0;
  const float* hsrc = dir ? g.h1 : g.h0;

  if (!DEC) {
    if (tid < TM)
      rows[tid] = g.gidx[(size_t)(m0 + tid) * S_ + (dir ? g.goff1 : g.goff0)];
    __syncthreads();
  }

  float ar[RM][2] = {}, az[RM][2] = {}, anI[RM][2] = {}, anH[RM][2] = {};
  float4 av[NA], wv[3], av2[NA], wv2[3];

  auto load_tile = [&](int kb, float4 (&AV)[NA], float4 (&WV)[3]) {
    if (kb < K1) {
#pragma unroll
      for (int i = 0; i < NA; ++i) {
        const int f = tid + i * 256;
        const int arow = f >> 3, kk = kb + ((f & 7) << 2);
        if (!DEC) {
          AV[i] = *(const float4*)(g.A1 + (size_t)rows[arow] * E_ + kk);
        } else {
          const int off = (kk < 512) ? (3072 + kk) : (512 + kk);
          AV[i] = *(const float4*)(g.A1 + (size_t)(m0 + arow) * 3584 + off);
        }
      }
#pragma unroll
      for (int th = 0; th < 3; ++th)
        WV[th] = *(const float4*)(Wih + (size_t)(th * H_ + q0 + wrow) * K1 + kb + wkp);
    } else {
      const int kb2 = kb - K1;
#pragma unroll
      for (int i = 0; i < NA; ++i) {
        const int f = tid + i * 256;
        const int arow = f >> 3, kk = kb2 + ((f & 7) << 2);
        AV[i] = *(const float4*)(hsrc + (size_t)(m0 + arow) * g.ldh + kk);
      }
#pragma unroll
      for (int th = 0; th < 3; ++th)
        WV[th] = *(const float4*)(Whh + (size_t)(th * H_ + q0 + wrow) * H_ + kb2 + wkp);
    }
  };

  auto compute_tile = [&](float (&an)[RM][2]) {
#pragma unroll
    for (int k = 0; k < 32; ++k) {
      float am[RM];
      if constexpr (TM == 64) {
        const float4 a4 = *(const float4*)&As[k][ty << 2];
        am[0] = a4.x; am[1] = a4.y; am[2] = a4.z; am[3] = a4.w;
      } else {
        const float2 a2 = *(const float2*)&As[k][ty << 1];
        am[0] = a2.x; am[1] = a2.y;
      }
      const float2 wr = *(const float2*)&Ws[0][k][tx << 1];
      const float2 wz = *(const float2*)&Ws[1][k][tx << 1];
      const float2 wn = *(const float2*)&Ws[2][k][tx << 1];
#pragma unroll
      for (int i = 0; i < RM; ++i) {
        ar[i][0] += am[i] * wr.x; ar[i][1] += am[i] * wr.y;
        az[i][0] += am[i] * wz.x; az[i][1] += am[i] * wz.y;
        an[i][0] += am[i] * wn.x; an[i][1] += am[i] * wn.y;
      }
    }
  };

  load_tile(0, av, wv);
  for (int kt = 0; kt < NT; ++kt) {
    __syncthreads();
#pragma unroll
    for (int i = 0; i < NA; ++i) {
      const int f = tid + i * 256;
      const int arow = f >> 3, kp = (f & 7) << 2;
      As[kp + 0][arow] = av[i].x; As[kp + 1][arow] = av[i].y;
      As[kp + 2][arow] = av[i].z; As[kp + 3][arow] = av[i].w;
    }
#pragma unroll
    for (int th = 0; th < 3; ++th) {
      Ws[th][wkp + 0][wrow] = wv[th].x; Ws[th][wkp + 1][wrow] = wv[th].y;
      Ws[th][wkp + 2][wrow] = wv[th].z; Ws[th][wkp + 3][wrow] = wv[th].w;
    }
    __syncthreads();
    if (kt + 1 < NT) load_tile((kt + 1) * 32, av2, wv2);
    if (kt * 32 < K1) compute_tile(anI); else compute_tile(anH);
#pragma unroll
    for (int i = 0; i < NA; ++i) av[i] = av2[i];
#pragma unroll
    for (int th = 0; th < 3; ++th) wv[th] = wv2[th];
  }

  // ---------- gate epilogue ----------
  const float* bih = dir ? g.bih1 : g.bih0;
  const float* bhh = dir ? g.bhh1 : g.bhh0;
  float* dst = dir ? g.d1 : g.d0;
  const int qq = q0 + (tx << 1);
  const float2 bir = *(const float2*)(bih + qq);
  const float2 biz = *(const float2*)(bih + H_ + qq);
  const float2 bin = *(const float2*)(bih + 2 * H_ + qq);
  const float2 bhr = *(const float2*)(bhh + qq);
  const float2 bhz = *(const float2*)(bhh + H_ + qq);
  const float2 bhn = *(const float2*)(bhh + 2 * H_ + qq);
#pragma unroll
  for (int i = 0; i < RM; ++i) {
    const int b = m0 + ty * RM + i;
    const float2 hold = *(const float2*)(hsrc + (size_t)b * g.ldh + qq);
    float2 hv;
    float r = sigmoidf_(ar[i][0] + bir.x + bhr.x);
    float z = sigmoidf_(az[i][0] + biz.x + bhz.x);
    float n = tanhf(anI[i][0] + bin.x + r * (anH[i][0] + bhn.x));
    hv.x = (1.f - z) * n + z * hold.x;
    r = sigmoidf_(ar[i][1] + bir.y + bhr.y);
    z = sigmoidf_(az[i][1] + biz.y + bhz.y);
    n = tanhf(anI[i][1] + bin.y + r * (anH[i][1] + bhn.y));
    hv.y = (1.f - z) * n + z * hold.y;
    *(float2*)(dst + (size_t)b * g.ldd + qq) = hv;
    if (!DEC) {
      __half* edst = dir ? g.e1 : g.e0;
      *(__half2*)(edst + (size_t)b * g.lde + qq) = __floats2half2_rn(hv.x, hv.y);
    } else {
      *(float2*)(g.predin + (size_t)b * 3584 + qq) = hv;
    }
  }
}

// =================== generic fp32 tiled GEMM (pipelined, 64x64, k-tile 32) ==============
// AMODE: 0 plain f32, 2 cond concat [hf|hb|modeE|tenseE|personE] (K=2432), 4 plain fp16
// CMODE: 0 f32 (optional tanh), 1 fp16
struct GB {
  const float* A; int lda;
  const __half* Ah;
  const float* W; int ldw;
  const float* bias;
  float* C; int ldc;
  __half* Ch;
  int M, N, K, act;
  const float *hf, *hb; int ldh;
  const float *mE, *tE, *pE;
  const int *mi, *ti, *pi;
};

template<int AMODE, int CMODE>
__global__ __launch_bounds__(256)
void gemm_k(GB g0, GB g1)
{
  GB g = blockIdx.z ? g1 : g0;
  const int m0 = blockIdx.y * 64, n0 = blockIdx.x * 64;
  if (m0 >= g.M || n0 >= g.N) return;
  __shared__ float As[32][68];
  __shared__ float Ws[32][68];
  const int tid = threadIdx.x, tx = tid & 15, ty = tid >> 4;
  const int lm = tid >> 3, lk = (tid & 7) << 2;
  float acc[4][4] = {};
  float4 av[2], wv[2], av2[2], wv2[2];

  auto load_tile = [&](int k0, float4 (&AV)[2], float4 (&WV)[2]) {
#pragma unroll
    for (int i = 0; i < 2; ++i) {
      const int row = lm + i * 32;
      const int kk = k0 + lk;
      if (AMODE == 0) {
        AV[i] = *(const float4*)(g.A + (size_t)(m0 + row) * g.lda + kk);
      } else if (AMODE == 4) {
        const __half* ap = g.Ah + (size_t)(m0 + row) * g.lda + kk;
        const __half2 h0 = *(const __half2*)ap;
        const __half2 h1 = *(const __half2*)(ap + 2);
        AV[i] = make_float4(__half2float(h0.x), __half2float(h0.y),
                            __half2float(h1.x), __half2float(h1.y));
      } else {
        const int mg = m0 + row; const float* sp; size_t o;
        if (kk < 1024)      { sp = g.hf; o = (size_t)mg * g.ldh + kk; }
        else if (kk < 2048) { sp = g.hb; o = (size_t)mg * g.ldh + kk - 1024; }
        else if (kk < 2176) { sp = g.mE; o = (size_t)g.mi[mg] * C_ + kk - 2048; }
        else if (kk < 2304) { sp = g.tE; o = (size_t)g.ti[mg] * C_ + kk - 2176; }
        else                { sp = g.pE; o = (size_t)g.pi[mg] * C_ + kk - 2304; }
        AV[i] = *(const float4*)(sp + o);
      }
      WV[i] = *(const float4*)(g.W + (size_t)(n0 + row) * g.ldw + kk);
    }
  };

  load_tile(0, av, wv);
  for (int k0 = 0; k0 < g.K; k0 += 32) {
    __syncthreads();
#pragma unroll
    for (int i = 0; i < 2; ++i) {
      const int row = lm + i * 32;
      As[lk + 0][row] = av[i].x; As[lk + 1][row] = av[i].y;
      As[lk + 2][row] = av[i].z; As[lk + 3][row] = av[i].w;
      Ws[lk + 0][row] = wv[i].x; Ws[lk + 1][row] = wv[i].y;
      Ws[lk + 2][row] = wv[i].z; Ws[lk + 3][row] = wv[i].w;
    }
    __syncthreads();
    if (k0 + 32 < g.K) load_tile(k0 + 32, av2, wv2);
#pragma unroll
    for (int k = 0; k < 32; ++k) {
      const float4 a4 = *(const float4*)&As[k][ty << 2];
      const float4 b4 = *(const float4*)&Ws[k][tx << 2];
      acc[0][0] += a4.x * b4.x; acc[0][1] += a4.x * b4.y; acc[0][2] += a4.x * b4.z; acc[0][3] += a4.x * b4.w;
      acc[1][0] += a4.y * b4.x; acc[1][1] += a4.y * b4.y; acc[1][2] += a4.y * b4.z; acc[1][3] += a4.y * b4.w;
      acc[2][0] += a4.z * b4.x; acc[2][1] += a4.z * b4.y; acc[2][2] += a4.z * b4.z; acc[2][3] += a4.z * b4.w;
      acc[3][0] += a4.w * b4.x; acc[3][1] += a4.w * b4.y; acc[3][2] += a4.w * b4.z; acc[3][3] += a4.w * b4.w;
    }
#pragma unroll
    for (int i = 0; i < 2; ++i) { av[i] = av2[i]; wv[i] = wv2[i]; }
  }
  const int n = n0 + (tx << 2);
  float4 bb = make_float4(0.f, 0.f, 0.f, 0.f);
  if (g.bias) bb = *(const float4*)(g.bias + n);
#pragma unroll
  for (int i = 0; i < 4; ++i) {
    const int m = m0 + (ty << 2) + i;
    float4 v = make_float4(acc[i][0] + bb.x, acc[i][1] + bb.y, acc[i][2] + bb.z, acc[i][3] + bb.w);
    if (CMODE == 0) {
      if (g.act) { v.x = tanhf(v.x); v.y = tanhf(v.y); v.z = tanhf(v.z); v.w = tanhf(v.w); }
      *(float4*)(g.C + (size_t)m * g.ldc + n) = v;
    } else {
      __half2* cp = (__half2*)(g.Ch + (size_t)m * g.ldc + n);
      cp[0] = __floats2half2_rn(v.x, v.y);
      cp[1] = __floats2half2_rn(v.z, v.w);
    }
  }
}

// =================== fused decoder attention step (fp16 enc_out/proj) ===================
// grid (B_), 1024 thr: argmax -> emb -> scores -> softmax -> ctx.
__global__ __launch_bounds__(1024)
void attn_k(const float* __restrict__ out, const int* __restrict__ tgt,
            const float* __restrict__ q, const __half* __restrict__ proj,
            const float* __restrict__ va, const int* __restrict__ src,
            const __half* __restrict__ enc, const float* __restrict__ dec_emb,
            float* __restrict__ predin, int t)
{
  const int b = blockIdx.x, tid = threadIdx.x;
  const int lane = tid & 63, wv = tid >> 6;
  __shared__ float sm[128];
  __shared__ float tr[128];
  __shared__ float rv[4];
  __shared__ int ri[4];
  __shared__ int tok_s;
  if (t == 0) {
    if (tid == 0) tok_s = tgt[(size_t)b * T_];
  } else {
    if (tid < 256) {
      float av = out[((size_t)b * (T_ - 1) + (t - 1)) * V_ + tid];
      int ai = tid;
      for (int off = 32; off; off >>= 1) {
        const float ov = __shfl_down(av, off);
        const int   oi = __shfl_down(ai, off);
        if (ov > av) { av = ov; ai = oi; }   // strict >: first-max semantics
      }
      if (lane == 0) { rv[wv] = av; ri[wv] = ai; }
    }
    __syncthreads();
    if (tid == 0) {
      float bv = rv[0]; int bi = ri[0];
      for (int w = 1; w < 4; ++w) if (rv[w] > bv) { bv = rv[w]; bi = ri[w]; }
      tok_s = bi;
    }
  }
  __syncthreads();
  const int tok = tok_s;
  if (tid < E_) predin[(size_t)b * 3584 + 3072 + tid] = dec_emb[(size_t)tok * E_ + tid];
  // scores: wave wv owns s = wv*6 .. wv*6+5, half2/float2 vector loads
  const float* qb = q + (size_t)b * H_;
  for (int s = wv * 6; s < wv * 6 + 6; ++s) {
    const __half* pb = proj + ((size_t)b * S_ + s) * H_;
    float part = 0.f;
#pragma unroll
    for (int j = 0; j < 8; ++j) {
      const int h = lane * 2 + j * 128;
      const __half2 p2 = *(const __half2*)(pb + h);
      const float2 q2 = *(const float2*)(qb + h);
      const float2 v2 = *(const float2*)(va + h);
      part += v2.x * tanhf(q2.x + __half2float(p2.x));
      part += v2.y * tanhf(q2.y + __half2float(p2.y));
    }
    for (int off = 32; off; off >>= 1) part += __shfl_down(part, off);
    if (lane == 0)
      sm[s] = (src[(size_t)b * S_ + s] == 0) ? -1.0e9f : part;
  }
  __syncthreads();
  // softmax over 96
  if (tid < 128) tr[tid] = (tid < S_) ? sm[tid] : -3.0e38f;
  __syncthreads();
  for (int s2 = 64; s2 > 0; s2 >>= 1) { if (tid < s2) tr[tid] = fmaxf(tr[tid], tr[tid + s2]); __syncthreads(); }
  const float mx = tr[0];
  __syncthreads();
  if (tid < 128) tr[tid] = (tid < S_) ? expf(sm[tid] - mx) : 0.f;
  __syncthreads();
  for (int s2 = 64; s2 > 0; s2 >>= 1) { if (tid < s2) tr[tid] += tr[tid + s2]; __syncthreads(); }
  const float inv = 1.0f / tr[0];
  __syncthreads();
  if (tid < S_) sm[tid] = expf(sm[tid] - mx) * inv;
  __syncthreads();
  // ctx: 2 consecutive dims/thread, s unrolled x8, half2 loads
  const int d = tid * 2;
  const __half* eb = enc + (size_t)b * S_ * (2 * H_) + d;
  float c0 = 0.f, c1 = 0.f;
  for (int s0 = 0; s0 < S_; s0 += 8) {
    __half2 v[8];
#pragma unroll
    for (int i = 0; i < 8; ++i) v[i] = *(const __half2*)(eb + (size_t)(s0 + i) * (2 * H_));
#pragma unroll
    for (int i = 0; i < 8; ++i) {
      const float w = sm[s0 + i];
      c0 += w * __half2float(v[i].x);
      c1 += w * __half2float(v[i].y);
    }
  }
  *(float2*)(predin + (size_t)b * 3584 + H_ + d) = make_float2(c0, c1);
}

// =================== misc ===================
__global__ void zero_k(float* __restrict__ p, int n)
{
  const int i = blockIdx.x * 256 + threadIdx.x;
  if (i < n) p[i] = 0.0f;
}

__global__ void sentinel_k(float* out, float v) { out[threadIdx.x] = v; }

// =================== host orchestration ===================
extern "C" void kernel_launch(void* const* d_in, const int* in_sizes, int n_in,
                              void* d_out, int out_size, void* d_ws, size_t ws_size,
                              hipStream_t stream)
{
  const int*   src        = (const int*)d_in[0];
  const int*   tgt        = (const int*)d_in[1];
  const int*   mode_idx   = (const int*)d_in[2];
  const int*   tense_idx  = (const int*)d_in[3];
  const int*   person_idx = (const int*)d_in[4];
  const float* enc_emb    = (const float*)d_in[5];
  const float* eWih_f     = (const float*)d_in[6];
  const float* eWhh_f     = (const float*)d_in[7];
  const float* ebih_f     = (const float*)d_in[8];
  const float* ebhh_f     = (const float*)d_in[9];
  const float* eWih_b     = (const float*)d_in[10];
  const float* eWhh_b     = (const float*)d_in[11];
  const float* ebih_b     = (const float*)d_in[12];
  const float* ebhh_b     = (const float*)d_in[13];
  const float* Wa         = (const float*)d_in[14];
  const float* va         = (const float*)d_in[15];
  const float* dec_emb    = (const float*)d_in[16];
  const float* dWih       = (const float*)d_in[17];
  const float* dWhh       = (const float*)d_in[18];
  const float* dbih       = (const float*)d_in[19];
  const float* dbhh       = (const float*)d_in[20];
  const float* Wfc        = (const float*)d_in[21];
  const float* bfc        = (const float*)d_in[22];
  const float* mode_E     = (const float*)d_in[23];
  const float* tense_E    = (const float*)d_in[24];
  const float* person_E   = (const float*)d_in[25];
  const float* Wbr        = (const float*)d_in[26];
  const float* bbr        = (const float*)d_in[27];
  float* out = (float*)d_out;

  // ---- workspace carve (~163 MB) ----
  char* base = (char*)d_ws;
  size_t off = 0;
  auto alloc = [&](size_t bytes) { char* r = base + off; off = (off + bytes + 255) & ~(size_t)255; return r; };
  __half* enc_out = (__half*)alloc(2ull * B_ * S_ * 2 * H_);   // 100.7 MB (fp16)
  __half* proj    = (__half*)alloc(2ull * B_ * S_ * H_);       // 50.3 MB
  float* hfA   = (float*)alloc(4ull * B_ * H_);   // enc fwd h ping-pong (f32)
  float* hfB   = (float*)alloc(4ull * B_ * H_);
  float* hbA   = (float*)alloc(4ull * B_ * H_);   // enc bwd h ping-pong
  float* hbB   = (float*)alloc(4ull * B_ * H_);
  float* h_d0  = (float*)alloc(4ull * B_ * H_);
  float* h_d1  = (float*)alloc(4ull * B_ * H_);
  float* q     = (float*)alloc(4ull * B_ * H_);
  float* predin = (float*)alloc(4ull * B_ * 3584);             // [h2|ctx|emb]
  float* zero_buf = (float*)alloc(4ull * 1024);
  if (off > ws_size) {
    hipLaunchKernelGGL(sentinel_k, dim3(1), dim3(256), 0, stream, out,
                       1000.0f + (float)(ws_size >> 20));
    return;
  }

  hipLaunchKernelGGL(zero_k, dim3(4), dim3(256), 0, stream, zero_buf, 1024);

  // ---- encoder: 96 fused steps (f32 recurrence, fp16 enc_out) ----
  for (int t = 0; t < S_; ++t) {
    RS rs{};
    rs.A1 = enc_emb; rs.gidx = src; rs.goff0 = t; rs.goff1 = S_ - 1 - t;
    if (t == 0) { rs.h0 = zero_buf; rs.h1 = zero_buf; rs.ldh = 0; }
    else if (t & 1) { rs.h0 = hfA; rs.h1 = hbA; rs.ldh = H_; }
    else            { rs.h0 = hfB; rs.h1 = hbB; rs.ldh = H_; }
    rs.Wih0 = eWih_f; rs.Wih1 = eWih_b; rs.Whh0 = eWhh_f; rs.Whh1 = eWhh_b;
    rs.bih0 = ebih_f; rs.bih1 = ebih_b; rs.bhh0 = ebhh_f; rs.bhh1 = ebhh_b;
    if (t & 1) { rs.d0 = hfB; rs.d1 = hbB; } else { rs.d0 = hfA; rs.d1 = hbA; }
    rs.ldd = H_;
    rs.e0 = enc_out + (size_t)t * 2 * H_;
    rs.e1 = enc_out + (size_t)(S_ - 1 - t) * 2 * H_ + H_;
    rs.lde = S_ * 2 * H_;
    hipLaunchKernelGGL((rnnstep_k<0>), dim3(256), dim3(256), 0, stream, rs);
  }
  // final h: t=95 (odd) wrote hfB/hbB
  float* hf_fin = hfB;
  float* hb_fin = hbB;

  GB Z{};

  // ---- enc_proj (fp16 A, fp16 out) ----
  {
    GB ep = Z;
    ep.Ah = enc_out; ep.lda = 2 * H_; ep.W = Wa + H_; ep.ldw = 3 * H_;
    ep.Ch = proj; ep.ldc = H_; ep.M = B_ * S_; ep.N = H_; ep.K = 2 * H_;
    hipLaunchKernelGGL((gemm_k<4, 1>), dim3(16, 384, 1), dim3(256), 0, stream, ep, ep);
  }

  // ---- dec_h0 = tanh(cond @ Wbr.T + bbr) ----
  {
    GB br = Z;
    br.W = Wbr; br.ldw = 2432; br.bias = bbr; br.C = h_d0; br.ldc = H_;
    br.M = B_; br.N = H_; br.K = 2432; br.act = 1;
    br.hf = hf_fin; br.hb = hb_fin; br.ldh = H_;
    br.mE = mode_E; br.tE = tense_E; br.pE = person_E;
    br.mi = mode_idx; br.ti = tense_idx; br.pi = person_idx;
    hipLaunchKernelGGL((gemm_k<2, 0>), dim3(16, 4, 1), dim3(256), 0, stream, br, br);
  }

  // ---- q(0) ----
  {
    GB qa = Z;
    qa.A = h_d0; qa.lda = H_; qa.W = Wa; qa.ldw = 3 * H_; qa.C = q; qa.ldc = H_;
    qa.M = B_; qa.N = H_; qa.K = H_;
    hipLaunchKernelGGL((gemm_k<0, 0>), dim3(16, 4, 1), dim3(256), 0, stream, qa, qa);
  }

  // ---- decoder: 39 steps x (attn, fused gia+gh+gate, pred+qa) ----
  float* hd[2] = { h_d0, h_d1 };
  for (int t = 0; t < T_ - 1; ++t) {
    hipLaunchKernelGGL(attn_k, dim3(B_), dim3(1024), 0, stream,
                       out, tgt, q, proj, va, src, enc_out, dec_emb, predin, t);

    RS rs{};
    rs.A1 = predin;
    rs.h0 = hd[t & 1]; rs.h1 = hd[t & 1]; rs.ldh = H_;
    rs.Wih0 = dWih; rs.Wih1 = dWih; rs.Whh0 = dWhh; rs.Whh1 = dWhh;
    rs.bih0 = dbih; rs.bih1 = dbih; rs.bhh0 = dbhh; rs.bhh1 = dbhh;
    rs.d0 = hd[(t + 1) & 1]; rs.d1 = hd[(t + 1) & 1]; rs.ldd = H_;
    rs.predin = predin;
    hipLaunchKernelGGL((rnnstep_k<1>), dim3(256), dim3(256), 0, stream, rs);

    GB pr = Z, qa = Z;
    pr.A = predin; pr.lda = 3584; pr.W = Wfc; pr.ldw = 3584; pr.bias = bfc;
    pr.C = out + (size_t)t * V_; pr.ldc = (T_ - 1) * V_;
    pr.M = B_; pr.N = V_; pr.K = 3584;
    qa.A = hd[(t + 1) & 1]; qa.lda = H_; qa.W = Wa; qa.ldw = 3 * H_;
    qa.C = q; qa.ldc = H_; qa.M = B_; qa.N = H_; qa.K = H_;
    hipLaunchKernelGGL((gemm_k<0, 0>), dim3(16, 4, 2), dim3(256), 0, stream, pr, qa);
  }
}

// Round 9
// 26950.214 us; speedup vs baseline: 1.7240x; 1.0255x over previous
//
#include <hip/hip_runtime.h>
#include <hip/hip_fp16.h>
#include <cstdint>
#include <cstddef>

#define B_  256
#define S_  96
#define T_  40
#define V_  256
#define E_  512
#define H_  1024
#define C_  128

__device__ __forceinline__ float sigmoidf_(float x) { return 1.0f / (1.0f + expf(-x)); }

// =================== fused RNN step (q-tile 16, 512 blocks, XCD-swizzled) ===============
// Unified k-loop over [K1 input | H hidden], register->LDS double buffer.
// ENC: dir decoded from block id. h recurrence f32 ping-pong; enc_out written fp16.
// DEC: predin k-permuted input; h f32 ping-pong + predin[h2] write.
struct RS {
  const float* A1;                       // enc_emb (ENC) / predin (DEC)
  const int* gidx; int goff0, goff1;     // ENC gather (per dir)
  const float* h0; const float* h1; int ldh;   // f32 h sources (ldh=0 -> zeros)
  const float* Wih0; const float* Wih1;  // [3H][K1]
  const float* Whh0; const float* Whh1;  // [3H][H]
  const float* bih0; const float* bih1;
  const float* bhh0; const float* bhh1;
  float* d0; float* d1; int ldd;         // f32 h dst
  __half* e0; __half* e1; int lde;       // ENC: fp16 enc_out slices
  float* predin;                         // DEC only
};

template<int DEC>
__global__ __launch_bounds__(256)
void rnnstep_k(RS g)
{
  constexpr int K1 = DEC ? 2560 : E_;
  constexpr int TM = DEC ? 32 : 64;      // batch-tile
  constexpr int RM = DEC ? 1 : 2;        // rows per thread (ty spans 32)
  constexpr int NA = TM / 32;            // float4 A-stages per thread
  constexpr int NT = (K1 + H_) / 32;     // k-tiles
  constexpr int NM = B_ / TM;            // m-blocks (4 enc / 8 dec)
  constexpr int ND = DEC ? 1 : 2;        // dirs
  constexpr int APAD = TM + 2;           // 66 / 34 -> conflict-free scalar stores
  // XCD-chunked swizzle: m fastest, then dir, then q.
  const int nblk = 64 * NM * ND;         // 512
  const int per = nblk >> 3;
  const int fid = (blockIdx.x & 7) * per + (blockIdx.x >> 3);
  const int m0 = (fid % NM) * TM;
  const int r2 = fid / NM;
  const int dir = r2 % ND;
  const int q0 = (r2 / ND) * 16;

  __shared__ float As[32][APAD];
  __shared__ float Ws[3][32][22];
  __shared__ int rows[TM];
  const int tid = threadIdx.x;
  const int tx = tid & 7;                // 2 q columns each
  const int ty = tid >> 3;               // 32 row-groups
  const int wrow = tid >> 4;             // 16 weight rows
  const int wk2 = (tid & 15) << 1;       // k pair within tile
  const float* Wih = dir ? g.Wih1 : g.Wih0;
  const float* Whh = dir ? g.Whh1 : g.Whh0;
  const float* hsrc = dir ? g.h1 : g.h0;

  if (!DEC) {
    if (tid < TM)
      rows[tid] = g.gidx[(size_t)(m0 + tid) * S_ + (dir ? g.goff1 : g.goff0)];
    __syncthreads();
  }

  float ar[RM][2] = {}, az[RM][2] = {}, anI[RM][2] = {}, anH[RM][2] = {};
  float4 av[NA], av2[NA];
  float2 wv[3], wv2[3];

  auto load_tile = [&](int kb, float4 (&AV)[NA], float2 (&WV)[3]) {
    if (kb < K1) {
#pragma unroll
      for (int i = 0; i < NA; ++i) {
        const int f = tid + i * 256;
        const int arow = f >> 3, kk = kb + ((f & 7) << 2);
        if (!DEC) {
          AV[i] = *(const float4*)(g.A1 + (size_t)rows[arow] * E_ + kk);
        } else {
          const int off = (kk < 512) ? (3072 + kk) : (512 + kk);
          AV[i] = *(const float4*)(g.A1 + (size_t)(m0 + arow) * 3584 + off);
        }
      }
#pragma unroll
      for (int th = 0; th < 3; ++th)
        WV[th] = *(const float2*)(Wih + (size_t)(th * H_ + q0 + wrow) * K1 + kb + wk2);
    } else {
      const int kb2 = kb - K1;
#pragma unroll
      for (int i = 0; i < NA; ++i) {
        const int f = tid + i * 256;
        const int arow = f >> 3, kk = kb2 + ((f & 7) << 2);
        AV[i] = *(const float4*)(hsrc + (size_t)(m0 + arow) * g.ldh + kk);
      }
#pragma unroll
      for (int th = 0; th < 3; ++th)
        WV[th] = *(const float2*)(Whh + (size_t)(th * H_ + q0 + wrow) * H_ + kb2 + wk2);
    }
  };

  auto compute_tile = [&](float (&an)[RM][2]) {
#pragma unroll
    for (int k = 0; k < 32; ++k) {
      float am[RM];
      if constexpr (RM == 2) {
        const float2 a2 = *(const float2*)&As[k][ty << 1];
        am[0] = a2.x; am[1] = a2.y;
      } else {
        am[0] = As[k][ty];
      }
      const float2 wr = *(const float2*)&Ws[0][k][tx << 1];
      const float2 wz = *(const float2*)&Ws[1][k][tx << 1];
      const float2 wn = *(const float2*)&Ws[2][k][tx << 1];
#pragma unroll
      for (int i = 0; i < RM; ++i) {
        ar[i][0] += am[i] * wr.x; ar[i][1] += am[i] * wr.y;
        az[i][0] += am[i] * wz.x; az[i][1] += am[i] * wz.y;
        an[i][0] += am[i] * wn.x; an[i][1] += am[i] * wn.y;
      }
    }
  };

  load_tile(0, av, wv);
  for (int kt = 0; kt < NT; ++kt) {
    __syncthreads();
#pragma unroll
    for (int i = 0; i < NA; ++i) {
      const int f = tid + i * 256;
      const int arow = f >> 3, kp = (f & 7) << 2;
      As[kp + 0][arow] = av[i].x; As[kp + 1][arow] = av[i].y;
      As[kp + 2][arow] = av[i].z; As[kp + 3][arow] = av[i].w;
    }
#pragma unroll
    for (int th = 0; th < 3; ++th) {
      Ws[th][wk2 + 0][wrow] = wv[th].x;
      Ws[th][wk2 + 1][wrow] = wv[th].y;
    }
    __syncthreads();
    if (kt + 1 < NT) load_tile((kt + 1) * 32, av2, wv2);
    if (kt * 32 < K1) compute_tile(anI); else compute_tile(anH);
#pragma unroll
    for (int i = 0; i < NA; ++i) av[i] = av2[i];
#pragma unroll
    for (int th = 0; th < 3; ++th) wv[th] = wv2[th];
  }

  // ---------- gate epilogue ----------
  const float* bih = dir ? g.bih1 : g.bih0;
  const float* bhh = dir ? g.bhh1 : g.bhh0;
  float* dst = dir ? g.d1 : g.d0;
  const int qq = q0 + (tx << 1);
  const float2 bir = *(const float2*)(bih + qq);
  const float2 biz = *(const float2*)(bih + H_ + qq);
  const float2 bin = *(const float2*)(bih + 2 * H_ + qq);
  const float2 bhr = *(const float2*)(bhh + qq);
  const float2 bhz = *(const float2*)(bhh + H_ + qq);
  const float2 bhn = *(const float2*)(bhh + 2 * H_ + qq);
#pragma unroll
  for (int i = 0; i < RM; ++i) {
    const int b = m0 + ty * RM + i;
    const float2 hold = *(const float2*)(hsrc + (size_t)b * g.ldh + qq);
    float2 hv;
    float r = sigmoidf_(ar[i][0] + bir.x + bhr.x);
    float z = sigmoidf_(az[i][0] + biz.x + bhz.x);
    float n = tanhf(anI[i][0] + bin.x + r * (anH[i][0] + bhn.x));
    hv.x = (1.f - z) * n + z * hold.x;
    r = sigmoidf_(ar[i][1] + bir.y + bhr.y);
    z = sigmoidf_(az[i][1] + biz.y + bhz.y);
    n = tanhf(anI[i][1] + bin.y + r * (anH[i][1] + bhn.y));
    hv.y = (1.f - z) * n + z * hold.y;
    *(float2*)(dst + (size_t)b * g.ldd + qq) = hv;
    if (!DEC) {
      __half* edst = dir ? g.e1 : g.e0;
      *(__half2*)(edst + (size_t)b * g.lde + qq) = __floats2half2_rn(hv.x, hv.y);
    } else {
      *(float2*)(g.predin + (size_t)b * 3584 + qq) = hv;
    }
  }
}

// =================== fused pred-GEMM + q-GEMM (512 blocks) ===================
// blocks [0,256): pred 16x16 tiles (M=256,N=256,K=3584), out slice write.
// blocks [256,512): q 32x32 tiles (M=256,N=1024,K=1024) from h_new.
__global__ __launch_bounds__(256)
void prqa_k(const float* __restrict__ predin,
            const float* __restrict__ Wfc, const float* __restrict__ bfc,
            const float* __restrict__ hnew, const float* __restrict__ Wa,
            float* __restrict__ out_t, float* __restrict__ q)
{
  const int bid = blockIdx.x, tid = threadIdx.x;
  if (bid < 256) {
    const int m0 = (bid >> 4) << 4, n0 = (bid & 15) << 4;
    __shared__ float As[32][17], Ws[32][17];
    const int r = tid >> 4, kq = (tid & 15) << 1;
    const int tym = tid >> 4, txn = tid & 15;
    float acc = 0.f;
    for (int k0 = 0; k0 < 3584; k0 += 32) {
      const float2 a2 = *(const float2*)(predin + (size_t)(m0 + r) * 3584 + k0 + kq);
      const float2 w2 = *(const float2*)(Wfc + (size_t)(n0 + r) * 3584 + k0 + kq);
      __syncthreads();
      As[kq][r] = a2.x; As[kq + 1][r] = a2.y;
      Ws[kq][r] = w2.x; Ws[kq + 1][r] = w2.y;
      __syncthreads();
#pragma unroll
      for (int k = 0; k < 32; ++k)
        acc += As[k][tym] * Ws[k][txn];
    }
    out_t[(size_t)(m0 + tym) * ((T_ - 1) * V_) + n0 + txn] = acc + bfc[n0 + txn];
  } else {
    const int b2 = bid - 256;
    const int m0 = (b2 >> 5) << 5, n0 = (b2 & 31) << 5;
    __shared__ float As[32][34], Ws[32][34];
    const int r = tid >> 3, kq = (tid & 7) << 2;
    const int tx = tid & 15, ty = tid >> 4;
    float acc[2][2] = {};
    for (int k0 = 0; k0 < 1024; k0 += 32) {
      const float4 a4 = *(const float4*)(hnew + (size_t)(m0 + r) * H_ + k0 + kq);
      const float4 w4 = *(const float4*)(Wa + (size_t)(n0 + r) * (3 * H_) + k0 + kq);
      __syncthreads();
      As[kq + 0][r] = a4.x; As[kq + 1][r] = a4.y; As[kq + 2][r] = a4.z; As[kq + 3][r] = a4.w;
      Ws[kq + 0][r] = w4.x; Ws[kq + 1][r] = w4.y; Ws[kq + 2][r] = w4.z; Ws[kq + 3][r] = w4.w;
      __syncthreads();
#pragma unroll
      for (int k = 0; k < 32; ++k) {
        const float2 a2 = *(const float2*)&As[k][ty << 1];
        const float2 w2 = *(const float2*)&Ws[k][tx << 1];
        acc[0][0] += a2.x * w2.x; acc[0][1] += a2.x * w2.y;
        acc[1][0] += a2.y * w2.x; acc[1][1] += a2.y * w2.y;
      }
    }
#pragma unroll
    for (int i = 0; i < 2; ++i)
#pragma unroll
      for (int j = 0; j < 2; ++j)
        q[(size_t)(m0 + (ty << 1) + i) * H_ + n0 + (tx << 1) + j] = acc[i][j];
  }
}

// =================== generic fp32 tiled GEMM (enc_proj / br / q0) ==============
// AMODE: 0 plain f32, 2 cond concat (K=2432), 4 plain fp16
// CMODE: 0 f32 (optional tanh), 1 fp16
struct GB {
  const float* A; int lda;
  const __half* Ah;
  const float* W; int ldw;
  const float* bias;
  float* C; int ldc;
  __half* Ch;
  int M, N, K, act;
  const float *hf, *hb; int ldh;
  const float *mE, *tE, *pE;
  const int *mi, *ti, *pi;
};

template<int AMODE, int CMODE>
__global__ __launch_bounds__(256)
void gemm_k(GB g0, GB g1)
{
  GB g = blockIdx.z ? g1 : g0;
  const int m0 = blockIdx.y * 64, n0 = blockIdx.x * 64;
  if (m0 >= g.M || n0 >= g.N) return;
  __shared__ float As[32][68];
  __shared__ float Ws[32][68];
  const int tid = threadIdx.x, tx = tid & 15, ty = tid >> 4;
  const int lm = tid >> 3, lk = (tid & 7) << 2;
  float acc[4][4] = {};
  float4 av[2], wv[2], av2[2], wv2[2];

  auto load_tile = [&](int k0, float4 (&AV)[2], float4 (&WV)[2]) {
#pragma unroll
    for (int i = 0; i < 2; ++i) {
      const int row = lm + i * 32;
      const int kk = k0 + lk;
      if (AMODE == 0) {
        AV[i] = *(const float4*)(g.A + (size_t)(m0 + row) * g.lda + kk);
      } else if (AMODE == 4) {
        const __half* ap = g.Ah + (size_t)(m0 + row) * g.lda + kk;
        const __half2 h0 = *(const __half2*)ap;
        const __half2 h1 = *(const __half2*)(ap + 2);
        AV[i] = make_float4(__half2float(h0.x), __half2float(h0.y),
                            __half2float(h1.x), __half2float(h1.y));
      } else {
        const int mg = m0 + row; const float* sp; size_t o;
        if (kk < 1024)      { sp = g.hf; o = (size_t)mg * g.ldh + kk; }
        else if (kk < 2048) { sp = g.hb; o = (size_t)mg * g.ldh + kk - 1024; }
        else if (kk < 2176) { sp = g.mE; o = (size_t)g.mi[mg] * C_ + kk - 2048; }
        else if (kk < 2304) { sp = g.tE; o = (size_t)g.ti[mg] * C_ + kk - 2176; }
        else                { sp = g.pE; o = (size_t)g.pi[mg] * C_ + kk - 2304; }
        AV[i] = *(const float4*)(sp + o);
      }
      WV[i] = *(const float4*)(g.W + (size_t)(n0 + row) * g.ldw + kk);
    }
  };

  load_tile(0, av, wv);
  for (int k0 = 0; k0 < g.K; k0 += 32) {
    __syncthreads();
#pragma unroll
    for (int i = 0; i < 2; ++i) {
      const int row = lm + i * 32;
      As[lk + 0][row] = av[i].x; As[lk + 1][row] = av[i].y;
      As[lk + 2][row] = av[i].z; As[lk + 3][row] = av[i].w;
      Ws[lk + 0][row] = wv[i].x; Ws[lk + 1][row] = wv[i].y;
      Ws[lk + 2][row] = wv[i].z; Ws[lk + 3][row] = wv[i].w;
    }
    __syncthreads();
    if (k0 + 32 < g.K) load_tile(k0 + 32, av2, wv2);
#pragma unroll
    for (int k = 0; k < 32; ++k) {
      const float4 a4 = *(const float4*)&As[k][ty << 2];
      const float4 b4 = *(const float4*)&Ws[k][tx << 2];
      acc[0][0] += a4.x * b4.x; acc[0][1] += a4.x * b4.y; acc[0][2] += a4.x * b4.z; acc[0][3] += a4.x * b4.w;
      acc[1][0] += a4.y * b4.x; acc[1][1] += a4.y * b4.y; acc[1][2] += a4.y * b4.z; acc[1][3] += a4.y * b4.w;
      acc[2][0] += a4.z * b4.x; acc[2][1] += a4.z * b4.y; acc[2][2] += a4.z * b4.z; acc[2][3] += a4.z * b4.w;
      acc[3][0] += a4.w * b4.x; acc[3][1] += a4.w * b4.y; acc[3][2] += a4.w * b4.z; acc[3][3] += a4.w * b4.w;
    }
#pragma unroll
    for (int i = 0; i < 2; ++i) { av[i] = av2[i]; wv[i] = wv2[i]; }
  }
  const int n = n0 + (tx << 2);
  float4 bb = make_float4(0.f, 0.f, 0.f, 0.f);
  if (g.bias) bb = *(const float4*)(g.bias + n);
#pragma unroll
  for (int i = 0; i < 4; ++i) {
    const int m = m0 + (ty << 2) + i;
    float4 v = make_float4(acc[i][0] + bb.x, acc[i][1] + bb.y, acc[i][2] + bb.z, acc[i][3] + bb.w);
    if (CMODE == 0) {
      if (g.act) { v.x = tanhf(v.x); v.y = tanhf(v.y); v.z = tanhf(v.z); v.w = tanhf(v.w); }
      *(float4*)(g.C + (size_t)m * g.ldc + n) = v;
    } else {
      __half2* cp = (__half2*)(g.Ch + (size_t)m * g.ldc + n);
      cp[0] = __floats2half2_rn(v.x, v.y);
      cp[1] = __floats2half2_rn(v.z, v.w);
    }
  }
}

// =================== fused decoder attention step (fp16 enc_out/proj) ===================
__global__ __launch_bounds__(1024)
void attn_k(const float* __restrict__ out, const int* __restrict__ tgt,
            const float* __restrict__ q, const __half* __restrict__ proj,
            const float* __restrict__ va, const int* __restrict__ src,
            const __half* __restrict__ enc, const float* __restrict__ dec_emb,
            float* __restrict__ predin, int t)
{
  const int b = blockIdx.x, tid = threadIdx.x;
  const int lane = tid & 63, wv = tid >> 6;
  __shared__ float sm[128];
  __shared__ float tr[128];
  __shared__ float rv[4];
  __shared__ int ri[4];
  __shared__ int tok_s;
  if (t == 0) {
    if (tid == 0) tok_s = tgt[(size_t)b * T_];
  } else {
    if (tid < 256) {
      float av = out[((size_t)b * (T_ - 1) + (t - 1)) * V_ + tid];
      int ai = tid;
      for (int off = 32; off; off >>= 1) {
        const float ov = __shfl_down(av, off);
        const int   oi = __shfl_down(ai, off);
        if (ov > av) { av = ov; ai = oi; }   // strict >: first-max semantics
      }
      if (lane == 0) { rv[wv] = av; ri[wv] = ai; }
    }
    __syncthreads();
    if (tid == 0) {
      float bv = rv[0]; int bi = ri[0];
      for (int w = 1; w < 4; ++w) if (rv[w] > bv) { bv = rv[w]; bi = ri[w]; }
      tok_s = bi;
    }
  }
  __syncthreads();
  const int tok = tok_s;
  if (tid < E_) predin[(size_t)b * 3584 + 3072 + tid] = dec_emb[(size_t)tok * E_ + tid];
  const float* qb = q + (size_t)b * H_;
  for (int s = wv * 6; s < wv * 6 + 6; ++s) {
    const __half* pb = proj + ((size_t)b * S_ + s) * H_;
    float part = 0.f;
#pragma unroll
    for (int j = 0; j < 8; ++j) {
      const int h = lane * 2 + j * 128;
      const __half2 p2 = *(const __half2*)(pb + h);
      const float2 q2 = *(const float2*)(qb + h);
      const float2 v2 = *(const float2*)(va + h);
      part += v2.x * tanhf(q2.x + __half2float(p2.x));
      part += v2.y * tanhf(q2.y + __half2float(p2.y));
    }
    for (int off = 32; off; off >>= 1) part += __shfl_down(part, off);
    if (lane == 0)
      sm[s] = (src[(size_t)b * S_ + s] == 0) ? -1.0e9f : part;
  }
  __syncthreads();
  if (tid < 128) tr[tid] = (tid < S_) ? sm[tid] : -3.0e38f;
  __syncthreads();
  for (int s2 = 64; s2 > 0; s2 >>= 1) { if (tid < s2) tr[tid] = fmaxf(tr[tid], tr[tid + s2]); __syncthreads(); }
  const float mx = tr[0];
  __syncthreads();
  if (tid < 128) tr[tid] = (tid < S_) ? expf(sm[tid] - mx) : 0.f;
  __syncthreads();
  for (int s2 = 64; s2 > 0; s2 >>= 1) { if (tid < s2) tr[tid] += tr[tid + s2]; __syncthreads(); }
  const float inv = 1.0f / tr[0];
  __syncthreads();
  if (tid < S_) sm[tid] = expf(sm[tid] - mx) * inv;
  __syncthreads();
  const int d = tid * 2;
  const __half* eb = enc + (size_t)b * S_ * (2 * H_) + d;
  float c0 = 0.f, c1 = 0.f;
  for (int s0 = 0; s0 < S_; s0 += 8) {
    __half2 v[8];
#pragma unroll
    for (int i = 0; i < 8; ++i) v[i] = *(const __half2*)(eb + (size_t)(s0 + i) * (2 * H_));
#pragma unroll
    for (int i = 0; i < 8; ++i) {
      const float w = sm[s0 + i];
      c0 += w * __half2float(v[i].x);
      c1 += w * __half2float(v[i].y);
    }
  }
  *(float2*)(predin + (size_t)b * 3584 + H_ + d) = make_float2(c0, c1);
}

// =================== misc ===================
__global__ void zero_k(float* __restrict__ p, int n)
{
  const int i = blockIdx.x * 256 + threadIdx.x;
  if (i < n) p[i] = 0.0f;
}

__global__ void sentinel_k(float* out, float v) { out[threadIdx.x] = v; }

// =================== host orchestration ===================
extern "C" void kernel_launch(void* const* d_in, const int* in_sizes, int n_in,
                              void* d_out, int out_size, void* d_ws, size_t ws_size,
                              hipStream_t stream)
{
  const int*   src        = (const int*)d_in[0];
  const int*   tgt        = (const int*)d_in[1];
  const int*   mode_idx   = (const int*)d_in[2];
  const int*   tense_idx  = (const int*)d_in[3];
  const int*   person_idx = (const int*)d_in[4];
  const float* enc_emb    = (const float*)d_in[5];
  const float* eWih_f     = (const float*)d_in[6];
  const float* eWhh_f     = (const float*)d_in[7];
  const float* ebih_f     = (const float*)d_in[8];
  const float* ebhh_f     = (const float*)d_in[9];
  const float* eWih_b     = (const float*)d_in[10];
  const float* eWhh_b     = (const float*)d_in[11];
  const float* ebih_b     = (const float*)d_in[12];
  const float* ebhh_b     = (const float*)d_in[13];
  const float* Wa         = (const float*)d_in[14];
  const float* va         = (const float*)d_in[15];
  const float* dec_emb    = (const float*)d_in[16];
  const float* dWih       = (const float*)d_in[17];
  const float* dWhh       = (const float*)d_in[18];
  const float* dbih       = (const float*)d_in[19];
  const float* dbhh       = (const float*)d_in[20];
  const float* Wfc        = (const float*)d_in[21];
  const float* bfc        = (const float*)d_in[22];
  const float* mode_E     = (const float*)d_in[23];
  const float* tense_E    = (const float*)d_in[24];
  const float* person_E   = (const float*)d_in[25];
  const float* Wbr        = (const float*)d_in[26];
  const float* bbr        = (const float*)d_in[27];
  float* out = (float*)d_out;

  // ---- workspace carve (~163 MB) ----
  char* base = (char*)d_ws;
  size_t off = 0;
  auto alloc = [&](size_t bytes) { char* r = base + off; off = (off + bytes + 255) & ~(size_t)255; return r; };
  __half* enc_out = (__half*)alloc(2ull * B_ * S_ * 2 * H_);   // 100.7 MB (fp16)
  __half* proj    = (__half*)alloc(2ull * B_ * S_ * H_);       // 50.3 MB
  float* hfA   = (float*)alloc(4ull * B_ * H_);   // enc fwd h ping-pong (f32)
  float* hfB   = (float*)alloc(4ull * B_ * H_);
  float* hbA   = (float*)alloc(4ull * B_ * H_);   // enc bwd h ping-pong
  float* hbB   = (float*)alloc(4ull * B_ * H_);
  float* h_d0  = (float*)alloc(4ull * B_ * H_);
  float* h_d1  = (float*)alloc(4ull * B_ * H_);
  float* q     = (float*)alloc(4ull * B_ * H_);
  float* predin = (float*)alloc(4ull * B_ * 3584);             // [h2|ctx|emb]
  float* zero_buf = (float*)alloc(4ull * 1024);
  if (off > ws_size) {
    hipLaunchKernelGGL(sentinel_k, dim3(1), dim3(256), 0, stream, out,
                       1000.0f + (float)(ws_size >> 20));
    return;
  }

  hipLaunchKernelGGL(zero_k, dim3(4), dim3(256), 0, stream, zero_buf, 1024);

  // ---- encoder: 96 fused steps (f32 recurrence, fp16 enc_out) ----
  for (int t = 0; t < S_; ++t) {
    RS rs{};
    rs.A1 = enc_emb; rs.gidx = src; rs.goff0 = t; rs.goff1 = S_ - 1 - t;
    if (t == 0) { rs.h0 = zero_buf; rs.h1 = zero_buf; rs.ldh = 0; }
    else if (t & 1) { rs.h0 = hfA; rs.h1 = hbA; rs.ldh = H_; }
    else            { rs.h0 = hfB; rs.h1 = hbB; rs.ldh = H_; }
    rs.Wih0 = eWih_f; rs.Wih1 = eWih_b; rs.Whh0 = eWhh_f; rs.Whh1 = eWhh_b;
    rs.bih0 = ebih_f; rs.bih1 = ebih_b; rs.bhh0 = ebhh_f; rs.bhh1 = ebhh_b;
    if (t & 1) { rs.d0 = hfB; rs.d1 = hbB; } else { rs.d0 = hfA; rs.d1 = hbA; }
    rs.ldd = H_;
    rs.e0 = enc_out + (size_t)t * 2 * H_;
    rs.e1 = enc_out + (size_t)(S_ - 1 - t) * 2 * H_ + H_;
    rs.lde = S_ * 2 * H_;
    hipLaunchKernelGGL((rnnstep_k<0>), dim3(512), dim3(256), 0, stream, rs);
  }
  float* hf_fin = hfB;   // t=95 (odd) wrote hfB/hbB
  float* hb_fin = hbB;

  GB Z{};

  // ---- enc_proj (fp16 A, fp16 out) ----
  {
    GB ep = Z;
    ep.Ah = enc_out; ep.lda = 2 * H_; ep.W = Wa + H_; ep.ldw = 3 * H_;
    ep.Ch = proj; ep.ldc = H_; ep.M = B_ * S_; ep.N = H_; ep.K = 2 * H_;
    hipLaunchKernelGGL((gemm_k<4, 1>), dim3(16, 384, 1), dim3(256), 0, stream, ep, ep);
  }

  // ---- dec_h0 = tanh(cond @ Wbr.T + bbr) ----
  {
    GB br = Z;
    br.W = Wbr; br.ldw = 2432; br.bias = bbr; br.C = h_d0; br.ldc = H_;
    br.M = B_; br.N = H_; br.K = 2432; br.act = 1;
    br.hf = hf_fin; br.hb = hb_fin; br.ldh = H_;
    br.mE = mode_E; br.tE = tense_E; br.pE = person_E;
    br.mi = mode_idx; br.ti = tense_idx; br.pi = person_idx;
    hipLaunchKernelGGL((gemm_k<2, 0>), dim3(16, 4, 1), dim3(256), 0, stream, br, br);
  }

  // ---- q(0) ----
  {
    GB qa = Z;
    qa.A = h_d0; qa.lda = H_; qa.W = Wa; qa.ldw = 3 * H_; qa.C = q; qa.ldc = H_;
    qa.M = B_; qa.N = H_; qa.K = H_;
    hipLaunchKernelGGL((gemm_k<0, 0>), dim3(16, 4, 1), dim3(256), 0, stream, qa, qa);
  }

  // ---- decoder: 39 steps x (attn, fused gia+gh+gate, pred+qa) ----
  float* hd[2] = { h_d0, h_d1 };
  for (int t = 0; t < T_ - 1; ++t) {
    hipLaunchKernelGGL(attn_k, dim3(B_), dim3(1024), 0, stream,
                       out, tgt, q, proj, va, src, enc_out, dec_emb, predin, t);

    RS rs{};
    rs.A1 = predin;
    rs.h0 = hd[t & 1]; rs.h1 = hd[t & 1]; rs.ldh = H_;
    rs.Wih0 = dWih; rs.Wih1 = dWih; rs.Whh0 = dWhh; rs.Whh1 = dWhh;
    rs.bih0 = dbih; rs.bih1 = dbih; rs.bhh0 = dbhh; rs.bhh1 = dbhh;
    rs.d0 = hd[(t + 1) & 1]; rs.d1 = hd[(t + 1) & 1]; rs.ldd = H_;
    rs.predin = predin;
    hipLaunchKernelGGL((rnnstep_k<1>), dim3(512), dim3(256), 0, stream, rs);

    hipLaunchKernelGGL(prqa_k, dim3(512), dim3(256), 0, stream,
                       predin, Wfc, bfc, hd[(t + 1) & 1], Wa,
                       out + (size_t)t * V_, q);
  }
}

// Round 10
// 22596.951 us; speedup vs baseline: 2.0561x; 1.1926x over previous
//
#include <hip/hip_runtime.h>
#include <hip/hip_fp16.h>
#include <cstdint>
#include <cstddef>

#define B_  256
#define S_  96
#define T_  40
#define V_  256
#define E_  512
#define H_  1024
#define C_  128

__device__ __forceinline__ float sigmoidf_(float x) { return 1.0f / (1.0f + expf(-x)); }

// =================== fused RNN step (token-table input, pipelined, XCD-swizzled) ========
// ENC (DEC=0): K-loop = hidden GEMM only (K=1024); input contribution gathered from
//              per-token table Gi[tok] in the epilogue (bit-identical chain).
// DEC (DEC=1): K-loop = ctx GEMM (K=2048, predin ctx region) + hidden GEMM (K=1024);
//              emb contribution gathered from Gd[tok].
struct RS {
  const float* A1;                       // DEC: predin + 1024 (ctx region), lda 3584
  const int* gidx; int goff0, goff1;     // ENC: token ids per dir
  const int* tok;                        // DEC: current tokens
  const float* Gt0; const float* Gt1;    // token tables [V][3H]
  const float* h0; const float* h1; int ldh;   // f32 h source (ldh=0 -> zeros)
  const float* Wih0;                     // DEC: dWih + 512 (ctx cols), ldw 2560
  const float* Whh0; const float* Whh1;  // [3H][H]
  const float* bih0; const float* bih1;
  const float* bhh0; const float* bhh1;
  float* d0; float* d1; int ldd;         // f32 h dst
  __half* e0; __half* e1; int lde;       // ENC: fp16 enc_out slices
  float* predin;                         // DEC: h2 write
};

template<int DEC>
__global__ __launch_bounds__(256)
void rnnstep_k(RS g)
{
  constexpr int K1 = DEC ? 2048 : 0;     // ctx phase length
  constexpr int TM = 64;
  constexpr int RM = 2;
  constexpr int NA = 2;                  // float4 A-stages per thread
  constexpr int NT = (K1 + H_) / 32;     // 96 dec / 32 enc
  constexpr int NM = B_ / TM;            // 4
  constexpr int ND = DEC ? 1 : 2;
  const int nblk = 64 * NM * ND;         // 512 enc / 256 dec
  const int per = nblk >> 3;
  const int fid = (blockIdx.x & 7) * per + (blockIdx.x >> 3);
  const int m0 = (fid % NM) * TM;
  const int r2 = fid / NM;
  const int dir = r2 % ND;
  const int q0 = (r2 / ND) * 16;

  __shared__ float As[32][TM + 2];
  __shared__ float Ws[3][32][22];
  __shared__ int rows[TM];
  const int tid = threadIdx.x;
  const int tx = tid & 7;                // 2 q columns
  const int ty = tid >> 3;               // 32 row-groups
  const int wrow = tid >> 4;             // 16 weight rows
  const int wk2 = (tid & 15) << 1;       // k pair
  const float* Whh = dir ? g.Whh1 : g.Whh0;
  const float* hsrc = dir ? g.h1 : g.h0;

  if (!DEC) {
    if (tid < TM)
      rows[tid] = g.gidx[(size_t)(m0 + tid) * S_ + (dir ? g.goff1 : g.goff0)];
    __syncthreads();
  }

  float ar[RM][2] = {}, az[RM][2] = {}, anI[RM][2] = {}, anH[RM][2] = {};
  float4 av[NA], av2[NA];
  float2 wv[3], wv2[3];

  auto load_tile = [&](int kb, float4 (&AV)[NA], float2 (&WV)[3]) {
    if (DEC && kb < K1) {
#pragma unroll
      for (int i = 0; i < NA; ++i) {
        const int f = tid + i * 256;
        const int arow = f >> 3, kk = kb + ((f & 7) << 2);
        AV[i] = *(const float4*)(g.A1 + (size_t)(m0 + arow) * 3584 + kk);
      }
#pragma unroll
      for (int th = 0; th < 3; ++th)
        WV[th] = *(const float2*)(g.Wih0 + (size_t)(th * H_ + q0 + wrow) * 2560 + kb + wk2);
    } else {
      const int kb2 = kb - K1;
#pragma unroll
      for (int i = 0; i < NA; ++i) {
        const int f = tid + i * 256;
        const int arow = f >> 3, kk = kb2 + ((f & 7) << 2);
        AV[i] = *(const float4*)(hsrc + (size_t)(m0 + arow) * g.ldh + kk);
      }
#pragma unroll
      for (int th = 0; th < 3; ++th)
        WV[th] = *(const float2*)(Whh + (size_t)(th * H_ + q0 + wrow) * H_ + kb2 + wk2);
    }
  };

  auto compute_tile = [&](float (&an)[RM][2]) {
#pragma unroll
    for (int k = 0; k < 32; ++k) {
      const float2 a2 = *(const float2*)&As[k][ty << 1];
      const float am[2] = { a2.x, a2.y };
      const float2 wr = *(const float2*)&Ws[0][k][tx << 1];
      const float2 wz = *(const float2*)&Ws[1][k][tx << 1];
      const float2 wn = *(const float2*)&Ws[2][k][tx << 1];
#pragma unroll
      for (int i = 0; i < RM; ++i) {
        ar[i][0] += am[i] * wr.x; ar[i][1] += am[i] * wr.y;
        az[i][0] += am[i] * wz.x; az[i][1] += am[i] * wz.y;
        an[i][0] += am[i] * wn.x; an[i][1] += am[i] * wn.y;
      }
    }
  };

  load_tile(0, av, wv);
  for (int kt = 0; kt < NT; ++kt) {
    __syncthreads();
#pragma unroll
    for (int i = 0; i < NA; ++i) {
      const int f = tid + i * 256;
      const int arow = f >> 3, kp = (f & 7) << 2;
      As[kp + 0][arow] = av[i].x; As[kp + 1][arow] = av[i].y;
      As[kp + 2][arow] = av[i].z; As[kp + 3][arow] = av[i].w;
    }
#pragma unroll
    for (int th = 0; th < 3; ++th) {
      Ws[th][wk2 + 0][wrow] = wv[th].x;
      Ws[th][wk2 + 1][wrow] = wv[th].y;
    }
    __syncthreads();
    if (kt + 1 < NT) load_tile((kt + 1) * 32, av2, wv2);
    if (DEC && kt * 32 < K1) compute_tile(anI); else compute_tile(anH);
#pragma unroll
    for (int i = 0; i < NA; ++i) av[i] = av2[i];
#pragma unroll
    for (int th = 0; th < 3; ++th) wv[th] = wv2[th];
  }

  // ---------- gate epilogue (token-table input part gathered here) ----------
  const float* bih = dir ? g.bih1 : g.bih0;
  const float* bhh = dir ? g.bhh1 : g.bhh0;
  const float* Gt = dir ? g.Gt1 : g.Gt0;
  float* dst = dir ? g.d1 : g.d0;
  const int qq = q0 + (tx << 1);
  const float2 bir = *(const float2*)(bih + qq);
  const float2 biz = *(const float2*)(bih + H_ + qq);
  const float2 bin = *(const float2*)(bih + 2 * H_ + qq);
  const float2 bhr = *(const float2*)(bhh + qq);
  const float2 bhz = *(const float2*)(bhh + H_ + qq);
  const float2 bhn = *(const float2*)(bhh + 2 * H_ + qq);
#pragma unroll
  for (int i = 0; i < RM; ++i) {
    const int b = m0 + ty * RM + i;
    const int tk = DEC ? g.tok[b] : rows[b - m0];
    const float* Gr = Gt + (size_t)tk * (3 * H_);
    const float2 g_r = *(const float2*)(Gr + qq);
    const float2 g_z = *(const float2*)(Gr + H_ + qq);
    const float2 g_n = *(const float2*)(Gr + 2 * H_ + qq);
    const float2 hold = *(const float2*)(hsrc + (size_t)b * g.ldh + qq);
    float2 hv;
    float r = sigmoidf_(ar[i][0] + g_r.x + bir.x + bhr.x);
    float z = sigmoidf_(az[i][0] + g_z.x + biz.x + bhz.x);
    float n = tanhf(anI[i][0] + g_n.x + bin.x + r * (anH[i][0] + bhn.x));
    hv.x = (1.f - z) * n + z * hold.x;
    r = sigmoidf_(ar[i][1] + g_r.y + bir.y + bhr.y);
    z = sigmoidf_(az[i][1] + g_z.y + biz.y + bhz.y);
    n = tanhf(anI[i][1] + g_n.y + bin.y + r * (anH[i][1] + bhn.y));
    hv.y = (1.f - z) * n + z * hold.y;
    *(float2*)(dst + (size_t)b * g.ldd + qq) = hv;
    if (!DEC) {
      __half* edst = dir ? g.e1 : g.e0;
      *(__half2*)(edst + (size_t)b * g.lde + qq) = __floats2half2_rn(hv.x, hv.y);
    } else {
      *(float2*)(g.predin + (size_t)b * 3584 + qq) = hv;
    }
  }
}

// =================== fused pred-GEMM + q-GEMM (512 blocks) ===================
__global__ __launch_bounds__(256)
void prqa_k(const float* __restrict__ predin,
            const float* __restrict__ Wfc, const float* __restrict__ bfc,
            const float* __restrict__ hnew, const float* __restrict__ Wa,
            float* __restrict__ out_t, float* __restrict__ q)
{
  const int bid = blockIdx.x, tid = threadIdx.x;
  if (bid < 256) {
    const int m0 = (bid >> 4) << 4, n0 = (bid & 15) << 4;
    __shared__ float As[32][17], Ws[32][17];
    const int r = tid >> 4, kq = (tid & 15) << 1;
    const int tym = tid >> 4, txn = tid & 15;
    float acc = 0.f;
    for (int k0 = 0; k0 < 3584; k0 += 32) {
      const float2 a2 = *(const float2*)(predin + (size_t)(m0 + r) * 3584 + k0 + kq);
      const float2 w2 = *(const float2*)(Wfc + (size_t)(n0 + r) * 3584 + k0 + kq);
      __syncthreads();
      As[kq][r] = a2.x; As[kq + 1][r] = a2.y;
      Ws[kq][r] = w2.x; Ws[kq + 1][r] = w2.y;
      __syncthreads();
#pragma unroll
      for (int k = 0; k < 32; ++k)
        acc += As[k][tym] * Ws[k][txn];
    }
    out_t[(size_t)(m0 + tym) * ((T_ - 1) * V_) + n0 + txn] = acc + bfc[n0 + txn];
  } else {
    const int b2 = bid - 256;
    const int m0 = (b2 >> 5) << 5, n0 = (b2 & 31) << 5;
    __shared__ float As[32][34], Ws[32][34];
    const int r = tid >> 3, kq = (tid & 7) << 2;
    const int tx = tid & 15, ty = tid >> 4;
    float acc[2][2] = {};
    for (int k0 = 0; k0 < 1024; k0 += 32) {
      const float4 a4 = *(const float4*)(hnew + (size_t)(m0 + r) * H_ + k0 + kq);
      const float4 w4 = *(const float4*)(Wa + (size_t)(n0 + r) * (3 * H_) + k0 + kq);
      __syncthreads();
      As[kq + 0][r] = a4.x; As[kq + 1][r] = a4.y; As[kq + 2][r] = a4.z; As[kq + 3][r] = a4.w;
      Ws[kq + 0][r] = w4.x; Ws[kq + 1][r] = w4.y; Ws[kq + 2][r] = w4.z; Ws[kq + 3][r] = w4.w;
      __syncthreads();
#pragma unroll
      for (int k = 0; k < 32; ++k) {
        const float2 a2 = *(const float2*)&As[k][ty << 1];
        const float2 w2 = *(const float2*)&Ws[k][tx << 1];
        acc[0][0] += a2.x * w2.x; acc[0][1] += a2.x * w2.y;
        acc[1][0] += a2.y * w2.x; acc[1][1] += a2.y * w2.y;
      }
    }
#pragma unroll
    for (int i = 0; i < 2; ++i)
#pragma unroll
      for (int j = 0; j < 2; ++j)
        q[(size_t)(m0 + (ty << 1) + i) * H_ + n0 + (tx << 1) + j] = acc[i][j];
  }
}

// =================== generic fp32 tiled GEMM (tables / enc_proj / br / q0) ==============
// AMODE: 0 plain f32, 2 cond concat (K=2432), 4 plain fp16
// CMODE: 0 f32 (optional tanh), 1 fp16
struct GB {
  const float* A; int lda;
  const __half* Ah;
  const float* W; int ldw;
  const float* bias;
  float* C; int ldc;
  __half* Ch;
  int M, N, K, act;
  const float *hf, *hb; int ldh;
  const float *mE, *tE, *pE;
  const int *mi, *ti, *pi;
};

template<int AMODE, int CMODE>
__global__ __launch_bounds__(256)
void gemm_k(GB g0, GB g1)
{
  GB g = blockIdx.z ? g1 : g0;
  const int m0 = blockIdx.y * 64, n0 = blockIdx.x * 64;
  if (m0 >= g.M || n0 >= g.N) return;
  __shared__ float As[32][68];
  __shared__ float Ws[32][68];
  const int tid = threadIdx.x, tx = tid & 15, ty = tid >> 4;
  const int lm = tid >> 3, lk = (tid & 7) << 2;
  float acc[4][4] = {};
  float4 av[2], wv[2], av2[2], wv2[2];

  auto load_tile = [&](int k0, float4 (&AV)[2], float4 (&WV)[2]) {
#pragma unroll
    for (int i = 0; i < 2; ++i) {
      const int row = lm + i * 32;
      const int kk = k0 + lk;
      if (AMODE == 0) {
        AV[i] = *(const float4*)(g.A + (size_t)(m0 + row) * g.lda + kk);
      } else if (AMODE == 4) {
        const __half* ap = g.Ah + (size_t)(m0 + row) * g.lda + kk;
        const __half2 h0 = *(const __half2*)ap;
        const __half2 h1 = *(const __half2*)(ap + 2);
        AV[i] = make_float4(__half2float(h0.x), __half2float(h0.y),
                            __half2float(h1.x), __half2float(h1.y));
      } else {
        const int mg = m0 + row; const float* sp; size_t o;
        if (kk < 1024)      { sp = g.hf; o = (size_t)mg * g.ldh + kk; }
        else if (kk < 2048) { sp = g.hb; o = (size_t)mg * g.ldh + kk - 1024; }
        else if (kk < 2176) { sp = g.mE; o = (size_t)g.mi[mg] * C_ + kk - 2048; }
        else if (kk < 2304) { sp = g.tE; o = (size_t)g.ti[mg] * C_ + kk - 2176; }
        else                { sp = g.pE; o = (size_t)g.pi[mg] * C_ + kk - 2304; }
        AV[i] = *(const float4*)(sp + o);
      }
      WV[i] = *(const float4*)(g.W + (size_t)(n0 + row) * g.ldw + kk);
    }
  };

  load_tile(0, av, wv);
  for (int k0 = 0; k0 < g.K; k0 += 32) {
    __syncthreads();
#pragma unroll
    for (int i = 0; i < 2; ++i) {
      const int row = lm + i * 32;
      As[lk + 0][row] = av[i].x; As[lk + 1][row] = av[i].y;
      As[lk + 2][row] = av[i].z; As[lk + 3][row] = av[i].w;
      Ws[lk + 0][row] = wv[i].x; Ws[lk + 1][row] = wv[i].y;
      Ws[lk + 2][row] = wv[i].z; Ws[lk + 3][row] = wv[i].w;
    }
    __syncthreads();
    if (k0 + 32 < g.K) load_tile(k0 + 32, av2, wv2);
#pragma unroll
    for (int k = 0; k < 32; ++k) {
      const float4 a4 = *(const float4*)&As[k][ty << 2];
      const float4 b4 = *(const float4*)&Ws[k][tx << 2];
      acc[0][0] += a4.x * b4.x; acc[0][1] += a4.x * b4.y; acc[0][2] += a4.x * b4.z; acc[0][3] += a4.x * b4.w;
      acc[1][0] += a4.y * b4.x; acc[1][1] += a4.y * b4.y; acc[1][2] += a4.y * b4.z; acc[1][3] += a4.y * b4.w;
      acc[2][0] += a4.z * b4.x; acc[2][1] += a4.z * b4.y; acc[2][2] += a4.z * b4.z; acc[2][3] += a4.z * b4.w;
      acc[3][0] += a4.w * b4.x; acc[3][1] += a4.w * b4.y; acc[3][2] += a4.w * b4.z; acc[3][3] += a4.w * b4.w;
    }
#pragma unroll
    for (int i = 0; i < 2; ++i) { av[i] = av2[i]; wv[i] = wv2[i]; }
  }
  const int n = n0 + (tx << 2);
  float4 bb = make_float4(0.f, 0.f, 0.f, 0.f);
  if (g.bias) bb = *(const float4*)(g.bias + n);
#pragma unroll
  for (int i = 0; i < 4; ++i) {
    const int m = m0 + (ty << 2) + i;
    float4 v = make_float4(acc[i][0] + bb.x, acc[i][1] + bb.y, acc[i][2] + bb.z, acc[i][3] + bb.w);
    if (CMODE == 0) {
      if (g.act) { v.x = tanhf(v.x); v.y = tanhf(v.y); v.z = tanhf(v.z); v.w = tanhf(v.w); }
      *(float4*)(g.C + (size_t)m * g.ldc + n) = v;
    } else {
      __half2* cp = (__half2*)(g.Ch + (size_t)m * g.ldc + n);
      cp[0] = __floats2half2_rn(v.x, v.y);
      cp[1] = __floats2half2_rn(v.z, v.w);
    }
  }
}

// =================== fused decoder attention step (fp16 enc_out/proj) ===================
__global__ __launch_bounds__(1024)
void attn_k(const float* __restrict__ out, const int* __restrict__ tgt,
            const float* __restrict__ q, const __half* __restrict__ proj,
            const float* __restrict__ va, const int* __restrict__ src,
            const __half* __restrict__ enc, const float* __restrict__ dec_emb,
            float* __restrict__ predin, int* __restrict__ tokbuf, int t)
{
  const int b = blockIdx.x, tid = threadIdx.x;
  const int lane = tid & 63, wv = tid >> 6;
  __shared__ float sm[128];
  __shared__ float tr[128];
  __shared__ float rv[4];
  __shared__ int ri[4];
  __shared__ int tok_s;
  if (t == 0) {
    if (tid == 0) tok_s = tgt[(size_t)b * T_];
  } else {
    if (tid < 256) {
      float av = out[((size_t)b * (T_ - 1) + (t - 1)) * V_ + tid];
      int ai = tid;
      for (int off = 32; off; off >>= 1) {
        const float ov = __shfl_down(av, off);
        const int   oi = __shfl_down(ai, off);
        if (ov > av) { av = ov; ai = oi; }   // strict >: first-max semantics
      }
      if (lane == 0) { rv[wv] = av; ri[wv] = ai; }
    }
    __syncthreads();
    if (tid == 0) {
      float bv = rv[0]; int bi = ri[0];
      for (int w = 1; w < 4; ++w) if (rv[w] > bv) { bv = rv[w]; bi = ri[w]; }
      tok_s = bi;
    }
  }
  __syncthreads();
  const int tok = tok_s;
  if (tid == 0) tokbuf[b] = tok;
  if (tid < E_) predin[(size_t)b * 3584 + 3072 + tid] = dec_emb[(size_t)tok * E_ + tid];
  const float* qb = q + (size_t)b * H_;
  for (int s = wv * 6; s < wv * 6 + 6; ++s) {
    const __half* pb = proj + ((size_t)b * S_ + s) * H_;
    float part = 0.f;
#pragma unroll
    for (int j = 0; j < 8; ++j) {
      const int h = lane * 2 + j * 128;
      const __half2 p2 = *(const __half2*)(pb + h);
      const float2 q2 = *(const float2*)(qb + h);
      const float2 v2 = *(const float2*)(va + h);
      part += v2.x * tanhf(q2.x + __half2float(p2.x));
      part += v2.y * tanhf(q2.y + __half2float(p2.y));
    }
    for (int off = 32; off; off >>= 1) part += __shfl_down(part, off);
    if (lane == 0)
      sm[s] = (src[(size_t)b * S_ + s] == 0) ? -1.0e9f : part;
  }
  __syncthreads();
  if (tid < 128) tr[tid] = (tid < S_) ? sm[tid] : -3.0e38f;
  __syncthreads();
  for (int s2 = 64; s2 > 0; s2 >>= 1) { if (tid < s2) tr[tid] = fmaxf(tr[tid], tr[tid + s2]); __syncthreads(); }
  const float mx = tr[0];
  __syncthreads();
  if (tid < 128) tr[tid] = (tid < S_) ? expf(sm[tid] - mx) : 0.f;
  __syncthreads();
  for (int s2 = 64; s2 > 0; s2 >>= 1) { if (tid < s2) tr[tid] += tr[tid + s2]; __syncthreads(); }
  const float inv = 1.0f / tr[0];
  __syncthreads();
  if (tid < S_) sm[tid] = expf(sm[tid] - mx) * inv;
  __syncthreads();
  const int d = tid * 2;
  const __half* eb = enc + (size_t)b * S_ * (2 * H_) + d;
  float c0 = 0.f, c1 = 0.f;
  for (int s0 = 0; s0 < S_; s0 += 8) {
    __half2 v[8];
#pragma unroll
    for (int i = 0; i < 8; ++i) v[i] = *(const __half2*)(eb + (size_t)(s0 + i) * (2 * H_));
#pragma unroll
    for (int i = 0; i < 8; ++i) {
      const float w = sm[s0 + i];
      c0 += w * __half2float(v[i].x);
      c1 += w * __half2float(v[i].y);
    }
  }
  *(float2*)(predin + (size_t)b * 3584 + H_ + d) = make_float2(c0, c1);
}

// =================== misc ===================
__global__ void zero_k(float* __restrict__ p, int n)
{
  const int i = blockIdx.x * 256 + threadIdx.x;
  if (i < n) p[i] = 0.0f;
}

__global__ void sentinel_k(float* out, float v) { out[threadIdx.x] = v; }

// =================== host orchestration ===================
extern "C" void kernel_launch(void* const* d_in, const int* in_sizes, int n_in,
                              void* d_out, int out_size, void* d_ws, size_t ws_size,
                              hipStream_t stream)
{
  const int*   src        = (const int*)d_in[0];
  const int*   tgt        = (const int*)d_in[1];
  const int*   mode_idx   = (const int*)d_in[2];
  const int*   tense_idx  = (const int*)d_in[3];
  const int*   person_idx = (const int*)d_in[4];
  const float* enc_emb    = (const float*)d_in[5];
  const float* eWih_f     = (const float*)d_in[6];
  const float* eWhh_f     = (const float*)d_in[7];
  const float* ebih_f     = (const float*)d_in[8];
  const float* ebhh_f     = (const float*)d_in[9];
  const float* eWih_b     = (const float*)d_in[10];
  const float* eWhh_b     = (const float*)d_in[11];
  const float* ebih_b     = (const float*)d_in[12];
  const float* ebhh_b     = (const float*)d_in[13];
  const float* Wa         = (const float*)d_in[14];
  const float* va         = (const float*)d_in[15];
  const float* dec_emb    = (const float*)d_in[16];
  const float* dWih       = (const float*)d_in[17];
  const float* dWhh       = (const float*)d_in[18];
  const float* dbih       = (const float*)d_in[19];
  const float* dbhh       = (const float*)d_in[20];
  const float* Wfc        = (const float*)d_in[21];
  const float* bfc        = (const float*)d_in[22];
  const float* mode_E     = (const float*)d_in[23];
  const float* tense_E    = (const float*)d_in[24];
  const float* person_E   = (const float*)d_in[25];
  const float* Wbr        = (const float*)d_in[26];
  const float* bbr        = (const float*)d_in[27];
  float* out = (float*)d_out;

  // ---- workspace carve (~172 MB) ----
  char* base = (char*)d_ws;
  size_t off = 0;
  auto alloc = [&](size_t bytes) { char* r = base + off; off = (off + bytes + 255) & ~(size_t)255; return r; };
  __half* enc_out = (__half*)alloc(2ull * B_ * S_ * 2 * H_);   // 100.7 MB
  __half* proj    = (__half*)alloc(2ull * B_ * S_ * H_);       // 50.3 MB
  float* Gi_f  = (float*)alloc(4ull * V_ * 3 * H_);   // token tables (3.1 MB each)
  float* Gi_b  = (float*)alloc(4ull * V_ * 3 * H_);
  float* Gd    = (float*)alloc(4ull * V_ * 3 * H_);
  float* hfA   = (float*)alloc(4ull * B_ * H_);
  float* hfB   = (float*)alloc(4ull * B_ * H_);
  float* hbA   = (float*)alloc(4ull * B_ * H_);
  float* hbB   = (float*)alloc(4ull * B_ * H_);
  float* h_d0  = (float*)alloc(4ull * B_ * H_);
  float* h_d1  = (float*)alloc(4ull * B_ * H_);
  float* q     = (float*)alloc(4ull * B_ * H_);
  float* predin = (float*)alloc(4ull * B_ * 3584);
  int*   tok   = (int*)alloc(4ull * B_);
  float* zero_buf = (float*)alloc(4ull * 1024);
  if (off > ws_size) {
    hipLaunchKernelGGL(sentinel_k, dim3(1), dim3(256), 0, stream, out,
                       1000.0f + (float)(ws_size >> 20));
    return;
  }

  hipLaunchKernelGGL(zero_k, dim3(4), dim3(256), 0, stream, zero_buf, 1024);

  GB Z{};

  // ---- token tables: Gi_f/Gi_b = enc_emb @ eWih^T ; Gd = dec_emb @ dWih[:,:512]^T ----
  {
    GB t0 = Z, t1 = Z;
    t0.A = enc_emb; t0.lda = E_; t0.W = eWih_f; t0.ldw = E_;
    t0.C = Gi_f; t0.ldc = 3 * H_; t0.M = V_; t0.N = 3 * H_; t0.K = E_;
    t1 = t0; t1.W = eWih_b; t1.C = Gi_b;
    hipLaunchKernelGGL((gemm_k<0, 0>), dim3(48, 4, 2), dim3(256), 0, stream, t0, t1);
    GB t2 = Z;
    t2.A = dec_emb; t2.lda = E_; t2.W = dWih; t2.ldw = 2560;
    t2.C = Gd; t2.ldc = 3 * H_; t2.M = V_; t2.N = 3 * H_; t2.K = E_;
    hipLaunchKernelGGL((gemm_k<0, 0>), dim3(48, 4, 1), dim3(256), 0, stream, t2, t2);
  }

  // ---- encoder: 96 steps, hidden GEMM only (K=1024) + table gather ----
  for (int t = 0; t < S_; ++t) {
    RS rs{};
    rs.gidx = src; rs.goff0 = t; rs.goff1 = S_ - 1 - t;
    rs.Gt0 = Gi_f; rs.Gt1 = Gi_b;
    if (t == 0) { rs.h0 = zero_buf; rs.h1 = zero_buf; rs.ldh = 0; }
    else if (t & 1) { rs.h0 = hfA; rs.h1 = hbA; rs.ldh = H_; }
    else            { rs.h0 = hfB; rs.h1 = hbB; rs.ldh = H_; }
    rs.Whh0 = eWhh_f; rs.Whh1 = eWhh_b;
    rs.bih0 = ebih_f; rs.bih1 = ebih_b; rs.bhh0 = ebhh_f; rs.bhh1 = ebhh_b;
    if (t & 1) { rs.d0 = hfB; rs.d1 = hbB; } else { rs.d0 = hfA; rs.d1 = hbA; }
    rs.ldd = H_;
    rs.e0 = enc_out + (size_t)t * 2 * H_;
    rs.e1 = enc_out + (size_t)(S_ - 1 - t) * 2 * H_ + H_;
    rs.lde = S_ * 2 * H_;
    hipLaunchKernelGGL((rnnstep_k<0>), dim3(512), dim3(256), 0, stream, rs);
  }
  float* hf_fin = hfB;   // t=95 (odd) wrote hfB/hbB
  float* hb_fin = hbB;

  // ---- enc_proj (fp16 A, fp16 out) ----
  {
    GB ep = Z;
    ep.Ah = enc_out; ep.lda = 2 * H_; ep.W = Wa + H_; ep.ldw = 3 * H_;
    ep.Ch = proj; ep.ldc = H_; ep.M = B_ * S_; ep.N = H_; ep.K = 2 * H_;
    hipLaunchKernelGGL((gemm_k<4, 1>), dim3(16, 384, 1), dim3(256), 0, stream, ep, ep);
  }

  // ---- dec_h0 = tanh(cond @ Wbr.T + bbr) ----
  {
    GB br = Z;
    br.W = Wbr; br.ldw = 2432; br.bias = bbr; br.C = h_d0; br.ldc = H_;
    br.M = B_; br.N = H_; br.K = 2432; br.act = 1;
    br.hf = hf_fin; br.hb = hb_fin; br.ldh = H_;
    br.mE = mode_E; br.tE = tense_E; br.pE = person_E;
    br.mi = mode_idx; br.ti = tense_idx; br.pi = person_idx;
    hipLaunchKernelGGL((gemm_k<2, 0>), dim3(16, 4, 1), dim3(256), 0, stream, br, br);
  }

  // ---- q(0) ----
  {
    GB qa = Z;
    qa.A = h_d0; qa.lda = H_; qa.W = Wa; qa.ldw = 3 * H_; qa.C = q; qa.ldc = H_;
    qa.M = B_; qa.N = H_; qa.K = H_;
    hipLaunchKernelGGL((gemm_k<0, 0>), dim3(16, 4, 1), dim3(256), 0, stream, qa, qa);
  }

  // ---- decoder: 39 steps x (attn, rnnstep ctx+hidden, pred+qa) ----
  float* hd[2] = { h_d0, h_d1 };
  for (int t = 0; t < T_ - 1; ++t) {
    hipLaunchKernelGGL(attn_k, dim3(B_), dim3(1024), 0, stream,
                       out, tgt, q, proj, va, src, enc_out, dec_emb, predin, tok, t);

    RS rs{};
    rs.A1 = predin + 1024;        // ctx region
    rs.tok = tok; rs.Gt0 = Gd; rs.Gt1 = Gd;
    rs.h0 = hd[t & 1]; rs.h1 = hd[t & 1]; rs.ldh = H_;
    rs.Wih0 = dWih + 512;         // ctx cols of dWih
    rs.Whh0 = dWhh; rs.Whh1 = dWhh;
    rs.bih0 = dbih; rs.bih1 = dbih; rs.bhh0 = dbhh; rs.bhh1 = dbhh;
    rs.d0 = hd[(t + 1) & 1]; rs.d1 = hd[(t + 1) & 1]; rs.ldd = H_;
    rs.predin = predin;
    hipLaunchKernelGGL((rnnstep_k<1>), dim3(256), dim3(256), 0, stream, rs);

    hipLaunchKernelGGL(prqa_k, dim3(512), dim3(256), 0, stream,
                       predin, Wfc, bfc, hd[(t + 1) & 1], Wa,
                       out + (size_t)t * V_, q);
  }
}

// Round 11
// 20702.208 us; speedup vs baseline: 2.2443x; 1.0915x over previous
//
#include <hip/hip_runtime.h>
#include <hip/hip_fp16.h>
#include <cstdint>
#include <cstddef>

#define B_  256
#define S_  96
#define T_  40
#define V_  256
#define E_  512
#define H_  1024
#define C_  128

__device__ __forceinline__ float sigmoidf_(float x) { return 1.0f / (1.0f + expf(-x)); }

// =================== encoder step: hidden GEMM (K=1024) + table gather + gate ===========
// q-tile 32, QN=4 per thread, TM=64, RM=2. 256 blocks, XCD-swizzled (m fastest).
struct ES {
  const int* gidx; int goff0, goff1;
  const float* Gt0; const float* Gt1;    // token tables [V][3H]
  const float* h0; const float* h1; int ldh;   // f32 h src (ldh=0 -> zero_buf)
  const float* Whh0; const float* Whh1;  // [3H][H]
  const float* bih0; const float* bih1;
  const float* bhh0; const float* bhh1;
  float* d0; float* d1;                  // f32 h dst (ld = H)
  __half* e0; __half* e1; int lde;       // fp16 enc_out slices
};

__global__ __launch_bounds__(256)
void enc_step_k(ES g)
{
  // decode: 256 blocks = 4 m x 2 dir x 32 q  (m fastest)
  const int fid = (blockIdx.x & 7) * 32 + (blockIdx.x >> 3);
  const int m0 = (fid & 3) * 64;
  const int r2 = fid >> 2;
  const int dir = r2 & 1;
  const int q0 = (r2 >> 1) * 32;

  __shared__ float As[32][66];
  __shared__ float Ws[3][32][36];
  __shared__ int rows[64];
  const int tid = threadIdx.x;
  const int tx = tid & 7;                // 4 q cols each -> 32
  const int ty = tid >> 3;               // 2 rows each -> 64
  const int wrow = tid >> 3;             // 32 weight q-rows
  const int wk4 = (tid & 7) << 2;        // k quad
  const float* Whh = dir ? g.Whh1 : g.Whh0;
  const float* hsrc = dir ? g.h1 : g.h0;

  if (tid < 64)
    rows[tid] = g.gidx[(size_t)(m0 + tid) * S_ + (dir ? g.goff1 : g.goff0)];
  __syncthreads();

  float ar[2][4] = {}, az[2][4] = {}, an[2][4] = {};
  float4 av[2], av2[2], wv[3], wv2[3];

  auto load_tile = [&](int kb, float4 (&AV)[2], float4 (&WV)[3]) {
#pragma unroll
    for (int i = 0; i < 2; ++i) {
      const int f = tid + i * 256;
      const int arow = f >> 3, ka = (f & 7) << 2;
      AV[i] = *(const float4*)(hsrc + (size_t)(m0 + arow) * g.ldh + kb + ka);
    }
#pragma unroll
    for (int th = 0; th < 3; ++th)
      WV[th] = *(const float4*)(Whh + (size_t)(th * H_ + q0 + wrow) * H_ + kb + wk4);
  };

  load_tile(0, av, wv);
  for (int kt = 0; kt < 32; ++kt) {
    __syncthreads();
#pragma unroll
    for (int i = 0; i < 2; ++i) {
      const int f = tid + i * 256;
      const int arow = f >> 3, ka = (f & 7) << 2;
      As[ka + 0][arow] = av[i].x; As[ka + 1][arow] = av[i].y;
      As[ka + 2][arow] = av[i].z; As[ka + 3][arow] = av[i].w;
    }
#pragma unroll
    for (int th = 0; th < 3; ++th) {
      Ws[th][wk4 + 0][wrow] = wv[th].x; Ws[th][wk4 + 1][wrow] = wv[th].y;
      Ws[th][wk4 + 2][wrow] = wv[th].z; Ws[th][wk4 + 3][wrow] = wv[th].w;
    }
    __syncthreads();
    if (kt + 1 < 32) load_tile((kt + 1) * 32, av2, wv2);
#pragma unroll
    for (int k = 0; k < 32; ++k) {
      const float2 a2 = *(const float2*)&As[k][ty << 1];
      const float am[2] = { a2.x, a2.y };
      const float4 wr = *(const float4*)&Ws[0][k][tx << 2];
      const float4 wz = *(const float4*)&Ws[1][k][tx << 2];
      const float4 wn = *(const float4*)&Ws[2][k][tx << 2];
#pragma unroll
      for (int i = 0; i < 2; ++i) {
        ar[i][0] += am[i] * wr.x; ar[i][1] += am[i] * wr.y;
        ar[i][2] += am[i] * wr.z; ar[i][3] += am[i] * wr.w;
        az[i][0] += am[i] * wz.x; az[i][1] += am[i] * wz.y;
        az[i][2] += am[i] * wz.z; az[i][3] += am[i] * wz.w;
        an[i][0] += am[i] * wn.x; an[i][1] += am[i] * wn.y;
        an[i][2] += am[i] * wn.z; an[i][3] += am[i] * wn.w;
      }
    }
#pragma unroll
    for (int i = 0; i < 2; ++i) av[i] = av2[i];
#pragma unroll
    for (int th = 0; th < 3; ++th) wv[th] = wv2[th];
  }

  // ---------- gate epilogue (QN=4, float4) ----------
  const float* bih = dir ? g.bih1 : g.bih0;
  const float* bhh = dir ? g.bhh1 : g.bhh0;
  const float* Gt = dir ? g.Gt1 : g.Gt0;
  float* dst = dir ? g.d1 : g.d0;
  __half* edst = dir ? g.e1 : g.e0;
  const int qq = q0 + (tx << 2);
  const float4 bir = *(const float4*)(bih + qq);
  const float4 biz = *(const float4*)(bih + H_ + qq);
  const float4 bin = *(const float4*)(bih + 2 * H_ + qq);
  const float4 bhr = *(const float4*)(bhh + qq);
  const float4 bhz = *(const float4*)(bhh + H_ + qq);
  const float4 bhn = *(const float4*)(bhh + 2 * H_ + qq);
#pragma unroll
  for (int i = 0; i < 2; ++i) {
    const int b = m0 + (ty << 1) + i;
    const float* Gr = Gt + (size_t)rows[b - m0] * (3 * H_);
    const float4 g_r = *(const float4*)(Gr + qq);
    const float4 g_z = *(const float4*)(Gr + H_ + qq);
    const float4 g_n = *(const float4*)(Gr + 2 * H_ + qq);
    const float4 hold = *(const float4*)(hsrc + (size_t)b * g.ldh + qq);
    float4 hv;
    {
      float r, z, n;
      r = sigmoidf_(ar[i][0] + g_r.x + bir.x + bhr.x);
      z = sigmoidf_(az[i][0] + g_z.x + biz.x + bhz.x);
      n = tanhf(g_n.x + bin.x + r * (an[i][0] + bhn.x));
      hv.x = (1.f - z) * n + z * hold.x;
      r = sigmoidf_(ar[i][1] + g_r.y + bir.y + bhr.y);
      z = sigmoidf_(az[i][1] + g_z.y + biz.y + bhz.y);
      n = tanhf(g_n.y + bin.y + r * (an[i][1] + bhn.y));
      hv.y = (1.f - z) * n + z * hold.y;
      r = sigmoidf_(ar[i][2] + g_r.z + bir.z + bhr.z);
      z = sigmoidf_(az[i][2] + g_z.z + biz.z + bhz.z);
      n = tanhf(g_n.z + bin.z + r * (an[i][2] + bhn.z));
      hv.z = (1.f - z) * n + z * hold.z;
      r = sigmoidf_(ar[i][3] + g_r.w + bir.w + bhr.w);
      z = sigmoidf_(az[i][3] + g_z.w + biz.w + bhz.w);
      n = tanhf(g_n.w + bin.w + r * (an[i][3] + bhn.w));
      hv.w = (1.f - z) * n + z * hold.w;
    }
    *(float4*)(dst + (size_t)b * H_ + qq) = hv;
    __half2* ep = (__half2*)(edst + (size_t)b * g.lde + qq);
    ep[0] = __floats2half2_rn(hv.x, hv.y);
    ep[1] = __floats2half2_rn(hv.z, hv.w);
  }
}

// =================== decoder step: ctx GEMM (K=2048) + hidden GEMM + gate ===============
struct DS {
  const float* A1;                       // predin + 1024 (ctx region), row stride 3584
  const int* tok;
  const float* Gd;                       // [V][3H]
  const float* h; 
  const float* Wih;                      // dWih + 512, row stride 2560
  const float* Whh;
  const float* bih; const float* bhh;
  float* d;
  float* predin;
};

__global__ __launch_bounds__(256)
void dec_step_k(DS g)
{
  // 256 blocks = 4 m x 64 q (m fastest), XCD swizzle
  const int fid = (blockIdx.x & 7) * 32 + (blockIdx.x >> 3);
  const int m0 = (fid & 3) * 64;
  const int q0 = (fid >> 2) * 16;

  __shared__ float As[32][66];
  __shared__ float Ws[3][32][22];
  const int tid = threadIdx.x;
  const int tx = tid & 7, ty = tid >> 3;
  const int wrow = tid >> 4, wk2 = (tid & 15) << 1;

  float ar[2][2] = {}, az[2][2] = {}, anI[2][2] = {}, anH[2][2] = {};
  float4 av[2], av2[2];
  float2 wv[3], wv2[3];

  auto load_tile = [&](int kb, float4 (&AV)[2], float2 (&WV)[3]) {
    if (kb < 2048) {
#pragma unroll
      for (int i = 0; i < 2; ++i) {
        const int f = tid + i * 256;
        const int arow = f >> 3, ka = (f & 7) << 2;
        AV[i] = *(const float4*)(g.A1 + (size_t)(m0 + arow) * 3584 + kb + ka);
      }
#pragma unroll
      for (int th = 0; th < 3; ++th)
        WV[th] = *(const float2*)(g.Wih + (size_t)(th * H_ + q0 + wrow) * 2560 + kb + wk2);
    } else {
      const int kb2 = kb - 2048;
#pragma unroll
      for (int i = 0; i < 2; ++i) {
        const int f = tid + i * 256;
        const int arow = f >> 3, ka = (f & 7) << 2;
        AV[i] = *(const float4*)(g.h + (size_t)(m0 + arow) * H_ + kb2 + ka);
      }
#pragma unroll
      for (int th = 0; th < 3; ++th)
        WV[th] = *(const float2*)(g.Whh + (size_t)(th * H_ + q0 + wrow) * H_ + kb2 + wk2);
    }
  };

  auto compute_tile = [&](float (&an)[2][2]) {
#pragma unroll
    for (int k = 0; k < 32; ++k) {
      const float2 a2 = *(const float2*)&As[k][ty << 1];
      const float am[2] = { a2.x, a2.y };
      const float2 wr = *(const float2*)&Ws[0][k][tx << 1];
      const float2 wz = *(const float2*)&Ws[1][k][tx << 1];
      const float2 wn = *(const float2*)&Ws[2][k][tx << 1];
#pragma unroll
      for (int i = 0; i < 2; ++i) {
        ar[i][0] += am[i] * wr.x; ar[i][1] += am[i] * wr.y;
        az[i][0] += am[i] * wz.x; az[i][1] += am[i] * wz.y;
        an[i][0] += am[i] * wn.x; an[i][1] += am[i] * wn.y;
      }
    }
  };

  load_tile(0, av, wv);
  for (int kt = 0; kt < 96; ++kt) {
    __syncthreads();
#pragma unroll
    for (int i = 0; i < 2; ++i) {
      const int f = tid + i * 256;
      const int arow = f >> 3, ka = (f & 7) << 2;
      As[ka + 0][arow] = av[i].x; As[ka + 1][arow] = av[i].y;
      As[ka + 2][arow] = av[i].z; As[ka + 3][arow] = av[i].w;
    }
#pragma unroll
    for (int th = 0; th < 3; ++th) {
      Ws[th][wk2 + 0][wrow] = wv[th].x;
      Ws[th][wk2 + 1][wrow] = wv[th].y;
    }
    __syncthreads();
    if (kt + 1 < 96) load_tile((kt + 1) * 32, av2, wv2);
    if (kt < 64) compute_tile(anI); else compute_tile(anH);
#pragma unroll
    for (int i = 0; i < 2; ++i) av[i] = av2[i];
#pragma unroll
    for (int th = 0; th < 3; ++th) wv[th] = wv2[th];
  }

  const int qq = q0 + (tx << 1);
  const float2 bir = *(const float2*)(g.bih + qq);
  const float2 biz = *(const float2*)(g.bih + H_ + qq);
  const float2 bin = *(const float2*)(g.bih + 2 * H_ + qq);
  const float2 bhr = *(const float2*)(g.bhh + qq);
  const float2 bhz = *(const float2*)(g.bhh + H_ + qq);
  const float2 bhn = *(const float2*)(g.bhh + 2 * H_ + qq);
#pragma unroll
  for (int i = 0; i < 2; ++i) {
    const int b = m0 + (ty << 1) + i;
    const float* Gr = g.Gd + (size_t)g.tok[b] * (3 * H_);
    const float2 g_r = *(const float2*)(Gr + qq);
    const float2 g_z = *(const float2*)(Gr + H_ + qq);
    const float2 g_n = *(const float2*)(Gr + 2 * H_ + qq);
    const float2 hold = *(const float2*)(g.h + (size_t)b * H_ + qq);
    float2 hv;
    float r = sigmoidf_(ar[i][0] + g_r.x + bir.x + bhr.x);
    float z = sigmoidf_(az[i][0] + g_z.x + biz.x + bhz.x);
    float n = tanhf(anI[i][0] + g_n.x + bin.x + r * (anH[i][0] + bhn.x));
    hv.x = (1.f - z) * n + z * hold.x;
    r = sigmoidf_(ar[i][1] + g_r.y + bir.y + bhr.y);
    z = sigmoidf_(az[i][1] + g_z.y + biz.y + bhz.y);
    n = tanhf(anI[i][1] + g_n.y + bin.y + r * (anH[i][1] + bhn.y));
    hv.y = (1.f - z) * n + z * hold.y;
    *(float2*)(g.d + (size_t)b * H_ + qq) = hv;
    *(float2*)(g.predin + (size_t)b * 3584 + qq) = hv;
  }
}

// =================== attn part 1: argmax + emb + scores + softmax ===================
__global__ __launch_bounds__(512)
void attn1_k(const float* __restrict__ out, const int* __restrict__ tgt,
             const float* __restrict__ q, const __half* __restrict__ proj,
             const float* __restrict__ va, const int* __restrict__ src,
             const float* __restrict__ dec_emb,
             float* __restrict__ predin, float* __restrict__ wts,
             int* __restrict__ tokbuf, int t)
{
  const int b = blockIdx.x, tid = threadIdx.x;
  const int lane = tid & 63, wv = tid >> 6;
  __shared__ float sm[128];
  __shared__ float tr[128];
  __shared__ float rv[4];
  __shared__ int ri[4];
  __shared__ int tok_s;
  if (t == 0) {
    if (tid == 0) tok_s = tgt[(size_t)b * T_];
  } else {
    if (tid < 256) {
      float av = out[((size_t)b * (T_ - 1) + (t - 1)) * V_ + tid];
      int ai = tid;
      for (int off = 32; off; off >>= 1) {
        const float ov = __shfl_down(av, off);
        const int   oi = __shfl_down(ai, off);
        if (ov > av) { av = ov; ai = oi; }   // strict >: first-max semantics
      }
      if (lane == 0) { rv[wv] = av; ri[wv] = ai; }
    }
    __syncthreads();
    if (tid == 0) {
      float bv = rv[0]; int bi = ri[0];
      for (int w = 1; w < 4; ++w) if (rv[w] > bv) { bv = rv[w]; bi = ri[w]; }
      tok_s = bi;
    }
  }
  __syncthreads();
  const int tok = tok_s;
  if (tid == 0) tokbuf[b] = tok;
  predin[(size_t)b * 3584 + 3072 + tid] = dec_emb[(size_t)tok * E_ + tid];
  // scores: 8 waves x 12 s
  const float* qb = q + (size_t)b * H_;
  for (int s = wv * 12; s < wv * 12 + 12; ++s) {
    const __half* pb = proj + ((size_t)b * S_ + s) * H_;
    float part = 0.f;
#pragma unroll
    for (int j = 0; j < 8; ++j) {
      const int h = lane * 2 + j * 128;
      const __half2 p2 = *(const __half2*)(pb + h);
      const float2 q2 = *(const float2*)(qb + h);
      const float2 v2 = *(const float2*)(va + h);
      part += v2.x * tanhf(q2.x + __half2float(p2.x));
      part += v2.y * tanhf(q2.y + __half2float(p2.y));
    }
    for (int off = 32; off; off >>= 1) part += __shfl_down(part, off);
    if (lane == 0)
      sm[s] = (src[(size_t)b * S_ + s] == 0) ? -1.0e9f : part;
  }
  __syncthreads();
  if (tid < 128) tr[tid] = (tid < S_) ? sm[tid] : -3.0e38f;
  __syncthreads();
  for (int s2 = 64; s2 > 0; s2 >>= 1) { if (tid < s2) tr[tid] = fmaxf(tr[tid], tr[tid + s2]); __syncthreads(); }
  const float mx = tr[0];
  __syncthreads();
  if (tid < 128) tr[tid] = (tid < S_) ? expf(sm[tid] - mx) : 0.f;
  __syncthreads();
  for (int s2 = 64; s2 > 0; s2 >>= 1) { if (tid < s2) tr[tid] += tr[tid + s2]; __syncthreads(); }
  const float inv = 1.0f / tr[0];
  __syncthreads();
  if (tid < S_) wts[(size_t)b * S_ + tid] = expf(sm[tid] - mx) * inv;
}

// =================== attn part 2: ctx (high-occupancy) ===================
// grid (4, B_): block covers 512 dims of b; 2 dims/thread; s-loop unroll 8.
__global__ __launch_bounds__(256)
void ctx_k(const float* __restrict__ wts, const __half* __restrict__ enc,
           float* __restrict__ predin)
{
  const int b = blockIdx.y, tid = threadIdx.x;
  __shared__ float sw[S_];
  if (tid < S_) sw[tid] = wts[(size_t)b * S_ + tid];
  __syncthreads();
  const int d = blockIdx.x * 512 + tid * 2;
  const __half* eb = enc + (size_t)b * S_ * (2 * H_) + d;
  float c0 = 0.f, c1 = 0.f;
  for (int s0 = 0; s0 < S_; s0 += 8) {
    __half2 v[8];
#pragma unroll
    for (int i = 0; i < 8; ++i) v[i] = *(const __half2*)(eb + (size_t)(s0 + i) * (2 * H_));
#pragma unroll
    for (int i = 0; i < 8; ++i) {
      const float w = sw[s0 + i];
      c0 += w * __half2float(v[i].x);
      c1 += w * __half2float(v[i].y);
    }
  }
  *(float2*)(predin + (size_t)b * 3584 + H_ + d) = make_float2(c0, c1);
}

// =================== fused pred-GEMM + q-GEMM (512 blocks) ===================
__global__ __launch_bounds__(256)
void prqa_k(const float* __restrict__ predin,
            const float* __restrict__ Wfc, const float* __restrict__ bfc,
            const float* __restrict__ hnew, const float* __restrict__ Wa,
            float* __restrict__ out_t, float* __restrict__ q)
{
  const int bid = blockIdx.x, tid = threadIdx.x;
  if (bid < 256) {
    const int m0 = (bid >> 4) << 4, n0 = (bid & 15) << 4;
    __shared__ float As[32][17], Ws[32][17];
    const int r = tid >> 4, kq = (tid & 15) << 1;
    const int tym = tid >> 4, txn = tid & 15;
    float acc = 0.f;
    for (int k0 = 0; k0 < 3584; k0 += 32) {
      const float2 a2 = *(const float2*)(predin + (size_t)(m0 + r) * 3584 + k0 + kq);
      const float2 w2 = *(const float2*)(Wfc + (size_t)(n0 + r) * 3584 + k0 + kq);
      __syncthreads();
      As[kq][r] = a2.x; As[kq + 1][r] = a2.y;
      Ws[kq][r] = w2.x; Ws[kq + 1][r] = w2.y;
      __syncthreads();
#pragma unroll
      for (int k = 0; k < 32; ++k)
        acc += As[k][tym] * Ws[k][txn];
    }
    out_t[(size_t)(m0 + tym) * ((T_ - 1) * V_) + n0 + txn] = acc + bfc[n0 + txn];
  } else {
    const int b2 = bid - 256;
    const int m0 = (b2 >> 5) << 5, n0 = (b2 & 31) << 5;
    __shared__ float As[32][34], Ws[32][34];
    const int r = tid >> 3, kq = (tid & 7) << 2;
    const int tx = tid & 15, ty = tid >> 4;
    float acc[2][2] = {};
    for (int k0 = 0; k0 < 1024; k0 += 32) {
      const float4 a4 = *(const float4*)(hnew + (size_t)(m0 + r) * H_ + k0 + kq);
      const float4 w4 = *(const float4*)(Wa + (size_t)(n0 + r) * (3 * H_) + k0 + kq);
      __syncthreads();
      As[kq + 0][r] = a4.x; As[kq + 1][r] = a4.y; As[kq + 2][r] = a4.z; As[kq + 3][r] = a4.w;
      Ws[kq + 0][r] = w4.x; Ws[kq + 1][r] = w4.y; Ws[kq + 2][r] = w4.z; Ws[kq + 3][r] = w4.w;
      __syncthreads();
#pragma unroll
      for (int k = 0; k < 32; ++k) {
        const float2 a2 = *(const float2*)&As[k][ty << 1];
        const float2 w2 = *(const float2*)&Ws[k][tx << 1];
        acc[0][0] += a2.x * w2.x; acc[0][1] += a2.x * w2.y;
        acc[1][0] += a2.y * w2.x; acc[1][1] += a2.y * w2.y;
      }
    }
#pragma unroll
    for (int i = 0; i < 2; ++i)
#pragma unroll
      for (int j = 0; j < 2; ++j)
        q[(size_t)(m0 + (ty << 1) + i) * H_ + n0 + (tx << 1) + j] = acc[i][j];
  }
}

// =================== generic fp32 tiled GEMM (tables / enc_proj / br / q0) ==============
struct GB {
  const float* A; int lda;
  const __half* Ah;
  const float* W; int ldw;
  const float* bias;
  float* C; int ldc;
  __half* Ch;
  int M, N, K, act;
  const float *hf, *hb; int ldh;
  const float *mE, *tE, *pE;
  const int *mi, *ti, *pi;
};

template<int AMODE, int CMODE>
__global__ __launch_bounds__(256)
void gemm_k(GB g0, GB g1)
{
  GB g = blockIdx.z ? g1 : g0;
  const int m0 = blockIdx.y * 64, n0 = blockIdx.x * 64;
  if (m0 >= g.M || n0 >= g.N) return;
  __shared__ float As[32][68];
  __shared__ float Ws[32][68];
  const int tid = threadIdx.x, tx = tid & 15, ty = tid >> 4;
  const int lm = tid >> 3, lk = (tid & 7) << 2;
  float acc[4][4] = {};
  float4 av[2], wv[2], av2[2], wv2[2];

  auto load_tile = [&](int k0, float4 (&AV)[2], float4 (&WV)[2]) {
#pragma unroll
    for (int i = 0; i < 2; ++i) {
      const int row = lm + i * 32;
      const int kk = k0 + lk;
      if (AMODE == 0) {
        AV[i] = *(const float4*)(g.A + (size_t)(m0 + row) * g.lda + kk);
      } else if (AMODE == 4) {
        const __half* ap = g.Ah + (size_t)(m0 + row) * g.lda + kk;
        const __half2 h0 = *(const __half2*)ap;
        const __half2 h1 = *(const __half2*)(ap + 2);
        AV[i] = make_float4(__half2float(h0.x), __half2float(h0.y),
                            __half2float(h1.x), __half2float(h1.y));
      } else {
        const int mg = m0 + row; const float* sp; size_t o;
        if (kk < 1024)      { sp = g.hf; o = (size_t)mg * g.ldh + kk; }
        else if (kk < 2048) { sp = g.hb; o = (size_t)mg * g.ldh + kk - 1024; }
        else if (kk < 2176) { sp = g.mE; o = (size_t)g.mi[mg] * C_ + kk - 2048; }
        else if (kk < 2304) { sp = g.tE; o = (size_t)g.ti[mg] * C_ + kk - 2176; }
        else                { sp = g.pE; o = (size_t)g.pi[mg] * C_ + kk - 2304; }
        AV[i] = *(const float4*)(sp + o);
      }
      WV[i] = *(const float4*)(g.W + (size_t)(n0 + row) * g.ldw + kk);
    }
  };

  load_tile(0, av, wv);
  for (int k0 = 0; k0 < g.K; k0 += 32) {
    __syncthreads();
#pragma unroll
    for (int i = 0; i < 2; ++i) {
      const int row = lm + i * 32;
      As[lk + 0][row] = av[i].x; As[lk + 1][row] = av[i].y;
      As[lk + 2][row] = av[i].z; As[lk + 3][row] = av[i].w;
      Ws[lk + 0][row] = wv[i].x; Ws[lk + 1][row] = wv[i].y;
      Ws[lk + 2][row] = wv[i].z; Ws[lk + 3][row] = wv[i].w;
    }
    __syncthreads();
    if (k0 + 32 < g.K) load_tile(k0 + 32, av2, wv2);
#pragma unroll
    for (int k = 0; k < 32; ++k) {
      const float4 a4 = *(const float4*)&As[k][ty << 2];
      const float4 b4 = *(const float4*)&Ws[k][tx << 2];
      acc[0][0] += a4.x * b4.x; acc[0][1] += a4.x * b4.y; acc[0][2] += a4.x * b4.z; acc[0][3] += a4.x * b4.w;
      acc[1][0] += a4.y * b4.x; acc[1][1] += a4.y * b4.y; acc[1][2] += a4.y * b4.z; acc[1][3] += a4.y * b4.w;
      acc[2][0] += a4.z * b4.x; acc[2][1] += a4.z * b4.y; acc[2][2] += a4.z * b4.z; acc[2][3] += a4.z * b4.w;
      acc[3][0] += a4.w * b4.x; acc[3][1] += a4.w * b4.y; acc[3][2] += a4.w * b4.z; acc[3][3] += a4.w * b4.w;
    }
#pragma unroll
    for (int i = 0; i < 2; ++i) { av[i] = av2[i]; wv[i] = wv2[i]; }
  }
  const int n = n0 + (tx << 2);
  float4 bb = make_float4(0.f, 0.f, 0.f, 0.f);
  if (g.bias) bb = *(const float4*)(g.bias + n);
#pragma unroll
  for (int i = 0; i < 4; ++i) {
    const int m = m0 + (ty << 2) + i;
    float4 v = make_float4(acc[i][0] + bb.x, acc[i][1] + bb.y, acc[i][2] + bb.z, acc[i][3] + bb.w);
    if (CMODE == 0) {
      if (g.act) { v.x = tanhf(v.x); v.y = tanhf(v.y); v.z = tanhf(v.z); v.w = tanhf(v.w); }
      *(float4*)(g.C + (size_t)m * g.ldc + n) = v;
    } else {
      __half2* cp = (__half2*)(g.Ch + (size_t)m * g.ldc + n);
      cp[0] = __floats2half2_rn(v.x, v.y);
      cp[1] = __floats2half2_rn(v.z, v.w);
    }
  }
}

// =================== misc ===================
__global__ void zero_k(float* __restrict__ p, int n)
{
  const int i = blockIdx.x * 256 + threadIdx.x;
  if (i < n) p[i] = 0.0f;
}

__global__ void sentinel_k(float* out, float v) { out[threadIdx.x] = v; }

// =================== host orchestration ===================
extern "C" void kernel_launch(void* const* d_in, const int* in_sizes, int n_in,
                              void* d_out, int out_size, void* d_ws, size_t ws_size,
                              hipStream_t stream)
{
  const int*   src        = (const int*)d_in[0];
  const int*   tgt        = (const int*)d_in[1];
  const int*   mode_idx   = (const int*)d_in[2];
  const int*   tense_idx  = (const int*)d_in[3];
  const int*   person_idx = (const int*)d_in[4];
  const float* enc_emb    = (const float*)d_in[5];
  const float* eWih_f     = (const float*)d_in[6];
  const float* eWhh_f     = (const float*)d_in[7];
  const float* ebih_f     = (const float*)d_in[8];
  const float* ebhh_f     = (const float*)d_in[9];
  const float* eWih_b     = (const float*)d_in[10];
  const float* eWhh_b     = (const float*)d_in[11];
  const float* ebih_b     = (const float*)d_in[12];
  const float* ebhh_b     = (const float*)d_in[13];
  const float* Wa         = (const float*)d_in[14];
  const float* va         = (const float*)d_in[15];
  const float* dec_emb    = (const float*)d_in[16];
  const float* dWih       = (const float*)d_in[17];
  const float* dWhh       = (const float*)d_in[18];
  const float* dbih       = (const float*)d_in[19];
  const float* dbhh       = (const float*)d_in[20];
  const float* Wfc        = (const float*)d_in[21];
  const float* bfc        = (const float*)d_in[22];
  const float* mode_E     = (const float*)d_in[23];
  const float* tense_E    = (const float*)d_in[24];
  const float* person_E   = (const float*)d_in[25];
  const float* Wbr        = (const float*)d_in[26];
  const float* bbr        = (const float*)d_in[27];
  float* out = (float*)d_out;

  // ---- workspace carve (~172 MB) ----
  char* base = (char*)d_ws;
  size_t off = 0;
  auto alloc = [&](size_t bytes) { char* r = base + off; off = (off + bytes + 255) & ~(size_t)255; return r; };
  __half* enc_out = (__half*)alloc(2ull * B_ * S_ * 2 * H_);   // 100.7 MB
  __half* proj    = (__half*)alloc(2ull * B_ * S_ * H_);       // 50.3 MB
  float* Gi_f  = (float*)alloc(4ull * V_ * 3 * H_);
  float* Gi_b  = (float*)alloc(4ull * V_ * 3 * H_);
  float* Gd    = (float*)alloc(4ull * V_ * 3 * H_);
  float* hfA   = (float*)alloc(4ull * B_ * H_);
  float* hfB   = (float*)alloc(4ull * B_ * H_);
  float* hbA   = (float*)alloc(4ull * B_ * H_);
  float* hbB   = (float*)alloc(4ull * B_ * H_);
  float* h_d0  = (float*)alloc(4ull * B_ * H_);
  float* h_d1  = (float*)alloc(4ull * B_ * H_);
  float* q     = (float*)alloc(4ull * B_ * H_);
  float* predin = (float*)alloc(4ull * B_ * 3584);
  float* wts   = (float*)alloc(4ull * B_ * S_);
  int*   tok   = (int*)alloc(4ull * B_);
  float* zero_buf = (float*)alloc(4ull * 1024);
  if (off > ws_size) {
    hipLaunchKernelGGL(sentinel_k, dim3(1), dim3(256), 0, stream, out,
                       1000.0f + (float)(ws_size >> 20));
    return;
  }

  hipLaunchKernelGGL(zero_k, dim3(4), dim3(256), 0, stream, zero_buf, 1024);

  GB Z{};

  // ---- token tables ----
  {
    GB t0 = Z, t1 = Z;
    t0.A = enc_emb; t0.lda = E_; t0.W = eWih_f; t0.ldw = E_;
    t0.C = Gi_f; t0.ldc = 3 * H_; t0.M = V_; t0.N = 3 * H_; t0.K = E_;
    t1 = t0; t1.W = eWih_b; t1.C = Gi_b;
    hipLaunchKernelGGL((gemm_k<0, 0>), dim3(48, 4, 2), dim3(256), 0, stream, t0, t1);
    GB t2 = Z;
    t2.A = dec_emb; t2.lda = E_; t2.W = dWih; t2.ldw = 2560;
    t2.C = Gd; t2.ldc = 3 * H_; t2.M = V_; t2.N = 3 * H_; t2.K = E_;
    hipLaunchKernelGGL((gemm_k<0, 0>), dim3(48, 4, 1), dim3(256), 0, stream, t2, t2);
  }

  // ---- encoder: 96 steps ----
  for (int t = 0; t < S_; ++t) {
    ES es{};
    es.gidx = src; es.goff0 = t; es.goff1 = S_ - 1 - t;
    es.Gt0 = Gi_f; es.Gt1 = Gi_b;
    if (t == 0) { es.h0 = zero_buf; es.h1 = zero_buf; es.ldh = 0; }
    else if (t & 1) { es.h0 = hfA; es.h1 = hbA; es.ldh = H_; }
    else            { es.h0 = hfB; es.h1 = hbB; es.ldh = H_; }
    es.Whh0 = eWhh_f; es.Whh1 = eWhh_b;
    es.bih0 = ebih_f; es.bih1 = ebih_b; es.bhh0 = ebhh_f; es.bhh1 = ebhh_b;
    if (t & 1) { es.d0 = hfB; es.d1 = hbB; } else { es.d0 = hfA; es.d1 = hbA; }
    es.e0 = enc_out + (size_t)t * 2 * H_;
    es.e1 = enc_out + (size_t)(S_ - 1 - t) * 2 * H_ + H_;
    es.lde = S_ * 2 * H_;
    hipLaunchKernelGGL(enc_step_k, dim3(256), dim3(256), 0, stream, es);
  }
  float* hf_fin = hfB;   // t=95 (odd) wrote hfB/hbB
  float* hb_fin = hbB;

  // ---- enc_proj (fp16 A, fp16 out) ----
  {
    GB ep = Z;
    ep.Ah = enc_out; ep.lda = 2 * H_; ep.W = Wa + H_; ep.ldw = 3 * H_;
    ep.Ch = proj; ep.ldc = H_; ep.M = B_ * S_; ep.N = H_; ep.K = 2 * H_;
    hipLaunchKernelGGL((gemm_k<4, 1>), dim3(16, 384, 1), dim3(256), 0, stream, ep, ep);
  }

  // ---- dec_h0 ----
  {
    GB br = Z;
    br.W = Wbr; br.ldw = 2432; br.bias = bbr; br.C = h_d0; br.ldc = H_;
    br.M = B_; br.N = H_; br.K = 2432; br.act = 1;
    br.hf = hf_fin; br.hb = hb_fin; br.ldh = H_;
    br.mE = mode_E; br.tE = tense_E; br.pE = person_E;
    br.mi = mode_idx; br.ti = tense_idx; br.pi = person_idx;
    hipLaunchKernelGGL((gemm_k<2, 0>), dim3(16, 4, 1), dim3(256), 0, stream, br, br);
  }

  // ---- q(0) ----
  {
    GB qa = Z;
    qa.A = h_d0; qa.lda = H_; qa.W = Wa; qa.ldw = 3 * H_; qa.C = q; qa.ldc = H_;
    qa.M = B_; qa.N = H_; qa.K = H_;
    hipLaunchKernelGGL((gemm_k<0, 0>), dim3(16, 4, 1), dim3(256), 0, stream, qa, qa);
  }

  // ---- decoder: 39 steps x (attn1, ctx, dec_step, prqa) ----
  float* hd[2] = { h_d0, h_d1 };
  for (int t = 0; t < T_ - 1; ++t) {
    hipLaunchKernelGGL(attn1_k, dim3(B_), dim3(512), 0, stream,
                       out, tgt, q, proj, va, src, dec_emb, predin, wts, tok, t);
    hipLaunchKernelGGL(ctx_k, dim3(4, B_), dim3(256), 0, stream, wts, enc_out, predin);

    DS ds{};
    ds.A1 = predin + 1024;
    ds.tok = tok; ds.Gd = Gd;
    ds.h = hd[t & 1];
    ds.Wih = dWih + 512;
    ds.Whh = dWhh;
    ds.bih = dbih; ds.bhh = dbhh;
    ds.d = hd[(t + 1) & 1];
    ds.predin = predin;
    hipLaunchKernelGGL(dec_step_k, dim3(256), dim3(256), 0, stream, ds);

    hipLaunchKernelGGL(prqa_k, dim3(512), dim3(256), 0, stream,
                       predin, Wfc, bfc, hd[(t + 1) & 1], Wa,
                       out + (size_t)t * V_, q);
  }
}

// Round 12
// 20499.205 us; speedup vs baseline: 2.2665x; 1.0099x over previous
//
#include <hip/hip_runtime.h>
#include <hip/hip_fp16.h>
#include <cstdint>
#include <cstddef>

#define B_  256
#define S_  96
#define T_  40
#define V_  256
#define E_  512
#define H_  1024
#define C_  128

typedef __attribute__((ext_vector_type(8))) short s8v;   // 8 bf16
typedef __attribute__((ext_vector_type(4))) float f4v;   // mfma acc

__device__ __forceinline__ float sigmoidf_(float x) { return 1.0f / (1.0f + expf(-x)); }

__device__ __forceinline__ uint32_t cvtpk_bf16(float a, float b) {
  uint32_t r;
  asm("v_cvt_pk_bf16_f32 %0, %1, %2" : "=v"(r) : "v"(a), "v"(b));
  return r;
}

union U4 { uint32_t u[4]; s8v v; };

// split 8 f32 into bf16 hi + bf16 lo fragments
__device__ __forceinline__ void split8(const float4 a, const float4 b, s8v& hi, s8v& lo) {
  U4 H, L;
  H.u[0] = cvtpk_bf16(a.x, a.y);
  H.u[1] = cvtpk_bf16(a.z, a.w);
  H.u[2] = cvtpk_bf16(b.x, b.y);
  H.u[3] = cvtpk_bf16(b.z, b.w);
  const float r0 = a.x - __uint_as_float(H.u[0] << 16);
  const float r1 = a.y - __uint_as_float(H.u[0] & 0xffff0000u);
  const float r2 = a.z - __uint_as_float(H.u[1] << 16);
  const float r3 = a.w - __uint_as_float(H.u[1] & 0xffff0000u);
  const float r4 = b.x - __uint_as_float(H.u[2] << 16);
  const float r5 = b.y - __uint_as_float(H.u[2] & 0xffff0000u);
  const float r6 = b.z - __uint_as_float(H.u[3] << 16);
  const float r7 = b.w - __uint_as_float(H.u[3] & 0xffff0000u);
  L.u[0] = cvtpk_bf16(r0, r1);
  L.u[1] = cvtpk_bf16(r2, r3);
  L.u[2] = cvtpk_bf16(r4, r5);
  L.u[3] = cvtpk_bf16(r6, r7);
  hi = H.v; lo = L.v;
}

// =================== weight split: f32 -> bf16 hi/lo planes ===================
__global__ void wsplit_k(const float* __restrict__ Wf, const float* __restrict__ Wb,
                         short* __restrict__ hi, short* __restrict__ lo, int n)
{
  const int i = blockIdx.x * 256 + threadIdx.x;   // over 2n
  const float w = (i < n) ? Wf[i] : Wb[i - n];
  const uint32_t h = cvtpk_bf16(w, w) & 0xffffu;
  const float wh = __uint_as_float(h << 16);
  const uint32_t l = cvtpk_bf16(w - wh, w - wh) & 0xffffu;
  hi[i] = (short)h;
  lo[i] = (short)l;
}

// =================== encoder step via MFMA bf16x3 ===================
// 512 blocks = 4 m x 2 dir x 64 q-tiles (m fastest, XCD-swizzled).
// Wave: 16 batch rows x 48 cols (3 gates x 16 q). K=1024, no LDS in k-loop.
struct EM {
  const int* gidx; int goff0, goff1;
  const float* Gt0; const float* Gt1;    // token tables [V][3H]
  const float* h0; const float* h1; int ldh;
  const short* whi; const short* wlo;    // [2][3H][H] bf16 planes (dir-major)
  const float* bih0; const float* bih1;
  const float* bhh0; const float* bhh1;
  float* d0; float* d1;
  __half* e0; __half* e1; int lde;
};

__global__ __launch_bounds__(256)
void enc_mfma_k(EM g)
{
  const int fid = (blockIdx.x & 7) * 64 + (blockIdx.x >> 3);
  const int m0 = (fid & 3) * 64;
  const int r2 = fid >> 2;
  const int dir = r2 & 1;
  const int q0 = (r2 >> 1) * 16;

  __shared__ int rows[64];
  const int tid = threadIdx.x;
  if (tid < 64)
    rows[tid] = g.gidx[(size_t)(m0 + tid) * S_ + (dir ? g.goff1 : g.goff0)];
  __syncthreads();

  const int w = tid >> 6, lane = tid & 63;
  const int arow = m0 + 16 * w + (lane & 15);
  const int kc = (lane >> 4) << 3;                 // k-chunk base (0/8/16/24)
  const float* hsrc = dir ? g.h1 : g.h0;
  const short* whi = g.whi + (size_t)dir * (3u * H_ * H_);
  const short* wlo = g.wlo + (size_t)dir * (3u * H_ * H_);
  const float* ap = hsrc + (size_t)arow * g.ldh;
  const int wrow = q0 + (lane & 15);

  f4v acc[3];
  acc[0] = f4v{0.f, 0.f, 0.f, 0.f};
  acc[1] = f4v{0.f, 0.f, 0.f, 0.f};
  acc[2] = f4v{0.f, 0.f, 0.f, 0.f};

  float4 a0 = *(const float4*)(ap + kc);
  float4 a1 = *(const float4*)(ap + kc + 4);
  s8v bh[3], bl[3];
#pragma unroll
  for (int g3 = 0; g3 < 3; ++g3) {
    const size_t wb = (size_t)(g3 * H_ + wrow) * H_ + kc;
    bh[g3] = *(const s8v*)(whi + wb);
    bl[g3] = *(const s8v*)(wlo + wb);
  }

  for (int kb = 0; kb < 1024; kb += 32) {
    float4 na0, na1;
    s8v nbh[3], nbl[3];
    if (kb + 32 < 1024) {
      na0 = *(const float4*)(ap + kb + 32 + kc);
      na1 = *(const float4*)(ap + kb + 32 + kc + 4);
#pragma unroll
      for (int g3 = 0; g3 < 3; ++g3) {
        const size_t wb = (size_t)(g3 * H_ + wrow) * H_ + kb + 32 + kc;
        nbh[g3] = *(const s8v*)(whi + wb);
        nbl[g3] = *(const s8v*)(wlo + wb);
      }
    }
    s8v ah, al;
    split8(a0, a1, ah, al);
#pragma unroll
    for (int g3 = 0; g3 < 3; ++g3) {
      acc[g3] = __builtin_amdgcn_mfma_f32_16x16x32_bf16(ah, bh[g3], acc[g3], 0, 0, 0);
      acc[g3] = __builtin_amdgcn_mfma_f32_16x16x32_bf16(al, bh[g3], acc[g3], 0, 0, 0);
      acc[g3] = __builtin_amdgcn_mfma_f32_16x16x32_bf16(ah, bl[g3], acc[g3], 0, 0, 0);
    }
    a0 = na0; a1 = na1;
#pragma unroll
    for (int g3 = 0; g3 < 3; ++g3) { bh[g3] = nbh[g3]; bl[g3] = nbl[g3]; }
  }

  // ---------- gate epilogue ----------
  const float* bih = dir ? g.bih1 : g.bih0;
  const float* bhh = dir ? g.bhh1 : g.bhh0;
  const float* Gt = dir ? g.Gt1 : g.Gt0;
  float* dst = dir ? g.d1 : g.d0;
  __half* edst = dir ? g.e1 : g.e0;
  const int col = q0 + (lane & 15);
  const float bir = bih[col], biz = bih[H_ + col], bin = bih[2 * H_ + col];
  const float bhr = bhh[col], bhz = bhh[H_ + col], bhn = bhh[2 * H_ + col];
#pragma unroll
  for (int r = 0; r < 4; ++r) {
    const int b = m0 + 16 * w + (lane >> 4) * 4 + r;
    const float* Gr = Gt + (size_t)rows[b - m0] * (3 * H_);
    const float hold = hsrc[(size_t)b * g.ldh + col];
    const float rr = sigmoidf_(acc[0][r] + Gr[col] + bir + bhr);
    const float zz = sigmoidf_(acc[1][r] + Gr[H_ + col] + biz + bhz);
    const float nn = tanhf(Gr[2 * H_ + col] + bin + rr * (acc[2][r] + bhn));
    const float hv = (1.f - zz) * nn + zz * hold;
    dst[(size_t)b * H_ + col] = hv;
    edst[(size_t)b * g.lde + col] = __float2half(hv);
  }
}

// =================== decoder step: ctx GEMM (K=2048) + hidden GEMM + gate ===============
struct DS {
  const float* A1;                       // predin + 1024 (ctx region), row stride 3584
  const int* tok;
  const float* Gd;                       // [V][3H]
  const float* h;
  const float* Wih;                      // dWih + 512, row stride 2560
  const float* Whh;
  const float* bih; const float* bhh;
  float* d;
  float* predin;
};

__global__ __launch_bounds__(256)
void dec_step_k(DS g)
{
  const int fid = (blockIdx.x & 7) * 32 + (blockIdx.x >> 3);
  const int m0 = (fid & 3) * 64;
  const int q0 = (fid >> 2) * 16;

  __shared__ float As[32][66];
  __shared__ float Ws[3][32][22];
  const int tid = threadIdx.x;
  const int tx = tid & 7, ty = tid >> 3;
  const int wrow = tid >> 4, wk2 = (tid & 15) << 1;

  float ar[2][2] = {}, az[2][2] = {}, anI[2][2] = {}, anH[2][2] = {};
  float4 av[2], av2[2];
  float2 wv[3], wv2[3];

  auto load_tile = [&](int kb, float4 (&AV)[2], float2 (&WV)[3]) {
    if (kb < 2048) {
#pragma unroll
      for (int i = 0; i < 2; ++i) {
        const int f = tid + i * 256;
        const int arow = f >> 3, ka = (f & 7) << 2;
        AV[i] = *(const float4*)(g.A1 + (size_t)(m0 + arow) * 3584 + kb + ka);
      }
#pragma unroll
      for (int th = 0; th < 3; ++th)
        WV[th] = *(const float2*)(g.Wih + (size_t)(th * H_ + q0 + wrow) * 2560 + kb + wk2);
    } else {
      const int kb2 = kb - 2048;
#pragma unroll
      for (int i = 0; i < 2; ++i) {
        const int f = tid + i * 256;
        const int arow = f >> 3, ka = (f & 7) << 2;
        AV[i] = *(const float4*)(g.h + (size_t)(m0 + arow) * H_ + kb2 + ka);
      }
#pragma unroll
      for (int th = 0; th < 3; ++th)
        WV[th] = *(const float2*)(g.Whh + (size_t)(th * H_ + q0 + wrow) * H_ + kb2 + wk2);
    }
  };

  auto compute_tile = [&](float (&an)[2][2]) {
#pragma unroll
    for (int k = 0; k < 32; ++k) {
      const float2 a2 = *(const float2*)&As[k][ty << 1];
      const float am[2] = { a2.x, a2.y };
      const float2 wr = *(const float2*)&Ws[0][k][tx << 1];
      const float2 wz = *(const float2*)&Ws[1][k][tx << 1];
      const float2 wn = *(const float2*)&Ws[2][k][tx << 1];
#pragma unroll
      for (int i = 0; i < 2; ++i) {
        ar[i][0] += am[i] * wr.x; ar[i][1] += am[i] * wr.y;
        az[i][0] += am[i] * wz.x; az[i][1] += am[i] * wz.y;
        an[i][0] += am[i] * wn.x; an[i][1] += am[i] * wn.y;
      }
    }
  };

  load_tile(0, av, wv);
  for (int kt = 0; kt < 96; ++kt) {
    __syncthreads();
#pragma unroll
    for (int i = 0; i < 2; ++i) {
      const int f = tid + i * 256;
      const int arow = f >> 3, ka = (f & 7) << 2;
      As[ka + 0][arow] = av[i].x; As[ka + 1][arow] = av[i].y;
      As[ka + 2][arow] = av[i].z; As[ka + 3][arow] = av[i].w;
    }
#pragma unroll
    for (int th = 0; th < 3; ++th) {
      Ws[th][wk2 + 0][wrow] = wv[th].x;
      Ws[th][wk2 + 1][wrow] = wv[th].y;
    }
    __syncthreads();
    if (kt + 1 < 96) load_tile((kt + 1) * 32, av2, wv2);
    if (kt < 64) compute_tile(anI); else compute_tile(anH);
#pragma unroll
    for (int i = 0; i < 2; ++i) av[i] = av2[i];
#pragma unroll
    for (int th = 0; th < 3; ++th) wv[th] = wv2[th];
  }

  const int qq = q0 + (tx << 1);
  const float2 bir = *(const float2*)(g.bih + qq);
  const float2 biz = *(const float2*)(g.bih + H_ + qq);
  const float2 bin = *(const float2*)(g.bih + 2 * H_ + qq);
  const float2 bhr = *(const float2*)(g.bhh + qq);
  const float2 bhz = *(const float2*)(g.bhh + H_ + qq);
  const float2 bhn = *(const float2*)(g.bhh + 2 * H_ + qq);
#pragma unroll
  for (int i = 0; i < 2; ++i) {
    const int b = m0 + (ty << 1) + i;
    const float* Gr = g.Gd + (size_t)g.tok[b] * (3 * H_);
    const float2 g_r = *(const float2*)(Gr + qq);
    const float2 g_z = *(const float2*)(Gr + H_ + qq);
    const float2 g_n = *(const float2*)(Gr + 2 * H_ + qq);
    const float2 hold = *(const float2*)(g.h + (size_t)b * H_ + qq);
    float2 hv;
    float r = sigmoidf_(ar[i][0] + g_r.x + bir.x + bhr.x);
    float z = sigmoidf_(az[i][0] + g_z.x + biz.x + bhz.x);
    float n = tanhf(anI[i][0] + g_n.x + bin.x + r * (anH[i][0] + bhn.x));
    hv.x = (1.f - z) * n + z * hold.x;
    r = sigmoidf_(ar[i][1] + g_r.y + bir.y + bhr.y);
    z = sigmoidf_(az[i][1] + g_z.y + biz.y + bhz.y);
    n = tanhf(anI[i][1] + g_n.y + bin.y + r * (anH[i][1] + bhn.y));
    hv.y = (1.f - z) * n + z * hold.y;
    *(float2*)(g.d + (size_t)b * H_ + qq) = hv;
    *(float2*)(g.predin + (size_t)b * 3584 + qq) = hv;
  }
}

// =================== attn part 1: argmax + emb + scores + softmax ===================
__global__ __launch_bounds__(512)
void attn1_k(const float* __restrict__ out, const int* __restrict__ tgt,
             const float* __restrict__ q, const __half* __restrict__ proj,
             const float* __restrict__ va, const int* __restrict__ src,
             const float* __restrict__ dec_emb,
             float* __restrict__ predin, float* __restrict__ wts,
             int* __restrict__ tokbuf, int t)
{
  const int b = blockIdx.x, tid = threadIdx.x;
  const int lane = tid & 63, wv = tid >> 6;
  __shared__ float sm[128];
  __shared__ float tr[128];
  __shared__ float rv[4];
  __shared__ int ri[4];
  __shared__ int tok_s;
  if (t == 0) {
    if (tid == 0) tok_s = tgt[(size_t)b * T_];
  } else {
    if (tid < 256) {
      float av = out[((size_t)b * (T_ - 1) + (t - 1)) * V_ + tid];
      int ai = tid;
      for (int off = 32; off; off >>= 1) {
        const float ov = __shfl_down(av, off);
        const int   oi = __shfl_down(ai, off);
        if (ov > av) { av = ov; ai = oi; }   // strict >: first-max semantics
      }
      if (lane == 0) { rv[wv] = av; ri[wv] = ai; }
    }
    __syncthreads();
    if (tid == 0) {
      float bv = rv[0]; int bi = ri[0];
      for (int w = 1; w < 4; ++w) if (rv[w] > bv) { bv = rv[w]; bi = ri[w]; }
      tok_s = bi;
    }
  }
  __syncthreads();
  const int tok = tok_s;
  if (tid == 0) tokbuf[b] = tok;
  predin[(size_t)b * 3584 + 3072 + tid] = dec_emb[(size_t)tok * E_ + tid];
  const float* qb = q + (size_t)b * H_;
  for (int s = wv * 12; s < wv * 12 + 12; ++s) {
    const __half* pb = proj + ((size_t)b * S_ + s) * H_;
    float part = 0.f;
#pragma unroll
    for (int j = 0; j < 8; ++j) {
      const int h = lane * 2 + j * 128;
      const __half2 p2 = *(const __half2*)(pb + h);
      const float2 q2 = *(const float2*)(qb + h);
      const float2 v2 = *(const float2*)(va + h);
      part += v2.x * tanhf(q2.x + __half2float(p2.x));
      part += v2.y * tanhf(q2.y + __half2float(p2.y));
    }
    for (int off = 32; off; off >>= 1) part += __shfl_down(part, off);
    if (lane == 0)
      sm[s] = (src[(size_t)b * S_ + s] == 0) ? -1.0e9f : part;
  }
  __syncthreads();
  if (tid < 128) tr[tid] = (tid < S_) ? sm[tid] : -3.0e38f;
  __syncthreads();
  for (int s2 = 64; s2 > 0; s2 >>= 1) { if (tid < s2) tr[tid] = fmaxf(tr[tid], tr[tid + s2]); __syncthreads(); }
  const float mx = tr[0];
  __syncthreads();
  if (tid < 128) tr[tid] = (tid < S_) ? expf(sm[tid] - mx) : 0.f;
  __syncthreads();
  for (int s2 = 64; s2 > 0; s2 >>= 1) { if (tid < s2) tr[tid] += tr[tid + s2]; __syncthreads(); }
  const float inv = 1.0f / tr[0];
  __syncthreads();
  if (tid < S_) wts[(size_t)b * S_ + tid] = expf(sm[tid] - mx) * inv;
}

// =================== attn part 2: ctx ===================
__global__ __launch_bounds__(256)
void ctx_k(const float* __restrict__ wts, const __half* __restrict__ enc,
           float* __restrict__ predin)
{
  const int b = blockIdx.y, tid = threadIdx.x;
  __shared__ float sw[S_];
  if (tid < S_) sw[tid] = wts[(size_t)b * S_ + tid];
  __syncthreads();
  const int d = blockIdx.x * 512 + tid * 2;
  const __half* eb = enc + (size_t)b * S_ * (2 * H_) + d;
  float c0 = 0.f, c1 = 0.f;
  for (int s0 = 0; s0 < S_; s0 += 8) {
    __half2 v[8];
#pragma unroll
    for (int i = 0; i < 8; ++i) v[i] = *(const __half2*)(eb + (size_t)(s0 + i) * (2 * H_));
#pragma unroll
    for (int i = 0; i < 8; ++i) {
      const float w = sw[s0 + i];
      c0 += w * __half2float(v[i].x);
      c1 += w * __half2float(v[i].y);
    }
  }
  *(float2*)(predin + (size_t)b * 3584 + H_ + d) = make_float2(c0, c1);
}

// =================== fused pred-GEMM + q-GEMM (512 blocks) ===================
__global__ __launch_bounds__(256)
void prqa_k(const float* __restrict__ predin,
            const float* __restrict__ Wfc, const float* __restrict__ bfc,
            const float* __restrict__ hnew, const float* __restrict__ Wa,
            float* __restrict__ out_t, float* __restrict__ q)
{
  const int bid = blockIdx.x, tid = threadIdx.x;
  if (bid < 256) {
    const int m0 = (bid >> 4) << 4, n0 = (bid & 15) << 4;
    __shared__ float As[32][17], Ws[32][17];
    const int r = tid >> 4, kq = (tid & 15) << 1;
    const int tym = tid >> 4, txn = tid & 15;
    float acc = 0.f;
    for (int k0 = 0; k0 < 3584; k0 += 32) {
      const float2 a2 = *(const float2*)(predin + (size_t)(m0 + r) * 3584 + k0 + kq);
      const float2 w2 = *(const float2*)(Wfc + (size_t)(n0 + r) * 3584 + k0 + kq);
      __syncthreads();
      As[kq][r] = a2.x; As[kq + 1][r] = a2.y;
      Ws[kq][r] = w2.x; Ws[kq + 1][r] = w2.y;
      __syncthreads();
#pragma unroll
      for (int k = 0; k < 32; ++k)
        acc += As[k][tym] * Ws[k][txn];
    }
    out_t[(size_t)(m0 + tym) * ((T_ - 1) * V_) + n0 + txn] = acc + bfc[n0 + txn];
  } else {
    const int b2 = bid - 256;
    const int m0 = (b2 >> 5) << 5, n0 = (b2 & 31) << 5;
    __shared__ float As[32][34], Ws[32][34];
    const int r = tid >> 3, kq = (tid & 7) << 2;
    const int tx = tid & 15, ty = tid >> 4;
    float acc[2][2] = {};
    for (int k0 = 0; k0 < 1024; k0 += 32) {
      const float4 a4 = *(const float4*)(hnew + (size_t)(m0 + r) * H_ + k0 + kq);
      const float4 w4 = *(const float4*)(Wa + (size_t)(n0 + r) * (3 * H_) + k0 + kq);
      __syncthreads();
      As[kq + 0][r] = a4.x; As[kq + 1][r] = a4.y; As[kq + 2][r] = a4.z; As[kq + 3][r] = a4.w;
      Ws[kq + 0][r] = w4.x; Ws[kq + 1][r] = w4.y; Ws[kq + 2][r] = w4.z; Ws[kq + 3][r] = w4.w;
      __syncthreads();
#pragma unroll
      for (int k = 0; k < 32; ++k) {
        const float2 a2 = *(const float2*)&As[k][ty << 1];
        const float2 w2 = *(const float2*)&Ws[k][tx << 1];
        acc[0][0] += a2.x * w2.x; acc[0][1] += a2.x * w2.y;
        acc[1][0] += a2.y * w2.x; acc[1][1] += a2.y * w2.y;
      }
    }
#pragma unroll
    for (int i = 0; i < 2; ++i)
#pragma unroll
      for (int j = 0; j < 2; ++j)
        q[(size_t)(m0 + (ty << 1) + i) * H_ + n0 + (tx << 1) + j] = acc[i][j];
  }
}

// =================== generic fp32 tiled GEMM (tables / enc_proj / br / q0) ==============
struct GB {
  const float* A; int lda;
  const __half* Ah;
  const float* W; int ldw;
  const float* bias;
  float* C; int ldc;
  __half* Ch;
  int M, N, K, act;
  const float *hf, *hb; int ldh;
  const float *mE, *tE, *pE;
  const int *mi, *ti, *pi;
};

template<int AMODE, int CMODE>
__global__ __launch_bounds__(256)
void gemm_k(GB g0, GB g1)
{
  GB g = blockIdx.z ? g1 : g0;
  const int m0 = blockIdx.y * 64, n0 = blockIdx.x * 64;
  if (m0 >= g.M || n0 >= g.N) return;
  __shared__ float As[32][68];
  __shared__ float Ws[32][68];
  const int tid = threadIdx.x, tx = tid & 15, ty = tid >> 4;
  const int lm = tid >> 3, lk = (tid & 7) << 2;
  float acc[4][4] = {};
  float4 av[2], wv[2], av2[2], wv2[2];

  auto load_tile = [&](int k0, float4 (&AV)[2], float4 (&WV)[2]) {
#pragma unroll
    for (int i = 0; i < 2; ++i) {
      const int row = lm + i * 32;
      const int kk = k0 + lk;
      if (AMODE == 0) {
        AV[i] = *(const float4*)(g.A + (size_t)(m0 + row) * g.lda + kk);
      } else if (AMODE == 4) {
        const __half* ap = g.Ah + (size_t)(m0 + row) * g.lda + kk;
        const __half2 h0 = *(const __half2*)ap;
        const __half2 h1 = *(const __half2*)(ap + 2);
        AV[i] = make_float4(__half2float(h0.x), __half2float(h0.y),
                            __half2float(h1.x), __half2float(h1.y));
      } else {
        const int mg = m0 + row; const float* sp; size_t o;
        if (kk < 1024)      { sp = g.hf; o = (size_t)mg * g.ldh + kk; }
        else if (kk < 2048) { sp = g.hb; o = (size_t)mg * g.ldh + kk - 1024; }
        else if (kk < 2176) { sp = g.mE; o = (size_t)g.mi[mg] * C_ + kk - 2048; }
        else if (kk < 2304) { sp = g.tE; o = (size_t)g.ti[mg] * C_ + kk - 2176; }
        else                { sp = g.pE; o = (size_t)g.pi[mg] * C_ + kk - 2304; }
        AV[i] = *(const float4*)(sp + o);
      }
      WV[i] = *(const float4*)(g.W + (size_t)(n0 + row) * g.ldw + kk);
    }
  };

  load_tile(0, av, wv);
  for (int k0 = 0; k0 < g.K; k0 += 32) {
    __syncthreads();
#pragma unroll
    for (int i = 0; i < 2; ++i) {
      const int row = lm + i * 32;
      As[lk + 0][row] = av[i].x; As[lk + 1][row] = av[i].y;
      As[lk + 2][row] = av[i].z; As[lk + 3][row] = av[i].w;
      Ws[lk + 0][row] = wv[i].x; Ws[lk + 1][row] = wv[i].y;
      Ws[lk + 2][row] = wv[i].z; Ws[lk + 3][row] = wv[i].w;
    }
    __syncthreads();
    if (k0 + 32 < g.K) load_tile(k0 + 32, av2, wv2);
#pragma unroll
    for (int k = 0; k < 32; ++k) {
      const float4 a4 = *(const float4*)&As[k][ty << 2];
      const float4 b4 = *(const float4*)&Ws[k][tx << 2];
      acc[0][0] += a4.x * b4.x; acc[0][1] += a4.x * b4.y; acc[0][2] += a4.x * b4.z; acc[0][3] += a4.x * b4.w;
      acc[1][0] += a4.y * b4.x; acc[1][1] += a4.y * b4.y; acc[1][2] += a4.y * b4.z; acc[1][3] += a4.y * b4.w;
      acc[2][0] += a4.z * b4.x; acc[2][1] += a4.z * b4.y; acc[2][2] += a4.z * b4.z; acc[2][3] += a4.z * b4.w;
      acc[3][0] += a4.w * b4.x; acc[3][1] += a4.w * b4.y; acc[3][2] += a4.w * b4.z; acc[3][3] += a4.w * b4.w;
    }
#pragma unroll
    for (int i = 0; i < 2; ++i) { av[i] = av2[i]; wv[i] = wv2[i]; }
  }
  const int n = n0 + (tx << 2);
  float4 bb = make_float4(0.f, 0.f, 0.f, 0.f);
  if (g.bias) bb = *(const float4*)(g.bias + n);
#pragma unroll
  for (int i = 0; i < 4; ++i) {
    const int m = m0 + (ty << 2) + i;
    float4 v = make_float4(acc[i][0] + bb.x, acc[i][1] + bb.y, acc[i][2] + bb.z, acc[i][3] + bb.w);
    if (CMODE == 0) {
      if (g.act) { v.x = tanhf(v.x); v.y = tanhf(v.y); v.z = tanhf(v.z); v.w = tanhf(v.w); }
      *(float4*)(g.C + (size_t)m * g.ldc + n) = v;
    } else {
      __half2* cp = (__half2*)(g.Ch + (size_t)m * g.ldc + n);
      cp[0] = __floats2half2_rn(v.x, v.y);
      cp[1] = __floats2half2_rn(v.z, v.w);
    }
  }
}

// =================== misc ===================
__global__ void zero_k(float* __restrict__ p, int n)
{
  const int i = blockIdx.x * 256 + threadIdx.x;
  if (i < n) p[i] = 0.0f;
}

__global__ void sentinel_k(float* out, float v) { out[threadIdx.x] = v; }

// =================== host orchestration ===================
extern "C" void kernel_launch(void* const* d_in, const int* in_sizes, int n_in,
                              void* d_out, int out_size, void* d_ws, size_t ws_size,
                              hipStream_t stream)
{
  const int*   src        = (const int*)d_in[0];
  const int*   tgt        = (const int*)d_in[1];
  const int*   mode_idx   = (const int*)d_in[2];
  const int*   tense_idx  = (const int*)d_in[3];
  const int*   person_idx = (const int*)d_in[4];
  const float* enc_emb    = (const float*)d_in[5];
  const float* eWih_f     = (const float*)d_in[6];
  const float* eWhh_f     = (const float*)d_in[7];
  const float* ebih_f     = (const float*)d_in[8];
  const float* ebhh_f     = (const float*)d_in[9];
  const float* eWih_b     = (const float*)d_in[10];
  const float* eWhh_b     = (const float*)d_in[11];
  const float* ebih_b     = (const float*)d_in[12];
  const float* ebhh_b     = (const float*)d_in[13];
  const float* Wa         = (const float*)d_in[14];
  const float* va         = (const float*)d_in[15];
  const float* dec_emb    = (const float*)d_in[16];
  const float* dWih       = (const float*)d_in[17];
  const float* dWhh       = (const float*)d_in[18];
  const float* dbih       = (const float*)d_in[19];
  const float* dbhh       = (const float*)d_in[20];
  const float* Wfc        = (const float*)d_in[21];
  const float* bfc        = (const float*)d_in[22];
  const float* mode_E     = (const float*)d_in[23];
  const float* tense_E    = (const float*)d_in[24];
  const float* person_E   = (const float*)d_in[25];
  const float* Wbr        = (const float*)d_in[26];
  const float* bbr        = (const float*)d_in[27];
  float* out = (float*)d_out;

  // ---- workspace carve (~197 MB; proven >= 268 MB) ----
  char* base = (char*)d_ws;
  size_t off = 0;
  auto alloc = [&](size_t bytes) { char* r = base + off; off = (off + bytes + 255) & ~(size_t)255; return r; };
  __half* enc_out = (__half*)alloc(2ull * B_ * S_ * 2 * H_);   // 100.7 MB
  __half* proj    = (__half*)alloc(2ull * B_ * S_ * H_);       // 50.3 MB
  short* whh_hi = (short*)alloc(2ull * 2 * 3 * H_ * H_);       // 12.6 MB (2 dirs)
  short* whh_lo = (short*)alloc(2ull * 2 * 3 * H_ * H_);       // 12.6 MB
  float* Gi_f  = (float*)alloc(4ull * V_ * 3 * H_);
  float* Gi_b  = (float*)alloc(4ull * V_ * 3 * H_);
  float* Gd    = (float*)alloc(4ull * V_ * 3 * H_);
  float* hfA   = (float*)alloc(4ull * B_ * H_);
  float* hfB   = (float*)alloc(4ull * B_ * H_);
  float* hbA   = (float*)alloc(4ull * B_ * H_);
  float* hbB   = (float*)alloc(4ull * B_ * H_);
  float* h_d0  = (float*)alloc(4ull * B_ * H_);
  float* h_d1  = (float*)alloc(4ull * B_ * H_);
  float* q     = (float*)alloc(4ull * B_ * H_);
  float* predin = (float*)alloc(4ull * B_ * 3584);
  float* wts   = (float*)alloc(4ull * B_ * S_);
  int*   tok   = (int*)alloc(4ull * B_);
  float* zero_buf = (float*)alloc(4ull * 1024);
  if (off > ws_size) {
    hipLaunchKernelGGL(sentinel_k, dim3(1), dim3(256), 0, stream, out,
                       1000.0f + (float)(ws_size >> 20));
    return;
  }

  hipLaunchKernelGGL(zero_k, dim3(4), dim3(256), 0, stream, zero_buf, 1024);

  // ---- split eWhh into bf16 hi/lo planes ----
  {
    const int n = 3 * H_ * H_;   // per dir
    hipLaunchKernelGGL(wsplit_k, dim3((2 * n) / 256), dim3(256), 0, stream,
                       eWhh_f, eWhh_b, whh_hi, whh_lo, n);
  }

  GB Z{};

  // ---- token tables ----
  {
    GB t0 = Z, t1 = Z;
    t0.A = enc_emb; t0.lda = E_; t0.W = eWih_f; t0.ldw = E_;
    t0.C = Gi_f; t0.ldc = 3 * H_; t0.M = V_; t0.N = 3 * H_; t0.K = E_;
    t1 = t0; t1.W = eWih_b; t1.C = Gi_b;
    hipLaunchKernelGGL((gemm_k<0, 0>), dim3(48, 4, 2), dim3(256), 0, stream, t0, t1);
    GB t2 = Z;
    t2.A = dec_emb; t2.lda = E_; t2.W = dWih; t2.ldw = 2560;
    t2.C = Gd; t2.ldc = 3 * H_; t2.M = V_; t2.N = 3 * H_; t2.K = E_;
    hipLaunchKernelGGL((gemm_k<0, 0>), dim3(48, 4, 1), dim3(256), 0, stream, t2, t2);
  }

  // ---- encoder: 96 MFMA steps ----
  for (int t = 0; t < S_; ++t) {
    EM em{};
    em.gidx = src; em.goff0 = t; em.goff1 = S_ - 1 - t;
    em.Gt0 = Gi_f; em.Gt1 = Gi_b;
    if (t == 0) { em.h0 = zero_buf; em.h1 = zero_buf; em.ldh = 0; }
    else if (t & 1) { em.h0 = hfA; em.h1 = hbA; em.ldh = H_; }
    else            { em.h0 = hfB; em.h1 = hbB; em.ldh = H_; }
    em.whi = whh_hi; em.wlo = whh_lo;
    em.bih0 = ebih_f; em.bih1 = ebih_b; em.bhh0 = ebhh_f; em.bhh1 = ebhh_b;
    if (t & 1) { em.d0 = hfB; em.d1 = hbB; } else { em.d0 = hfA; em.d1 = hbA; }
    em.e0 = enc_out + (size_t)t * 2 * H_;
    em.e1 = enc_out + (size_t)(S_ - 1 - t) * 2 * H_ + H_;
    em.lde = S_ * 2 * H_;
    hipLaunchKernelGGL(enc_mfma_k, dim3(512), dim3(256), 0, stream, em);
  }
  float* hf_fin = hfB;   // t=95 (odd) wrote hfB/hbB
  float* hb_fin = hbB;

  // ---- enc_proj (fp16 A, fp16 out) ----
  {
    GB ep = Z;
    ep.Ah = enc_out; ep.lda = 2 * H_; ep.W = Wa + H_; ep.ldw = 3 * H_;
    ep.Ch = proj; ep.ldc = H_; ep.M = B_ * S_; ep.N = H_; ep.K = 2 * H_;
    hipLaunchKernelGGL((gemm_k<4, 1>), dim3(16, 384, 1), dim3(256), 0, stream, ep, ep);
  }

  // ---- dec_h0 ----
  {
    GB br = Z;
    br.W = Wbr; br.ldw = 2432; br.bias = bbr; br.C = h_d0; br.ldc = H_;
    br.M = B_; br.N = H_; br.K = 2432; br.act = 1;
    br.hf = hf_fin; br.hb = hb_fin; br.ldh = H_;
    br.mE = mode_E; br.tE = tense_E; br.pE = person_E;
    br.mi = mode_idx; br.ti = tense_idx; br.pi = person_idx;
    hipLaunchKernelGGL((gemm_k<2, 0>), dim3(16, 4, 1), dim3(256), 0, stream, br, br);
  }

  // ---- q(0) ----
  {
    GB qa = Z;
    qa.A = h_d0; qa.lda = H_; qa.W = Wa; qa.ldw = 3 * H_; qa.C = q; qa.ldc = H_;
    qa.M = B_; qa.N = H_; qa.K = H_;
    hipLaunchKernelGGL((gemm_k<0, 0>), dim3(16, 4, 1), dim3(256), 0, stream, qa, qa);
  }

  // ---- decoder: 39 steps x (attn1, ctx, dec_step, prqa) ----
  float* hd[2] = { h_d0, h_d1 };
  for (int t = 0; t < T_ - 1; ++t) {
    hipLaunchKernelGGL(attn1_k, dim3(B_), dim3(512), 0, stream,
                       out, tgt, q, proj, va, src, dec_emb, predin, wts, tok, t);
    hipLaunchKernelGGL(ctx_k, dim3(4, B_), dim3(256), 0, stream, wts, enc_out, predin);

    DS ds{};
    ds.A1 = predin + 1024;
    ds.tok = tok; ds.Gd = Gd;
    ds.h = hd[t & 1];
    ds.Wih = dWih + 512;
    ds.Whh = dWhh;
    ds.bih = dbih; ds.bhh = dbhh;
    ds.d = hd[(t + 1) & 1];
    ds.predin = predin;
    hipLaunchKernelGGL(dec_step_k, dim3(256), dim3(256), 0, stream, ds);

    hipLaunchKernelGGL(prqa_k, dim3(512), dim3(256), 0, stream,
                       predin, Wfc, bfc, hd[(t + 1) & 1], Wa,
                       out + (size_t)t * V_, q);
  }
}

// Round 13
// 14944.043 us; speedup vs baseline: 3.1090x; 1.3717x over previous
//
#include <hip/hip_runtime.h>
#include <hip/hip_fp16.h>
#include <cstdint>
#include <cstddef>

#define B_  256
#define S_  96
#define T_  40
#define V_  256
#define E_  512
#define H_  1024
#define C_  128

typedef __attribute__((ext_vector_type(8))) short s8v;   // 8 bf16
typedef __attribute__((ext_vector_type(4))) float f4v;   // mfma acc

__device__ __forceinline__ float sigmoidf_(float x) { return 1.0f / (1.0f + expf(-x)); }

__device__ __forceinline__ uint32_t cvtpk_bf16(float a, float b) {
  uint32_t r;
  asm("v_cvt_pk_bf16_f32 %0, %1, %2" : "=v"(r) : "v"(a), "v"(b));
  return r;
}

union U4 { uint32_t u[4]; s8v v; };

// split 8 f32 into bf16 hi + bf16 lo fragments
__device__ __forceinline__ void split8(const float4 a, const float4 b, s8v& hi, s8v& lo) {
  U4 H, L;
  H.u[0] = cvtpk_bf16(a.x, a.y);
  H.u[1] = cvtpk_bf16(a.z, a.w);
  H.u[2] = cvtpk_bf16(b.x, b.y);
  H.u[3] = cvtpk_bf16(b.z, b.w);
  const float r0 = a.x - __uint_as_float(H.u[0] << 16);
  const float r1 = a.y - __uint_as_float(H.u[0] & 0xffff0000u);
  const float r2 = a.z - __uint_as_float(H.u[1] << 16);
  const float r3 = a.w - __uint_as_float(H.u[1] & 0xffff0000u);
  const float r4 = b.x - __uint_as_float(H.u[2] << 16);
  const float r5 = b.y - __uint_as_float(H.u[2] & 0xffff0000u);
  const float r6 = b.z - __uint_as_float(H.u[3] << 16);
  const float r7 = b.w - __uint_as_float(H.u[3] & 0xffff0000u);
  L.u[0] = cvtpk_bf16(r0, r1);
  L.u[1] = cvtpk_bf16(r2, r3);
  L.u[2] = cvtpk_bf16(r4, r5);
  L.u[3] = cvtpk_bf16(r6, r7);
  hi = H.v; lo = L.v;
}

// =================== weight split kernels ===================
__global__ void wsplit_k(const float* __restrict__ Wf, const float* __restrict__ Wb,
                         short* __restrict__ hi, short* __restrict__ lo, int n)
{
  const int i = blockIdx.x * 256 + threadIdx.x;
  const float w = (i < n) ? Wf[i] : Wb[i - n];
  const uint32_t h = cvtpk_bf16(w, w) & 0xffffu;
  const float wh = __uint_as_float(h << 16);
  const uint32_t l = cvtpk_bf16(w - wh, w - wh) & 0xffffu;
  hi[i] = (short)h;
  lo[i] = (short)l;
}

// plane[r][pcol0+c] = split(src[r*ld_src + col0 + c]), c < cols
__global__ void split_plane_k(const float* __restrict__ src, int ld_src, int col0,
                              short* __restrict__ hi, short* __restrict__ lo,
                              int ld_p, int pcol0, int total, int cols)
{
  const int i = blockIdx.x * 256 + threadIdx.x;
  if (i >= total) return;
  const int r = i / cols, c = i % cols;
  const float w = src[(size_t)r * ld_src + col0 + c];
  const uint32_t h = cvtpk_bf16(w, w) & 0xffffu;
  const float wh = __uint_as_float(h << 16);
  const uint32_t l = cvtpk_bf16(w - wh, w - wh) & 0xffffu;
  const size_t o = (size_t)r * ld_p + pcol0 + c;
  hi[o] = (short)h;
  lo[o] = (short)l;
}

// =================== encoder step via MFMA bf16x3 (verified r12) ===================
struct EM {
  const int* gidx; int goff0, goff1;
  const float* Gt0; const float* Gt1;
  const float* h0; const float* h1; int ldh;
  const short* whi; const short* wlo;    // [2][3H][H]
  const float* bih0; const float* bih1;
  const float* bhh0; const float* bhh1;
  float* d0; float* d1;
  __half* e0; __half* e1; int lde;
};

__global__ __launch_bounds__(256)
void enc_mfma_k(EM g)
{
  const int fid = (blockIdx.x & 7) * 64 + (blockIdx.x >> 3);
  const int m0 = (fid & 3) * 64;
  const int r2 = fid >> 2;
  const int dir = r2 & 1;
  const int q0 = (r2 >> 1) * 16;

  __shared__ int rows[64];
  const int tid = threadIdx.x;
  if (tid < 64)
    rows[tid] = g.gidx[(size_t)(m0 + tid) * S_ + (dir ? g.goff1 : g.goff0)];
  __syncthreads();

  const int w = tid >> 6, lane = tid & 63;
  const int arow = m0 + 16 * w + (lane & 15);
  const int kc = (lane >> 4) << 3;
  const float* hsrc = dir ? g.h1 : g.h0;
  const short* whi = g.whi + (size_t)dir * (3u * H_ * H_);
  const short* wlo = g.wlo + (size_t)dir * (3u * H_ * H_);
  const float* ap = hsrc + (size_t)arow * g.ldh;
  const int wrow = q0 + (lane & 15);

  f4v acc[3];
  acc[0] = f4v{0.f, 0.f, 0.f, 0.f};
  acc[1] = f4v{0.f, 0.f, 0.f, 0.f};
  acc[2] = f4v{0.f, 0.f, 0.f, 0.f};

  float4 a0 = *(const float4*)(ap + kc);
  float4 a1 = *(const float4*)(ap + kc + 4);
  s8v bh[3], bl[3];
#pragma unroll
  for (int g3 = 0; g3 < 3; ++g3) {
    const size_t wb = (size_t)(g3 * H_ + wrow) * H_ + kc;
    bh[g3] = *(const s8v*)(whi + wb);
    bl[g3] = *(const s8v*)(wlo + wb);
  }

  for (int kb = 0; kb < 1024; kb += 32) {
    float4 na0, na1;
    s8v nbh[3], nbl[3];
    if (kb + 32 < 1024) {
      na0 = *(const float4*)(ap + kb + 32 + kc);
      na1 = *(const float4*)(ap + kb + 32 + kc + 4);
#pragma unroll
      for (int g3 = 0; g3 < 3; ++g3) {
        const size_t wb = (size_t)(g3 * H_ + wrow) * H_ + kb + 32 + kc;
        nbh[g3] = *(const s8v*)(whi + wb);
        nbl[g3] = *(const s8v*)(wlo + wb);
      }
    }
    s8v ah, al;
    split8(a0, a1, ah, al);
#pragma unroll
    for (int g3 = 0; g3 < 3; ++g3) {
      acc[g3] = __builtin_amdgcn_mfma_f32_16x16x32_bf16(ah, bh[g3], acc[g3], 0, 0, 0);
      acc[g3] = __builtin_amdgcn_mfma_f32_16x16x32_bf16(al, bh[g3], acc[g3], 0, 0, 0);
      acc[g3] = __builtin_amdgcn_mfma_f32_16x16x32_bf16(ah, bl[g3], acc[g3], 0, 0, 0);
    }
    a0 = na0; a1 = na1;
#pragma unroll
    for (int g3 = 0; g3 < 3; ++g3) { bh[g3] = nbh[g3]; bl[g3] = nbl[g3]; }
  }

  const float* bih = dir ? g.bih1 : g.bih0;
  const float* bhh = dir ? g.bhh1 : g.bhh0;
  const float* Gt = dir ? g.Gt1 : g.Gt0;
  float* dst = dir ? g.d1 : g.d0;
  __half* edst = dir ? g.e1 : g.e0;
  const int col = q0 + (lane & 15);
  const float bir = bih[col], biz = bih[H_ + col], bin = bih[2 * H_ + col];
  const float bhr = bhh[col], bhz = bhh[H_ + col], bhn = bhh[2 * H_ + col];
#pragma unroll
  for (int r = 0; r < 4; ++r) {
    const int b = m0 + 16 * w + (lane >> 4) * 4 + r;
    const float* Gr = Gt + (size_t)rows[b - m0] * (3 * H_);
    const float hold = hsrc[(size_t)b * g.ldh + col];
    const float rr = sigmoidf_(acc[0][r] + Gr[col] + bir + bhr);
    const float zz = sigmoidf_(acc[1][r] + Gr[H_ + col] + biz + bhz);
    const float nn = tanhf(Gr[2 * H_ + col] + bin + rr * (acc[2][r] + bhn));
    const float hv = (1.f - zz) * nn + zz * hold;
    dst[(size_t)b * H_ + col] = hv;
    edst[(size_t)b * g.lde + col] = __float2half(hv);
  }
}

// =================== decoder step via MFMA bf16x3 ===================
// planes: [3H][3072], cols 0..2047 = dWih ctx cols, 2048..3071 = dWhh.
// 4 accumulators: r, z, nI (k<2048), nH (k>=2048).
struct DM {
  const float* predin;                   // ctx at row*3584 + 1024
  const float* h;
  const int* tok;
  const float* Gd;
  const short* whi; const short* wlo;
  const float* bih; const float* bhh;
  float* d;
  float* predout;
};

__global__ __launch_bounds__(256)
void dec_mfma_k(DM g)
{
  const int fid = (blockIdx.x & 7) * 32 + (blockIdx.x >> 3);
  const int m0 = (fid & 3) * 64;
  const int q0 = (fid >> 2) * 16;
  const int tid = threadIdx.x;
  const int w = tid >> 6, lane = tid & 63;
  const int arow = m0 + 16 * w + (lane & 15);
  const int kc = (lane >> 4) << 3;
  const float* actx = g.predin + (size_t)arow * 3584 + 1024;
  const float* ahid = g.h + (size_t)arow * H_;
  const int wrow = q0 + (lane & 15);

  f4v aR = f4v{0.f,0.f,0.f,0.f}, aZ = aR, aNI = aR, aNH = aR;

  auto loadA = [&](int kk, float4& x0, float4& x1) {
    const float* p = (kk < 2048) ? (actx + kk) : (ahid + kk - 2048);
    x0 = *(const float4*)p;
    x1 = *(const float4*)(p + 4);
  };

  float4 a0, a1;
  loadA(kc, a0, a1);
  s8v bh[3], bl[3];
#pragma unroll
  for (int g3 = 0; g3 < 3; ++g3) {
    const size_t wb = (size_t)(g3 * H_ + wrow) * 3072 + kc;
    bh[g3] = *(const s8v*)(g.whi + wb);
    bl[g3] = *(const s8v*)(g.wlo + wb);
  }

  for (int kb = 0; kb < 3072; kb += 32) {
    float4 na0, na1;
    s8v nbh[3], nbl[3];
    if (kb + 32 < 3072) {
      loadA(kb + 32 + kc, na0, na1);
#pragma unroll
      for (int g3 = 0; g3 < 3; ++g3) {
        const size_t wb = (size_t)(g3 * H_ + wrow) * 3072 + kb + 32 + kc;
        nbh[g3] = *(const s8v*)(g.whi + wb);
        nbl[g3] = *(const s8v*)(g.wlo + wb);
      }
    }
    s8v ah, al;
    split8(a0, a1, ah, al);
    aR = __builtin_amdgcn_mfma_f32_16x16x32_bf16(ah, bh[0], aR, 0, 0, 0);
    aR = __builtin_amdgcn_mfma_f32_16x16x32_bf16(al, bh[0], aR, 0, 0, 0);
    aR = __builtin_amdgcn_mfma_f32_16x16x32_bf16(ah, bl[0], aR, 0, 0, 0);
    aZ = __builtin_amdgcn_mfma_f32_16x16x32_bf16(ah, bh[1], aZ, 0, 0, 0);
    aZ = __builtin_amdgcn_mfma_f32_16x16x32_bf16(al, bh[1], aZ, 0, 0, 0);
    aZ = __builtin_amdgcn_mfma_f32_16x16x32_bf16(ah, bl[1], aZ, 0, 0, 0);
    if (kb < 2048) {
      aNI = __builtin_amdgcn_mfma_f32_16x16x32_bf16(ah, bh[2], aNI, 0, 0, 0);
      aNI = __builtin_amdgcn_mfma_f32_16x16x32_bf16(al, bh[2], aNI, 0, 0, 0);
      aNI = __builtin_amdgcn_mfma_f32_16x16x32_bf16(ah, bl[2], aNI, 0, 0, 0);
    } else {
      aNH = __builtin_amdgcn_mfma_f32_16x16x32_bf16(ah, bh[2], aNH, 0, 0, 0);
      aNH = __builtin_amdgcn_mfma_f32_16x16x32_bf16(al, bh[2], aNH, 0, 0, 0);
      aNH = __builtin_amdgcn_mfma_f32_16x16x32_bf16(ah, bl[2], aNH, 0, 0, 0);
    }
    a0 = na0; a1 = na1;
#pragma unroll
    for (int g3 = 0; g3 < 3; ++g3) { bh[g3] = nbh[g3]; bl[g3] = nbl[g3]; }
  }

  const int col = q0 + (lane & 15);
  const float bir = g.bih[col], biz = g.bih[H_ + col], bin = g.bih[2 * H_ + col];
  const float bhr = g.bhh[col], bhz = g.bhh[H_ + col], bhn = g.bhh[2 * H_ + col];
#pragma unroll
  for (int r = 0; r < 4; ++r) {
    const int b = m0 + 16 * w + (lane >> 4) * 4 + r;
    const float* Gr = g.Gd + (size_t)g.tok[b] * (3 * H_);
    const float hold = g.h[(size_t)b * H_ + col];
    const float rr = sigmoidf_(aR[r] + Gr[col] + bir + bhr);
    const float zz = sigmoidf_(aZ[r] + Gr[H_ + col] + biz + bhz);
    const float nn = tanhf(aNI[r] + Gr[2 * H_ + col] + bin + rr * (aNH[r] + bhn));
    const float hv = (1.f - zz) * nn + zz * hold;
    g.d[(size_t)b * H_ + col] = hv;
    g.predout[(size_t)b * 3584 + col] = hv;
  }
}

// =================== fused pred + q via MFMA (512 blocks) ===================
// bid<256: pred tile (16x16), K=3584 split 4 ways across waves, LDS reduce, +bias.
// bid>=256: q tiles, 4 per block (one per wave), K=1024.
__global__ __launch_bounds__(256)
void prqa_mfma_k(const float* __restrict__ predin,
                 const short* __restrict__ fhi, const short* __restrict__ flo,
                 const float* __restrict__ bfc,
                 const float* __restrict__ hnew,
                 const short* __restrict__ qhi, const short* __restrict__ qlo,
                 float* __restrict__ out_t, float* __restrict__ qout)
{
  const int bid = blockIdx.x, tid = threadIdx.x;
  const int w = tid >> 6, lane = tid & 63;
  const int kc = (lane >> 4) << 3;
  if (bid < 256) {
    const int m0 = (bid >> 4) << 4, n0 = (bid & 15) << 4;
    const float* ap = predin + (size_t)(m0 + (lane & 15)) * 3584 + w * 896;
    const short* bhp = fhi + (size_t)(n0 + (lane & 15)) * 3584 + w * 896;
    const short* blp = flo + (size_t)(n0 + (lane & 15)) * 3584 + w * 896;
    f4v acc = f4v{0.f, 0.f, 0.f, 0.f};
    float4 a0 = *(const float4*)(ap + kc), a1 = *(const float4*)(ap + kc + 4);
    s8v bh = *(const s8v*)(bhp + kc), bl = *(const s8v*)(blp + kc);
    for (int kb = 0; kb < 896; kb += 32) {
      float4 na0, na1; s8v nbh, nbl;
      if (kb + 32 < 896) {
        na0 = *(const float4*)(ap + kb + 32 + kc);
        na1 = *(const float4*)(ap + kb + 32 + kc + 4);
        nbh = *(const s8v*)(bhp + kb + 32 + kc);
        nbl = *(const s8v*)(blp + kb + 32 + kc);
      }
      s8v ah, al;
      split8(a0, a1, ah, al);
      acc = __builtin_amdgcn_mfma_f32_16x16x32_bf16(ah, bh, acc, 0, 0, 0);
      acc = __builtin_amdgcn_mfma_f32_16x16x32_bf16(al, bh, acc, 0, 0, 0);
      acc = __builtin_amdgcn_mfma_f32_16x16x32_bf16(ah, bl, acc, 0, 0, 0);
      a0 = na0; a1 = na1; bh = nbh; bl = nbl;
    }
    __shared__ float red[4][64][4];
#pragma unroll
    for (int r = 0; r < 4; ++r) red[w][lane][r] = acc[r];
    __syncthreads();
    const int row = tid >> 4, col = tid & 15;
    const int sl = col + ((row >> 2) << 4), reg = row & 3;
    const float s = red[0][sl][reg] + red[1][sl][reg] + red[2][sl][reg] + red[3][sl][reg];
    out_t[(size_t)(m0 + row) * ((T_ - 1) * V_) + n0 + col] = s + bfc[n0 + col];
  } else {
    const int tt = (bid - 256) * 4 + w;
    const int m0 = (tt >> 6) << 4, n0 = (tt & 63) << 4;
    const float* ap = hnew + (size_t)(m0 + (lane & 15)) * H_;
    const short* bhp = qhi + (size_t)(n0 + (lane & 15)) * H_;
    const short* blp = qlo + (size_t)(n0 + (lane & 15)) * H_;
    f4v acc = f4v{0.f, 0.f, 0.f, 0.f};
    float4 a0 = *(const float4*)(ap + kc), a1 = *(const float4*)(ap + kc + 4);
    s8v bh = *(const s8v*)(bhp + kc), bl = *(const s8v*)(blp + kc);
    for (int kb = 0; kb < 1024; kb += 32) {
      float4 na0, na1; s8v nbh, nbl;
      if (kb + 32 < 1024) {
        na0 = *(const float4*)(ap + kb + 32 + kc);
        na1 = *(const float4*)(ap + kb + 32 + kc + 4);
        nbh = *(const s8v*)(bhp + kb + 32 + kc);
        nbl = *(const s8v*)(blp + kb + 32 + kc);
      }
      s8v ah, al;
      split8(a0, a1, ah, al);
      acc = __builtin_amdgcn_mfma_f32_16x16x32_bf16(ah, bh, acc, 0, 0, 0);
      acc = __builtin_amdgcn_mfma_f32_16x16x32_bf16(al, bh, acc, 0, 0, 0);
      acc = __builtin_amdgcn_mfma_f32_16x16x32_bf16(ah, bl, acc, 0, 0, 0);
      a0 = na0; a1 = na1; bh = nbh; bl = nbl;
    }
#pragma unroll
    for (int r = 0; r < 4; ++r)
      qout[(size_t)(m0 + (lane >> 4) * 4 + r) * H_ + n0 + (lane & 15)] = acc[r];
  }
}

// =================== attn part 1: argmax + emb + scores + softmax ===================
__global__ __launch_bounds__(512)
void attn1_k(const float* __restrict__ out, const int* __restrict__ tgt,
             const float* __restrict__ q, const __half* __restrict__ proj,
             const float* __restrict__ va, const int* __restrict__ src,
             const float* __restrict__ dec_emb,
             float* __restrict__ predin, float* __restrict__ wts,
             int* __restrict__ tokbuf, int t)
{
  const int b = blockIdx.x, tid = threadIdx.x;
  const int lane = tid & 63, wv = tid >> 6;
  __shared__ float sm[128];
  __shared__ float tr[128];
  __shared__ float rv[4];
  __shared__ int ri[4];
  __shared__ int tok_s;
  if (t == 0) {
    if (tid == 0) tok_s = tgt[(size_t)b * T_];
  } else {
    if (tid < 256) {
      float av = out[((size_t)b * (T_ - 1) + (t - 1)) * V_ + tid];
      int ai = tid;
      for (int off = 32; off; off >>= 1) {
        const float ov = __shfl_down(av, off);
        const int   oi = __shfl_down(ai, off);
        if (ov > av) { av = ov; ai = oi; }
      }
      if (lane == 0) { rv[wv] = av; ri[wv] = ai; }
    }
    __syncthreads();
    if (tid == 0) {
      float bv = rv[0]; int bi = ri[0];
      for (int w2 = 1; w2 < 4; ++w2) if (rv[w2] > bv) { bv = rv[w2]; bi = ri[w2]; }
      tok_s = bi;
    }
  }
  __syncthreads();
  const int tok = tok_s;
  if (tid == 0) tokbuf[b] = tok;
  predin[(size_t)b * 3584 + 3072 + tid] = dec_emb[(size_t)tok * E_ + tid];
  const float* qb = q + (size_t)b * H_;
  for (int s = wv * 12; s < wv * 12 + 12; ++s) {
    const __half* pb = proj + ((size_t)b * S_ + s) * H_;
    float part = 0.f;
#pragma unroll
    for (int j = 0; j < 8; ++j) {
      const int h = lane * 2 + j * 128;
      const __half2 p2 = *(const __half2*)(pb + h);
      const float2 q2 = *(const float2*)(qb + h);
      const float2 v2 = *(const float2*)(va + h);
      part += v2.x * tanhf(q2.x + __half2float(p2.x));
      part += v2.y * tanhf(q2.y + __half2float(p2.y));
    }
    for (int off = 32; off; off >>= 1) part += __shfl_down(part, off);
    if (lane == 0)
      sm[s] = (src[(size_t)b * S_ + s] == 0) ? -1.0e9f : part;
  }
  __syncthreads();
  if (tid < 128) tr[tid] = (tid < S_) ? sm[tid] : -3.0e38f;
  __syncthreads();
  for (int s2 = 64; s2 > 0; s2 >>= 1) { if (tid < s2) tr[tid] = fmaxf(tr[tid], tr[tid + s2]); __syncthreads(); }
  const float mx = tr[0];
  __syncthreads();
  if (tid < 128) tr[tid] = (tid < S_) ? expf(sm[tid] - mx) : 0.f;
  __syncthreads();
  for (int s2 = 64; s2 > 0; s2 >>= 1) { if (tid < s2) tr[tid] += tr[tid + s2]; __syncthreads(); }
  const float inv = 1.0f / tr[0];
  __syncthreads();
  if (tid < S_) wts[(size_t)b * S_ + tid] = expf(sm[tid] - mx) * inv;
}

// =================== attn part 2: ctx ===================
__global__ __launch_bounds__(256)
void ctx_k(const float* __restrict__ wts, const __half* __restrict__ enc,
           float* __restrict__ predin)
{
  const int b = blockIdx.y, tid = threadIdx.x;
  __shared__ float sw[S_];
  if (tid < S_) sw[tid] = wts[(size_t)b * S_ + tid];
  __syncthreads();
  const int d = blockIdx.x * 512 + tid * 2;
  const __half* eb = enc + (size_t)b * S_ * (2 * H_) + d;
  float c0 = 0.f, c1 = 0.f;
  for (int s0 = 0; s0 < S_; s0 += 8) {
    __half2 v[8];
#pragma unroll
    for (int i = 0; i < 8; ++i) v[i] = *(const __half2*)(eb + (size_t)(s0 + i) * (2 * H_));
#pragma unroll
    for (int i = 0; i < 8; ++i) {
      const float w = sw[s0 + i];
      c0 += w * __half2float(v[i].x);
      c1 += w * __half2float(v[i].y);
    }
  }
  *(float2*)(predin + (size_t)b * 3584 + H_ + d) = make_float2(c0, c1);
}

// =================== generic fp32 tiled GEMM (tables / enc_proj / br / q0) ==============
struct GB {
  const float* A; int lda;
  const __half* Ah;
  const float* W; int ldw;
  const float* bias;
  float* C; int ldc;
  __half* Ch;
  int M, N, K, act;
  const float *hf, *hb; int ldh;
  const float *mE, *tE, *pE;
  const int *mi, *ti, *pi;
};

template<int AMODE, int CMODE>
__global__ __launch_bounds__(256)
void gemm_k(GB g0, GB g1)
{
  GB g = blockIdx.z ? g1 : g0;
  const int m0 = blockIdx.y * 64, n0 = blockIdx.x * 64;
  if (m0 >= g.M || n0 >= g.N) return;
  __shared__ float As[32][68];
  __shared__ float Ws[32][68];
  const int tid = threadIdx.x, tx = tid & 15, ty = tid >> 4;
  const int lm = tid >> 3, lk = (tid & 7) << 2;
  float acc[4][4] = {};
  float4 av[2], wv[2], av2[2], wv2[2];

  auto load_tile = [&](int k0, float4 (&AV)[2], float4 (&WV)[2]) {
#pragma unroll
    for (int i = 0; i < 2; ++i) {
      const int row = lm + i * 32;
      const int kk = k0 + lk;
      if (AMODE == 0) {
        AV[i] = *(const float4*)(g.A + (size_t)(m0 + row) * g.lda + kk);
      } else if (AMODE == 4) {
        const __half* ap = g.Ah + (size_t)(m0 + row) * g.lda + kk;
        const __half2 h0 = *(const __half2*)ap;
        const __half2 h1 = *(const __half2*)(ap + 2);
        AV[i] = make_float4(__half2float(h0.x), __half2float(h0.y),
                            __half2float(h1.x), __half2float(h1.y));
      } else {
        const int mg = m0 + row; const float* sp; size_t o;
        if (kk < 1024)      { sp = g.hf; o = (size_t)mg * g.ldh + kk; }
        else if (kk < 2048) { sp = g.hb; o = (size_t)mg * g.ldh + kk - 1024; }
        else if (kk < 2176) { sp = g.mE; o = (size_t)g.mi[mg] * C_ + kk - 2048; }
        else if (kk < 2304) { sp = g.tE; o = (size_t)g.ti[mg] * C_ + kk - 2176; }
        else                { sp = g.pE; o = (size_t)g.pi[mg] * C_ + kk - 2304; }
        AV[i] = *(const float4*)(sp + o);
      }
      WV[i] = *(const float4*)(g.W + (size_t)(n0 + row) * g.ldw + kk);
    }
  };

  load_tile(0, av, wv);
  for (int k0 = 0; k0 < g.K; k0 += 32) {
    __syncthreads();
#pragma unroll
    for (int i = 0; i < 2; ++i) {
      const int row = lm + i * 32;
      As[lk + 0][row] = av[i].x; As[lk + 1][row] = av[i].y;
      As[lk + 2][row] = av[i].z; As[lk + 3][row] = av[i].w;
      Ws[lk + 0][row] = wv[i].x; Ws[lk + 1][row] = wv[i].y;
      Ws[lk + 2][row] = wv[i].z; Ws[lk + 3][row] = wv[i].w;
    }
    __syncthreads();
    if (k0 + 32 < g.K) load_tile(k0 + 32, av2, wv2);
#pragma unroll
    for (int k = 0; k < 32; ++k) {
      const float4 a4 = *(const float4*)&As[k][ty << 2];
      const float4 b4 = *(const float4*)&Ws[k][tx << 2];
      acc[0][0] += a4.x * b4.x; acc[0][1] += a4.x * b4.y; acc[0][2] += a4.x * b4.z; acc[0][3] += a4.x * b4.w;
      acc[1][0] += a4.y * b4.x; acc[1][1] += a4.y * b4.y; acc[1][2] += a4.y * b4.z; acc[1][3] += a4.y * b4.w;
      acc[2][0] += a4.z * b4.x; acc[2][1] += a4.z * b4.y; acc[2][2] += a4.z * b4.z; acc[2][3] += a4.z * b4.w;
      acc[3][0] += a4.w * b4.x; acc[3][1] += a4.w * b4.y; acc[3][2] += a4.w * b4.z; acc[3][3] += a4.w * b4.w;
    }
#pragma unroll
    for (int i = 0; i < 2; ++i) { av[i] = av2[i]; wv[i] = wv2[i]; }
  }
  const int n = n0 + (tx << 2);
  float4 bb = make_float4(0.f, 0.f, 0.f, 0.f);
  if (g.bias) bb = *(const float4*)(g.bias + n);
#pragma unroll
  for (int i = 0; i < 4; ++i) {
    const int m = m0 + (ty << 2) + i;
    float4 v = make_float4(acc[i][0] + bb.x, acc[i][1] + bb.y, acc[i][2] + bb.z, acc[i][3] + bb.w);
    if (CMODE == 0) {
      if (g.act) { v.x = tanhf(v.x); v.y = tanhf(v.y); v.z = tanhf(v.z); v.w = tanhf(v.w); }
      *(float4*)(g.C + (size_t)m * g.ldc + n) = v;
    } else {
      __half2* cp = (__half2*)(g.Ch + (size_t)m * g.ldc + n);
      cp[0] = __floats2half2_rn(v.x, v.y);
      cp[1] = __floats2half2_rn(v.z, v.w);
    }
  }
}

// =================== misc ===================
__global__ void zero_k(float* __restrict__ p, int n)
{
  const int i = blockIdx.x * 256 + threadIdx.x;
  if (i < n) p[i] = 0.0f;
}

__global__ void sentinel_k(float* out, float v) { out[threadIdx.x] = v; }

// =================== host orchestration ===================
extern "C" void kernel_launch(void* const* d_in, const int* in_sizes, int n_in,
                              void* d_out, int out_size, void* d_ws, size_t ws_size,
                              hipStream_t stream)
{
  const int*   src        = (const int*)d_in[0];
  const int*   tgt        = (const int*)d_in[1];
  const int*   mode_idx   = (const int*)d_in[2];
  const int*   tense_idx  = (const int*)d_in[3];
  const int*   person_idx = (const int*)d_in[4];
  const float* enc_emb    = (const float*)d_in[5];
  const float* eWih_f     = (const float*)d_in[6];
  const float* eWhh_f     = (const float*)d_in[7];
  const float* ebih_f     = (const float*)d_in[8];
  const float* ebhh_f     = (const float*)d_in[9];
  const float* eWih_b     = (const float*)d_in[10];
  const float* eWhh_b     = (const float*)d_in[11];
  const float* ebih_b     = (const float*)d_in[12];
  const float* ebhh_b     = (const float*)d_in[13];
  const float* Wa         = (const float*)d_in[14];
  const float* va         = (const float*)d_in[15];
  const float* dec_emb    = (const float*)d_in[16];
  const float* dWih       = (const float*)d_in[17];
  const float* dWhh       = (const float*)d_in[18];
  const float* dbih       = (const float*)d_in[19];
  const float* dbhh       = (const float*)d_in[20];
  const float* Wfc        = (const float*)d_in[21];
  const float* bfc        = (const float*)d_in[22];
  const float* mode_E     = (const float*)d_in[23];
  const float* tense_E    = (const float*)d_in[24];
  const float* person_E   = (const float*)d_in[25];
  const float* Wbr        = (const float*)d_in[26];
  const float* bbr        = (const float*)d_in[27];
  float* out = (float*)d_out;

  // ---- workspace carve (~243 MB; proven >= 268 MB) ----
  char* base = (char*)d_ws;
  size_t off = 0;
  auto alloc = [&](size_t bytes) { char* r = base + off; off = (off + bytes + 255) & ~(size_t)255; return r; };
  __half* enc_out = (__half*)alloc(2ull * B_ * S_ * 2 * H_);   // 100.7 MB
  __half* proj    = (__half*)alloc(2ull * B_ * S_ * H_);       // 50.3 MB
  short* whh_hi = (short*)alloc(2ull * 2 * 3 * H_ * H_);       // 12.6 MB
  short* whh_lo = (short*)alloc(2ull * 2 * 3 * H_ * H_);
  short* dpl_hi = (short*)alloc(2ull * 3 * H_ * 3072);         // 18.9 MB
  short* dpl_lo = (short*)alloc(2ull * 3 * H_ * 3072);
  short* fc_hi  = (short*)alloc(2ull * V_ * 3584);             // 1.8 MB
  short* fc_lo  = (short*)alloc(2ull * V_ * 3584);
  short* qa_hi  = (short*)alloc(2ull * H_ * H_);               // 2.1 MB
  short* qa_lo  = (short*)alloc(2ull * H_ * H_);
  float* Gi_f  = (float*)alloc(4ull * V_ * 3 * H_);
  float* Gi_b  = (float*)alloc(4ull * V_ * 3 * H_);
  float* Gd    = (float*)alloc(4ull * V_ * 3 * H_);
  float* hfA   = (float*)alloc(4ull * B_ * H_);
  float* hfB   = (float*)alloc(4ull * B_ * H_);
  float* hbA   = (float*)alloc(4ull * B_ * H_);
  float* hbB   = (float*)alloc(4ull * B_ * H_);
  float* h_d0  = (float*)alloc(4ull * B_ * H_);
  float* h_d1  = (float*)alloc(4ull * B_ * H_);
  float* q     = (float*)alloc(4ull * B_ * H_);
  float* predin = (float*)alloc(4ull * B_ * 3584);
  float* wts   = (float*)alloc(4ull * B_ * S_);
  int*   tok   = (int*)alloc(4ull * B_);
  float* zero_buf = (float*)alloc(4ull * 1024);
  if (off > ws_size) {
    hipLaunchKernelGGL(sentinel_k, dim3(1), dim3(256), 0, stream, out,
                       1000.0f + (float)(ws_size >> 20));
    return;
  }

  hipLaunchKernelGGL(zero_k, dim3(4), dim3(256), 0, stream, zero_buf, 1024);

  // ---- weight splits ----
  {
    const int n = 3 * H_ * H_;
    hipLaunchKernelGGL(wsplit_k, dim3((2 * n) / 256), dim3(256), 0, stream,
                       eWhh_f, eWhh_b, whh_hi, whh_lo, n);
    // dec planes: cols 0..2047 from dWih ctx cols, 2048..3071 from dWhh
    int tot = 3 * H_ * 2048;
    hipLaunchKernelGGL(split_plane_k, dim3((tot + 255) / 256), dim3(256), 0, stream,
                       dWih, 2560, 512, dpl_hi, dpl_lo, 3072, 0, tot, 2048);
    tot = 3 * H_ * 1024;
    hipLaunchKernelGGL(split_plane_k, dim3((tot + 255) / 256), dim3(256), 0, stream,
                       dWhh, 1024, 0, dpl_hi, dpl_lo, 3072, 2048, tot, 1024);
    tot = V_ * 3584;
    hipLaunchKernelGGL(split_plane_k, dim3((tot + 255) / 256), dim3(256), 0, stream,
                       Wfc, 3584, 0, fc_hi, fc_lo, 3584, 0, tot, 3584);
    tot = H_ * 1024;
    hipLaunchKernelGGL(split_plane_k, dim3((tot + 255) / 256), dim3(256), 0, stream,
                       Wa, 3 * H_, 0, qa_hi, qa_lo, 1024, 0, tot, 1024);
  }

  GB Z{};

  // ---- token tables ----
  {
    GB t0 = Z, t1 = Z;
    t0.A = enc_emb; t0.lda = E_; t0.W = eWih_f; t0.ldw = E_;
    t0.C = Gi_f; t0.ldc = 3 * H_; t0.M = V_; t0.N = 3 * H_; t0.K = E_;
    t1 = t0; t1.W = eWih_b; t1.C = Gi_b;
    hipLaunchKernelGGL((gemm_k<0, 0>), dim3(48, 4, 2), dim3(256), 0, stream, t0, t1);
    GB t2 = Z;
    t2.A = dec_emb; t2.lda = E_; t2.W = dWih; t2.ldw = 2560;
    t2.C = Gd; t2.ldc = 3 * H_; t2.M = V_; t2.N = 3 * H_; t2.K = E_;
    hipLaunchKernelGGL((gemm_k<0, 0>), dim3(48, 4, 1), dim3(256), 0, stream, t2, t2);
  }

  // ---- encoder: 96 MFMA steps ----
  for (int t = 0; t < S_; ++t) {
    EM em{};
    em.gidx = src; em.goff0 = t; em.goff1 = S_ - 1 - t;
    em.Gt0 = Gi_f; em.Gt1 = Gi_b;
    if (t == 0) { em.h0 = zero_buf; em.h1 = zero_buf; em.ldh = 0; }
    else if (t & 1) { em.h0 = hfA; em.h1 = hbA; em.ldh = H_; }
    else            { em.h0 = hfB; em.h1 = hbB; em.ldh = H_; }
    em.whi = whh_hi; em.wlo = whh_lo;
    em.bih0 = ebih_f; em.bih1 = ebih_b; em.bhh0 = ebhh_f; em.bhh1 = ebhh_b;
    if (t & 1) { em.d0 = hfB; em.d1 = hbB; } else { em.d0 = hfA; em.d1 = hbA; }
    em.e0 = enc_out + (size_t)t * 2 * H_;
    em.e1 = enc_out + (size_t)(S_ - 1 - t) * 2 * H_ + H_;
    em.lde = S_ * 2 * H_;
    hipLaunchKernelGGL(enc_mfma_k, dim3(512), dim3(256), 0, stream, em);
  }
  float* hf_fin = hfB;   // t=95 (odd) wrote hfB/hbB
  float* hb_fin = hbB;

  // ---- enc_proj (fp16 A, fp16 out) ----
  {
    GB ep = Z;
    ep.Ah = enc_out; ep.lda = 2 * H_; ep.W = Wa + H_; ep.ldw = 3 * H_;
    ep.Ch = proj; ep.ldc = H_; ep.M = B_ * S_; ep.N = H_; ep.K = 2 * H_;
    hipLaunchKernelGGL((gemm_k<4, 1>), dim3(16, 384, 1), dim3(256), 0, stream, ep, ep);
  }

  // ---- dec_h0 ----
  {
    GB br = Z;
    br.W = Wbr; br.ldw = 2432; br.bias = bbr; br.C = h_d0; br.ldc = H_;
    br.M = B_; br.N = H_; br.K = 2432; br.act = 1;
    br.hf = hf_fin; br.hb = hb_fin; br.ldh = H_;
    br.mE = mode_E; br.tE = tense_E; br.pE = person_E;
    br.mi = mode_idx; br.ti = tense_idx; br.pi = person_idx;
    hipLaunchKernelGGL((gemm_k<2, 0>), dim3(16, 4, 1), dim3(256), 0, stream, br, br);
  }

  // ---- q(0) ----
  {
    GB qa = Z;
    qa.A = h_d0; qa.lda = H_; qa.W = Wa; qa.ldw = 3 * H_; qa.C = q; qa.ldc = H_;
    qa.M = B_; qa.N = H_; qa.K = H_;
    hipLaunchKernelGGL((gemm_k<0, 0>), dim3(16, 4, 1), dim3(256), 0, stream, qa, qa);
  }

  // ---- decoder: 39 steps x (attn1, ctx, dec_mfma, prqa_mfma) ----
  float* hd[2] = { h_d0, h_d1 };
  for (int t = 0; t < T_ - 1; ++t) {
    hipLaunchKernelGGL(attn1_k, dim3(B_), dim3(512), 0, stream,
                       out, tgt, q, proj, va, src, dec_emb, predin, wts, tok, t);
    hipLaunchKernelGGL(ctx_k, dim3(4, B_), dim3(256), 0, stream, wts, enc_out, predin);

    DM dm{};
    dm.predin = predin;
    dm.h = hd[t & 1];
    dm.tok = tok; dm.Gd = Gd;
    dm.whi = dpl_hi; dm.wlo = dpl_lo;
    dm.bih = dbih; dm.bhh = dbhh;
    dm.d = hd[(t + 1) & 1];
    dm.predout = predin;
    hipLaunchKernelGGL(dec_mfma_k, dim3(256), dim3(256), 0, stream, dm);

    hipLaunchKernelGGL(prqa_mfma_k, dim3(512), dim3(256), 0, stream,
                       predin, fc_hi, fc_lo, bfc, hd[(t + 1) & 1], qa_hi, qa_lo,
                       out + (size_t)t * V_, q);
  }
}

// Round 14
// 14244.092 us; speedup vs baseline: 3.2618x; 1.0491x over previous
//
#include <hip/hip_runtime.h>
#include <hip/hip_fp16.h>
#include <cstdint>
#include <cstddef>

#define B_  256
#define S_  96
#define T_  40
#define V_  256
#define E_  512
#define H_  1024
#define C_  128

typedef __attribute__((ext_vector_type(8))) short s8v;      // 8 bf16
typedef __attribute__((ext_vector_type(4))) float f4v;      // mfma acc
typedef _Float16 h8v __attribute__((ext_vector_type(8)));   // 8 fp16

__device__ __forceinline__ float sigmoidf_(float x) { return 1.0f / (1.0f + expf(-x)); }

__device__ __forceinline__ uint32_t cvtpk_bf16(float a, float b) {
  uint32_t r;
  asm("v_cvt_pk_bf16_f32 %0, %1, %2" : "=v"(r) : "v"(a), "v"(b));
  return r;
}

union U4 { uint32_t u[4]; s8v v; };

__device__ __forceinline__ void split8(const float4 a, const float4 b, s8v& hi, s8v& lo) {
  U4 H, L;
  H.u[0] = cvtpk_bf16(a.x, a.y);
  H.u[1] = cvtpk_bf16(a.z, a.w);
  H.u[2] = cvtpk_bf16(b.x, b.y);
  H.u[3] = cvtpk_bf16(b.z, b.w);
  const float r0 = a.x - __uint_as_float(H.u[0] << 16);
  const float r1 = a.y - __uint_as_float(H.u[0] & 0xffff0000u);
  const float r2 = a.z - __uint_as_float(H.u[1] << 16);
  const float r3 = a.w - __uint_as_float(H.u[1] & 0xffff0000u);
  const float r4 = b.x - __uint_as_float(H.u[2] << 16);
  const float r5 = b.y - __uint_as_float(H.u[2] & 0xffff0000u);
  const float r6 = b.z - __uint_as_float(H.u[3] << 16);
  const float r7 = b.w - __uint_as_float(H.u[3] & 0xffff0000u);
  L.u[0] = cvtpk_bf16(r0, r1);
  L.u[1] = cvtpk_bf16(r2, r3);
  L.u[2] = cvtpk_bf16(r4, r5);
  L.u[3] = cvtpk_bf16(r6, r7);
  hi = H.v; lo = L.v;
}

// =================== weight split kernels ===================
__global__ void wsplit_k(const float* __restrict__ Wf, const float* __restrict__ Wb,
                         short* __restrict__ hi, short* __restrict__ lo, int n)
{
  const int i = blockIdx.x * 256 + threadIdx.x;
  const float w = (i < n) ? Wf[i] : Wb[i - n];
  const uint32_t h = cvtpk_bf16(w, w) & 0xffffu;
  const float wh = __uint_as_float(h << 16);
  const uint32_t l = cvtpk_bf16(w - wh, w - wh) & 0xffffu;
  hi[i] = (short)h;
  lo[i] = (short)l;
}

__global__ void split_plane_k(const float* __restrict__ src, int ld_src, int col0,
                              short* __restrict__ hi, short* __restrict__ lo,
                              int ld_p, int pcol0, int total, int cols)
{
  const int i = blockIdx.x * 256 + threadIdx.x;
  if (i >= total) return;
  const int r = i / cols, c = i % cols;
  const float w = src[(size_t)r * ld_src + col0 + c];
  const uint32_t h = cvtpk_bf16(w, w) & 0xffffu;
  const float wh = __uint_as_float(h << 16);
  const uint32_t l = cvtpk_bf16(w - wh, w - wh) & 0xffffu;
  const size_t o = (size_t)r * ld_p + pcol0 + c;
  hi[o] = (short)h;
  lo[o] = (short)l;
}

// fp16 hi/lo split (for the fp16 MFMA proj)
__global__ void split_plane_h_k(const float* __restrict__ src, int ld_src, int col0,
                                __half* __restrict__ hi, __half* __restrict__ lo,
                                int ld_p, int total, int cols)
{
  const int i = blockIdx.x * 256 + threadIdx.x;
  if (i >= total) return;
  const int r = i / cols, c = i % cols;
  const float w = src[(size_t)r * ld_src + col0 + c];
  const __half h = __float2half(w);
  const __half l = __float2half(w - __half2float(h));
  const size_t o = (size_t)r * ld_p + c;
  hi[o] = h;
  lo[o] = l;
}

// =================== encoder step via MFMA bf16x3 (verified r12) ===================
struct EM {
  const int* gidx; int goff0, goff1;
  const float* Gt0; const float* Gt1;
  const float* h0; const float* h1; int ldh;
  const short* whi; const short* wlo;    // [2][3H][H]
  const float* bih0; const float* bih1;
  const float* bhh0; const float* bhh1;
  float* d0; float* d1;
  __half* e0; __half* e1; int lde;
};

__global__ __launch_bounds__(256)
void enc_mfma_k(EM g)
{
  const int fid = (blockIdx.x & 7) * 64 + (blockIdx.x >> 3);
  const int m0 = (fid & 3) * 64;
  const int r2 = fid >> 2;
  const int dir = r2 & 1;
  const int q0 = (r2 >> 1) * 16;

  __shared__ int rows[64];
  const int tid = threadIdx.x;
  if (tid < 64)
    rows[tid] = g.gidx[(size_t)(m0 + tid) * S_ + (dir ? g.goff1 : g.goff0)];
  __syncthreads();

  const int w = tid >> 6, lane = tid & 63;
  const int arow = m0 + 16 * w + (lane & 15);
  const int kc = (lane >> 4) << 3;
  const float* hsrc = dir ? g.h1 : g.h0;
  const short* whi = g.whi + (size_t)dir * (3u * H_ * H_);
  const short* wlo = g.wlo + (size_t)dir * (3u * H_ * H_);
  const float* ap = hsrc + (size_t)arow * g.ldh;
  const int wrow = q0 + (lane & 15);

  f4v acc[3];
  acc[0] = f4v{0.f, 0.f, 0.f, 0.f};
  acc[1] = f4v{0.f, 0.f, 0.f, 0.f};
  acc[2] = f4v{0.f, 0.f, 0.f, 0.f};

  float4 a0 = *(const float4*)(ap + kc);
  float4 a1 = *(const float4*)(ap + kc + 4);
  s8v bh[3], bl[3];
#pragma unroll
  for (int g3 = 0; g3 < 3; ++g3) {
    const size_t wb = (size_t)(g3 * H_ + wrow) * H_ + kc;
    bh[g3] = *(const s8v*)(whi + wb);
    bl[g3] = *(const s8v*)(wlo + wb);
  }

  for (int kb = 0; kb < 1024; kb += 32) {
    float4 na0, na1;
    s8v nbh[3], nbl[3];
    if (kb + 32 < 1024) {
      na0 = *(const float4*)(ap + kb + 32 + kc);
      na1 = *(const float4*)(ap + kb + 32 + kc + 4);
#pragma unroll
      for (int g3 = 0; g3 < 3; ++g3) {
        const size_t wb = (size_t)(g3 * H_ + wrow) * H_ + kb + 32 + kc;
        nbh[g3] = *(const s8v*)(whi + wb);
        nbl[g3] = *(const s8v*)(wlo + wb);
      }
    }
    s8v ah, al;
    split8(a0, a1, ah, al);
#pragma unroll
    for (int g3 = 0; g3 < 3; ++g3) {
      acc[g3] = __builtin_amdgcn_mfma_f32_16x16x32_bf16(ah, bh[g3], acc[g3], 0, 0, 0);
      acc[g3] = __builtin_amdgcn_mfma_f32_16x16x32_bf16(al, bh[g3], acc[g3], 0, 0, 0);
      acc[g3] = __builtin_amdgcn_mfma_f32_16x16x32_bf16(ah, bl[g3], acc[g3], 0, 0, 0);
    }
    a0 = na0; a1 = na1;
#pragma unroll
    for (int g3 = 0; g3 < 3; ++g3) { bh[g3] = nbh[g3]; bl[g3] = nbl[g3]; }
  }

  const float* bih = dir ? g.bih1 : g.bih0;
  const float* bhh = dir ? g.bhh1 : g.bhh0;
  const float* Gt = dir ? g.Gt1 : g.Gt0;
  float* dst = dir ? g.d1 : g.d0;
  __half* edst = dir ? g.e1 : g.e0;
  const int col = q0 + (lane & 15);
  const float bir = bih[col], biz = bih[H_ + col], bin = bih[2 * H_ + col];
  const float bhr = bhh[col], bhz = bhh[H_ + col], bhn = bhh[2 * H_ + col];
#pragma unroll
  for (int r = 0; r < 4; ++r) {
    const int b = m0 + 16 * w + (lane >> 4) * 4 + r;
    const float* Gr = Gt + (size_t)rows[b - m0] * (3 * H_);
    const float hold = hsrc[(size_t)b * g.ldh + col];
    const float rr = sigmoidf_(acc[0][r] + Gr[col] + bir + bhr);
    const float zz = sigmoidf_(acc[1][r] + Gr[H_ + col] + biz + bhz);
    const float nn = tanhf(Gr[2 * H_ + col] + bin + rr * (acc[2][r] + bhn));
    const float hv = (1.f - zz) * nn + zz * hold;
    dst[(size_t)b * H_ + col] = hv;
    edst[(size_t)b * g.lde + col] = __float2half(hv);
  }
}

// =================== decoder step: 12-wave MFMA, LDS-staged A ===================
// Block: 768 thr = 12 waves = 4 m-groups x 3 gates. A[64][3072] staged once
// (pre-split bf16 hi/lo, double-buffered). Accumulation order identical to r13.
struct DM {
  const float* predin;                   // ctx at row*3584 + 1024
  const float* h;
  const int* tok;
  const float* Gd;
  const short* whi; const short* wlo;    // [3H][3072]
  const float* bih; const float* bhh;
  float* d;
  float* predout;
};

__global__ __launch_bounds__(768)
void dec_mfma_k(DM g)
{
  const int fid = (blockIdx.x & 7) * 32 + (blockIdx.x >> 3);
  const int m0 = (fid & 3) * 64;
  const int q0 = (fid >> 2) * 16;
  const int tid = threadIdx.x;
  const int w = tid >> 6, lane = tid & 63;
  const int mg = w & 3;          // m-group
  const int gate = w >> 2;       // 0=r 1=z 2=n

  __shared__ short sA[2][2][64][40];     // [buf][hi/lo][row][k], pad 40 -> 2-way max
  __shared__ float eacc[4][64][16];      // r,z,nI,nH partials for epilogue

  // staging role: threads 0..255 (the 4 gate-0 waves; one per SIMD)
  const int srow = tid >> 2;
  const int skq = (tid & 3) << 3;
  const float* actx = g.predin + (size_t)(m0 + srow) * 3584 + 1024;
  const float* ahid = g.h + (size_t)(m0 + srow) * H_;
  auto loadA8 = [&](int kk, float4& x0, float4& x1) {
    const float* p = (kk < 2048) ? (actx + kk) : (ahid + kk - 2048);
    x0 = *(const float4*)p;
    x1 = *(const float4*)(p + 4);
  };

  const int kc = (lane >> 4) << 3;
  const int wrow = gate * H_ + q0 + (lane & 15);
  const short* whp = g.whi + (size_t)wrow * 3072 + kc;
  const short* wlp = g.wlo + (size_t)wrow * 3072 + kc;

  f4v acc0 = f4v{0.f, 0.f, 0.f, 0.f};   // r / z / nI
  f4v acc1 = acc0;                       // nH (gate 2 only)

  // prologue: stage chunk 0
  float4 sx0, sx1;
  if (tid < 256) loadA8(skq, sx0, sx1);
  s8v bh = *(const s8v*)whp;
  s8v bl = *(const s8v*)wlp;
  if (tid < 256) {
    s8v ah, al;
    split8(sx0, sx1, ah, al);
    *(s8v*)&sA[0][0][srow][skq] = ah;
    *(s8v*)&sA[0][1][srow][skq] = al;
  }
  __syncthreads();

  const int arowl = mg * 16 + (lane & 15);
  for (int ch = 0; ch < 96; ++ch) {
    const int buf = ch & 1;
    // issue next-chunk loads
    float4 nx0, nx1;
    if (tid < 256 && ch + 1 < 96) loadA8((ch + 1) * 32 + skq, nx0, nx1);
    s8v nbh, nbl;
    if (ch + 1 < 96) {
      nbh = *(const s8v*)(whp + (ch + 1) * 32);
      nbl = *(const s8v*)(wlp + (ch + 1) * 32);
    }
    // fragments from LDS
    const s8v ah = *(const s8v*)&sA[buf][0][arowl][kc];
    const s8v al = *(const s8v*)&sA[buf][1][arowl][kc];
    if (gate < 2) {
      acc0 = __builtin_amdgcn_mfma_f32_16x16x32_bf16(ah, bh, acc0, 0, 0, 0);
      acc0 = __builtin_amdgcn_mfma_f32_16x16x32_bf16(al, bh, acc0, 0, 0, 0);
      acc0 = __builtin_amdgcn_mfma_f32_16x16x32_bf16(ah, bl, acc0, 0, 0, 0);
    } else if (ch < 64) {
      acc0 = __builtin_amdgcn_mfma_f32_16x16x32_bf16(ah, bh, acc0, 0, 0, 0);
      acc0 = __builtin_amdgcn_mfma_f32_16x16x32_bf16(al, bh, acc0, 0, 0, 0);
      acc0 = __builtin_amdgcn_mfma_f32_16x16x32_bf16(ah, bl, acc0, 0, 0, 0);
    } else {
      acc1 = __builtin_amdgcn_mfma_f32_16x16x32_bf16(ah, bh, acc1, 0, 0, 0);
      acc1 = __builtin_amdgcn_mfma_f32_16x16x32_bf16(al, bh, acc1, 0, 0, 0);
      acc1 = __builtin_amdgcn_mfma_f32_16x16x32_bf16(ah, bl, acc1, 0, 0, 0);
    }
    // stage next into other buffer
    if (tid < 256 && ch + 1 < 96) {
      s8v ah2, al2;
      split8(nx0, nx1, ah2, al2);
      *(s8v*)&sA[buf ^ 1][0][srow][skq] = ah2;
      *(s8v*)&sA[buf ^ 1][1][srow][skq] = al2;
    }
    bh = nbh; bl = nbl;
    __syncthreads();
  }

  // partials -> LDS
#pragma unroll
  for (int r = 0; r < 4; ++r) {
    const int lr = mg * 16 + (lane >> 4) * 4 + r;
    if (gate < 2) {
      eacc[gate][lr][lane & 15] = acc0[r];
    } else {
      eacc[2][lr][lane & 15] = acc0[r];
      eacc[3][lr][lane & 15] = acc1[r];
    }
  }
  __syncthreads();

  // gate epilogue: 1024 outputs over 768 threads
  for (int o = tid; o < 1024; o += 768) {
    const int lr = o >> 4, lc = o & 15;
    const int b = m0 + lr, col = q0 + lc;
    const float* Gr = g.Gd + (size_t)g.tok[b] * (3 * H_);
    const float hold = g.h[(size_t)b * H_ + col];
    const float rr = sigmoidf_(eacc[0][lr][lc] + Gr[col] + g.bih[col] + g.bhh[col]);
    const float zz = sigmoidf_(eacc[1][lr][lc] + Gr[H_ + col] + g.bih[H_ + col] + g.bhh[H_ + col]);
    const float nn = tanhf(eacc[2][lr][lc] + Gr[2 * H_ + col] + g.bih[2 * H_ + col]
                           + rr * (eacc[3][lr][lc] + g.bhh[2 * H_ + col]));
    const float hv = (1.f - zz) * nn + zz * hold;
    g.d[(size_t)b * H_ + col] = hv;
    g.predout[(size_t)b * 3584 + col] = hv;
  }
}

// =================== enc_proj via fp16-split MFMA ===================
// 6144 blocks x 4 waves; wave = 1 m-tile x 4 n-tiles, K=2048.
__global__ __launch_bounds__(256)
void proj_mfma_k(const __half* __restrict__ enc, const __half* __restrict__ whi,
                 const __half* __restrict__ wlo, __half* __restrict__ proj)
{
  const int fid = (blockIdx.x & 7) * 768 + (blockIdx.x >> 3);
  const int w = threadIdx.x >> 6, lane = threadIdx.x & 63;
  const int wg = fid * 4 + w;
  const int ng = wg / 1536;            // n-group (0..15) -> n0 = ng*64
  const int mt = wg % 1536;            // m-tile (16 rows of B_*S_)
  const int n0 = ng * 64;
  const int kc = (lane >> 4) << 3;
  const __half* ap = enc + (size_t)(mt * 16 + (lane & 15)) * 2048 + kc;
  const __half* bhp = whi + (size_t)(n0 + (lane & 15)) * 2048 + kc;
  const __half* blp = wlo + (size_t)(n0 + (lane & 15)) * 2048 + kc;

  f4v acc[4];
#pragma unroll
  for (int j = 0; j < 4; ++j) acc[j] = f4v{0.f, 0.f, 0.f, 0.f};

  h8v a = *(const h8v*)ap;
  h8v bh[4], bl[4];
#pragma unroll
  for (int j = 0; j < 4; ++j) {
    bh[j] = *(const h8v*)(bhp + (size_t)j * 16 * 2048);
    bl[j] = *(const h8v*)(blp + (size_t)j * 16 * 2048);
  }

  for (int kb = 0; kb < 2048; kb += 32) {
    h8v na, nbh[4], nbl[4];
    if (kb + 32 < 2048) {
      na = *(const h8v*)(ap + kb + 32);
#pragma unroll
      for (int j = 0; j < 4; ++j) {
        nbh[j] = *(const h8v*)(bhp + (size_t)j * 16 * 2048 + kb + 32);
        nbl[j] = *(const h8v*)(blp + (size_t)j * 16 * 2048 + kb + 32);
      }
    }
#pragma unroll
    for (int j = 0; j < 4; ++j) {
      acc[j] = __builtin_amdgcn_mfma_f32_16x16x32_f16(a, bh[j], acc[j], 0, 0, 0);
      acc[j] = __builtin_amdgcn_mfma_f32_16x16x32_f16(a, bl[j], acc[j], 0, 0, 0);
    }
    a = na;
#pragma unroll
    for (int j = 0; j < 4; ++j) { bh[j] = nbh[j]; bl[j] = nbl[j]; }
  }

#pragma unroll
  for (int j = 0; j < 4; ++j)
#pragma unroll
    for (int r = 0; r < 4; ++r) {
      const int row = mt * 16 + (lane >> 4) * 4 + r;
      proj[(size_t)row * H_ + n0 + j * 16 + (lane & 15)] = __float2half(acc[j][r]);
    }
}

// =================== fused pred + q via MFMA (512 blocks) ===================
__global__ __launch_bounds__(256)
void prqa_mfma_k(const float* __restrict__ predin,
                 const short* __restrict__ fhi, const short* __restrict__ flo,
                 const float* __restrict__ bfc,
                 const float* __restrict__ hnew,
                 const short* __restrict__ qhi, const short* __restrict__ qlo,
                 float* __restrict__ out_t, float* __restrict__ qout)
{
  const int bid = blockIdx.x, tid = threadIdx.x;
  const int w = tid >> 6, lane = tid & 63;
  const int kc = (lane >> 4) << 3;
  if (bid < 256) {
    const int m0 = (bid >> 4) << 4, n0 = (bid & 15) << 4;
    const float* ap = predin + (size_t)(m0 + (lane & 15)) * 3584 + w * 896;
    const short* bhp = fhi + (size_t)(n0 + (lane & 15)) * 3584 + w * 896;
    const short* blp = flo + (size_t)(n0 + (lane & 15)) * 3584 + w * 896;
    f4v acc = f4v{0.f, 0.f, 0.f, 0.f};
    float4 a0 = *(const float4*)(ap + kc), a1 = *(const float4*)(ap + kc + 4);
    s8v bh = *(const s8v*)(bhp + kc), bl = *(const s8v*)(blp + kc);
    for (int kb = 0; kb < 896; kb += 32) {
      float4 na0, na1; s8v nbh, nbl;
      if (kb + 32 < 896) {
        na0 = *(const float4*)(ap + kb + 32 + kc);
        na1 = *(const float4*)(ap + kb + 32 + kc + 4);
        nbh = *(const s8v*)(bhp + kb + 32 + kc);
        nbl = *(const s8v*)(blp + kb + 32 + kc);
      }
      s8v ah, al;
      split8(a0, a1, ah, al);
      acc = __builtin_amdgcn_mfma_f32_16x16x32_bf16(ah, bh, acc, 0, 0, 0);
      acc = __builtin_amdgcn_mfma_f32_16x16x32_bf16(al, bh, acc, 0, 0, 0);
      acc = __builtin_amdgcn_mfma_f32_16x16x32_bf16(ah, bl, acc, 0, 0, 0);
      a0 = na0; a1 = na1; bh = nbh; bl = nbl;
    }
    __shared__ float red[4][64][4];
#pragma unroll
    for (int r = 0; r < 4; ++r) red[w][lane][r] = acc[r];
    __syncthreads();
    const int row = tid >> 4, col = tid & 15;
    const int sl = col + ((row >> 2) << 4), reg = row & 3;
    const float s = red[0][sl][reg] + red[1][sl][reg] + red[2][sl][reg] + red[3][sl][reg];
    out_t[(size_t)(m0 + row) * ((T_ - 1) * V_) + n0 + col] = s + bfc[n0 + col];
  } else {
    const int tt = (bid - 256) * 4 + w;
    const int m0 = (tt >> 6) << 4, n0 = (tt & 63) << 4;
    const float* ap = hnew + (size_t)(m0 + (lane & 15)) * H_;
    const short* bhp = qhi + (size_t)(n0 + (lane & 15)) * H_;
    const short* blp = qlo + (size_t)(n0 + (lane & 15)) * H_;
    f4v acc = f4v{0.f, 0.f, 0.f, 0.f};
    float4 a0 = *(const float4*)(ap + kc), a1 = *(const float4*)(ap + kc + 4);
    s8v bh = *(const s8v*)(bhp + kc), bl = *(const s8v*)(blp + kc);
    for (int kb = 0; kb < 1024; kb += 32) {
      float4 na0, na1; s8v nbh, nbl;
      if (kb + 32 < 1024) {
        na0 = *(const float4*)(ap + kb + 32 + kc);
        na1 = *(const float4*)(ap + kb + 32 + kc + 4);
        nbh = *(const s8v*)(bhp + kb + 32 + kc);
        nbl = *(const s8v*)(blp + kb + 32 + kc);
      }
      s8v ah, al;
      split8(a0, a1, ah, al);
      acc = __builtin_amdgcn_mfma_f32_16x16x32_bf16(ah, bh, acc, 0, 0, 0);
      acc = __builtin_amdgcn_mfma_f32_16x16x32_bf16(al, bh, acc, 0, 0, 0);
      acc = __builtin_amdgcn_mfma_f32_16x16x32_bf16(ah, bl, acc, 0, 0, 0);
      a0 = na0; a1 = na1; bh = nbh; bl = nbl;
    }
#pragma unroll
    for (int r = 0; r < 4; ++r)
      qout[(size_t)(m0 + (lane >> 4) * 4 + r) * H_ + n0 + (lane & 15)] = acc[r];
  }
}

// =================== attn part 1: argmax + emb + scores + softmax ===================
__global__ __launch_bounds__(512)
void attn1_k(const float* __restrict__ out, const int* __restrict__ tgt,
             const float* __restrict__ q, const __half* __restrict__ proj,
             const float* __restrict__ va, const int* __restrict__ src,
             const float* __restrict__ dec_emb,
             float* __restrict__ predin, float* __restrict__ wts,
             int* __restrict__ tokbuf, int t)
{
  const int b = blockIdx.x, tid = threadIdx.x;
  const int lane = tid & 63, wv = tid >> 6;
  __shared__ float sm[128];
  __shared__ float tr[128];
  __shared__ float rv[4];
  __shared__ int ri[4];
  __shared__ int tok_s;
  if (t == 0) {
    if (tid == 0) tok_s = tgt[(size_t)b * T_];
  } else {
    if (tid < 256) {
      float av = out[((size_t)b * (T_ - 1) + (t - 1)) * V_ + tid];
      int ai = tid;
      for (int off = 32; off; off >>= 1) {
        const float ov = __shfl_down(av, off);
        const int   oi = __shfl_down(ai, off);
        if (ov > av) { av = ov; ai = oi; }
      }
      if (lane == 0) { rv[wv] = av; ri[wv] = ai; }
    }
    __syncthreads();
    if (tid == 0) {
      float bv = rv[0]; int bi = ri[0];
      for (int w2 = 1; w2 < 4; ++w2) if (rv[w2] > bv) { bv = rv[w2]; bi = ri[w2]; }
      tok_s = bi;
    }
  }
  __syncthreads();
  const int tok = tok_s;
  if (tid == 0) tokbuf[b] = tok;
  predin[(size_t)b * 3584 + 3072 + tid] = dec_emb[(size_t)tok * E_ + tid];
  const float* qb = q + (size_t)b * H_;
  for (int s = wv * 12; s < wv * 12 + 12; ++s) {
    const __half* pb = proj + ((size_t)b * S_ + s) * H_;
    float part = 0.f;
#pragma unroll
    for (int j = 0; j < 8; ++j) {
      const int h = lane * 2 + j * 128;
      const __half2 p2 = *(const __half2*)(pb + h);
      const float2 q2 = *(const float2*)(qb + h);
      const float2 v2 = *(const float2*)(va + h);
      part += v2.x * tanhf(q2.x + __half2float(p2.x));
      part += v2.y * tanhf(q2.y + __half2float(p2.y));
    }
    for (int off = 32; off; off >>= 1) part += __shfl_down(part, off);
    if (lane == 0)
      sm[s] = (src[(size_t)b * S_ + s] == 0) ? -1.0e9f : part;
  }
  __syncthreads();
  if (tid < 128) tr[tid] = (tid < S_) ? sm[tid] : -3.0e38f;
  __syncthreads();
  for (int s2 = 64; s2 > 0; s2 >>= 1) { if (tid < s2) tr[tid] = fmaxf(tr[tid], tr[tid + s2]); __syncthreads(); }
  const float mx = tr[0];
  __syncthreads();
  if (tid < 128) tr[tid] = (tid < S_) ? expf(sm[tid] - mx) : 0.f;
  __syncthreads();
  for (int s2 = 64; s2 > 0; s2 >>= 1) { if (tid < s2) tr[tid] += tr[tid + s2]; __syncthreads(); }
  const float inv = 1.0f / tr[0];
  __syncthreads();
  if (tid < S_) wts[(size_t)b * S_ + tid] = expf(sm[tid] - mx) * inv;
}

// =================== attn part 2: ctx ===================
__global__ __launch_bounds__(256)
void ctx_k(const float* __restrict__ wts, const __half* __restrict__ enc,
           float* __restrict__ predin)
{
  const int b = blockIdx.y, tid = threadIdx.x;
  __shared__ float sw[S_];
  if (tid < S_) sw[tid] = wts[(size_t)b * S_ + tid];
  __syncthreads();
  const int d = blockIdx.x * 512 + tid * 2;
  const __half* eb = enc + (size_t)b * S_ * (2 * H_) + d;
  float c0 = 0.f, c1 = 0.f;
  for (int s0 = 0; s0 < S_; s0 += 8) {
    __half2 v[8];
#pragma unroll
    for (int i = 0; i < 8; ++i) v[i] = *(const __half2*)(eb + (size_t)(s0 + i) * (2 * H_));
#pragma unroll
    for (int i = 0; i < 8; ++i) {
      const float w = sw[s0 + i];
      c0 += w * __half2float(v[i].x);
      c1 += w * __half2float(v[i].y);
    }
  }
  *(float2*)(predin + (size_t)b * 3584 + H_ + d) = make_float2(c0, c1);
}

// =================== generic fp32 tiled GEMM (tables / br / q0) ==============
struct GB {
  const float* A; int lda;
  const __half* Ah;
  const float* W; int ldw;
  const float* bias;
  float* C; int ldc;
  __half* Ch;
  int M, N, K, act;
  const float *hf, *hb; int ldh;
  const float *mE, *tE, *pE;
  const int *mi, *ti, *pi;
};

template<int AMODE, int CMODE>
__global__ __launch_bounds__(256)
void gemm_k(GB g0, GB g1)
{
  GB g = blockIdx.z ? g1 : g0;
  const int m0 = blockIdx.y * 64, n0 = blockIdx.x * 64;
  if (m0 >= g.M || n0 >= g.N) return;
  __shared__ float As[32][68];
  __shared__ float Ws[32][68];
  const int tid = threadIdx.x, tx = tid & 15, ty = tid >> 4;
  const int lm = tid >> 3, lk = (tid & 7) << 2;
  float acc[4][4] = {};
  float4 av[2], wv[2], av2[2], wv2[2];

  auto load_tile = [&](int k0, float4 (&AV)[2], float4 (&WV)[2]) {
#pragma unroll
    for (int i = 0; i < 2; ++i) {
      const int row = lm + i * 32;
      const int kk = k0 + lk;
      if (AMODE == 0) {
        AV[i] = *(const float4*)(g.A + (size_t)(m0 + row) * g.lda + kk);
      } else if (AMODE == 4) {
        const __half* ap = g.Ah + (size_t)(m0 + row) * g.lda + kk;
        const __half2 h0 = *(const __half2*)ap;
        const __half2 h1 = *(const __half2*)(ap + 2);
        AV[i] = make_float4(__half2float(h0.x), __half2float(h0.y),
                            __half2float(h1.x), __half2float(h1.y));
      } else {
        const int mg = m0 + row; const float* sp; size_t o;
        if (kk < 1024)      { sp = g.hf; o = (size_t)mg * g.ldh + kk; }
        else if (kk < 2048) { sp = g.hb; o = (size_t)mg * g.ldh + kk - 1024; }
        else if (kk < 2176) { sp = g.mE; o = (size_t)g.mi[mg] * C_ + kk - 2048; }
        else if (kk < 2304) { sp = g.tE; o = (size_t)g.ti[mg] * C_ + kk - 2176; }
        else                { sp = g.pE; o = (size_t)g.pi[mg] * C_ + kk - 2304; }
        AV[i] = *(const float4*)(sp + o);
      }
      WV[i] = *(const float4*)(g.W + (size_t)(n0 + row) * g.ldw + kk);
    }
  };

  load_tile(0, av, wv);
  for (int k0 = 0; k0 < g.K; k0 += 32) {
    __syncthreads();
#pragma unroll
    for (int i = 0; i < 2; ++i) {
      const int row = lm + i * 32;
      As[lk + 0][row] = av[i].x; As[lk + 1][row] = av[i].y;
      As[lk + 2][row] = av[i].z; As[lk + 3][row] = av[i].w;
      Ws[lk + 0][row] = wv[i].x; Ws[lk + 1][row] = wv[i].y;
      Ws[lk + 2][row] = wv[i].z; Ws[lk + 3][row] = wv[i].w;
    }
    __syncthreads();
    if (k0 + 32 < g.K) load_tile(k0 + 32, av2, wv2);
#pragma unroll
    for (int k = 0; k < 32; ++k) {
      const float4 a4 = *(const float4*)&As[k][ty << 2];
      const float4 b4 = *(const float4*)&Ws[k][tx << 2];
      acc[0][0] += a4.x * b4.x; acc[0][1] += a4.x * b4.y; acc[0][2] += a4.x * b4.z; acc[0][3] += a4.x * b4.w;
      acc[1][0] += a4.y * b4.x; acc[1][1] += a4.y * b4.y; acc[1][2] += a4.y * b4.z; acc[1][3] += a4.y * b4.w;
      acc[2][0] += a4.z * b4.x; acc[2][1] += a4.z * b4.y; acc[2][2] += a4.z * b4.z; acc[2][3] += a4.z * b4.w;
      acc[3][0] += a4.w * b4.x; acc[3][1] += a4.w * b4.y; acc[3][2] += a4.w * b4.z; acc[3][3] += a4.w * b4.w;
    }
#pragma unroll
    for (int i = 0; i < 2; ++i) { av[i] = av2[i]; wv[i] = wv2[i]; }
  }
  const int n = n0 + (tx << 2);
  float4 bb = make_float4(0.f, 0.f, 0.f, 0.f);
  if (g.bias) bb = *(const float4*)(g.bias + n);
#pragma unroll
  for (int i = 0; i < 4; ++i) {
    const int m = m0 + (ty << 2) + i;
    float4 v = make_float4(acc[i][0] + bb.x, acc[i][1] + bb.y, acc[i][2] + bb.z, acc[i][3] + bb.w);
    if (CMODE == 0) {
      if (g.act) { v.x = tanhf(v.x); v.y = tanhf(v.y); v.z = tanhf(v.z); v.w = tanhf(v.w); }
      *(float4*)(g.C + (size_t)m * g.ldc + n) = v;
    } else {
      __half2* cp = (__half2*)(g.Ch + (size_t)m * g.ldc + n);
      cp[0] = __floats2half2_rn(v.x, v.y);
      cp[1] = __floats2half2_rn(v.z, v.w);
    }
  }
}

// =================== misc ===================
__global__ void zero_k(float* __restrict__ p, int n)
{
  const int i = blockIdx.x * 256 + threadIdx.x;
  if (i < n) p[i] = 0.0f;
}

__global__ void sentinel_k(float* out, float v) { out[threadIdx.x] = v; }

// =================== host orchestration ===================
extern "C" void kernel_launch(void* const* d_in, const int* in_sizes, int n_in,
                              void* d_out, int out_size, void* d_ws, size_t ws_size,
                              hipStream_t stream)
{
  const int*   src        = (const int*)d_in[0];
  const int*   tgt        = (const int*)d_in[1];
  const int*   mode_idx   = (const int*)d_in[2];
  const int*   tense_idx  = (const int*)d_in[3];
  const int*   person_idx = (const int*)d_in[4];
  const float* enc_emb    = (const float*)d_in[5];
  const float* eWih_f     = (const float*)d_in[6];
  const float* eWhh_f     = (const float*)d_in[7];
  const float* ebih_f     = (const float*)d_in[8];
  const float* ebhh_f     = (const float*)d_in[9];
  const float* eWih_b     = (const float*)d_in[10];
  const float* eWhh_b     = (const float*)d_in[11];
  const float* ebih_b     = (const float*)d_in[12];
  const float* ebhh_b     = (const float*)d_in[13];
  const float* Wa         = (const float*)d_in[14];
  const float* va         = (const float*)d_in[15];
  const float* dec_emb    = (const float*)d_in[16];
  const float* dWih       = (const float*)d_in[17];
  const float* dWhh       = (const float*)d_in[18];
  const float* dbih       = (const float*)d_in[19];
  const float* dbhh       = (const float*)d_in[20];
  const float* Wfc        = (const float*)d_in[21];
  const float* bfc        = (const float*)d_in[22];
  const float* mode_E     = (const float*)d_in[23];
  const float* tense_E    = (const float*)d_in[24];
  const float* person_E   = (const float*)d_in[25];
  const float* Wbr        = (const float*)d_in[26];
  const float* bbr        = (const float*)d_in[27];
  float* out = (float*)d_out;

  // ---- workspace carve (~251 MB; proven >= 268 MB) ----
  char* base = (char*)d_ws;
  size_t off = 0;
  auto alloc = [&](size_t bytes) { char* r = base + off; off = (off + bytes + 255) & ~(size_t)255; return r; };
  __half* enc_out = (__half*)alloc(2ull * B_ * S_ * 2 * H_);   // 100.7 MB
  __half* proj    = (__half*)alloc(2ull * B_ * S_ * H_);       // 50.3 MB
  short* whh_hi = (short*)alloc(2ull * 2 * 3 * H_ * H_);       // 12.6 MB
  short* whh_lo = (short*)alloc(2ull * 2 * 3 * H_ * H_);
  short* dpl_hi = (short*)alloc(2ull * 3 * H_ * 3072);         // 18.9 MB
  short* dpl_lo = (short*)alloc(2ull * 3 * H_ * 3072);
  short* fc_hi  = (short*)alloc(2ull * V_ * 3584);             // 1.8 MB
  short* fc_lo  = (short*)alloc(2ull * V_ * 3584);
  short* qa_hi  = (short*)alloc(2ull * H_ * H_);               // 2.1 MB
  short* qa_lo  = (short*)alloc(2ull * H_ * H_);
  __half* wae_hi = (__half*)alloc(2ull * H_ * 2048);           // 4.2 MB
  __half* wae_lo = (__half*)alloc(2ull * H_ * 2048);
  float* Gi_f  = (float*)alloc(4ull * V_ * 3 * H_);
  float* Gi_b  = (float*)alloc(4ull * V_ * 3 * H_);
  float* Gd    = (float*)alloc(4ull * V_ * 3 * H_);
  float* hfA   = (float*)alloc(4ull * B_ * H_);
  float* hfB   = (float*)alloc(4ull * B_ * H_);
  float* hbA   = (float*)alloc(4ull * B_ * H_);
  float* hbB   = (float*)alloc(4ull * B_ * H_);
  float* h_d0  = (float*)alloc(4ull * B_ * H_);
  float* h_d1  = (float*)alloc(4ull * B_ * H_);
  float* q     = (float*)alloc(4ull * B_ * H_);
  float* predin = (float*)alloc(4ull * B_ * 3584);
  float* wts   = (float*)alloc(4ull * B_ * S_);
  int*   tok   = (int*)alloc(4ull * B_);
  float* zero_buf = (float*)alloc(4ull * 1024);
  if (off > ws_size) {
    hipLaunchKernelGGL(sentinel_k, dim3(1), dim3(256), 0, stream, out,
                       1000.0f + (float)(ws_size >> 20));
    return;
  }

  hipLaunchKernelGGL(zero_k, dim3(4), dim3(256), 0, stream, zero_buf, 1024);

  // ---- weight splits ----
  {
    const int n = 3 * H_ * H_;
    hipLaunchKernelGGL(wsplit_k, dim3((2 * n) / 256), dim3(256), 0, stream,
                       eWhh_f, eWhh_b, whh_hi, whh_lo, n);
    int tot = 3 * H_ * 2048;
    hipLaunchKernelGGL(split_plane_k, dim3((tot + 255) / 256), dim3(256), 0, stream,
                       dWih, 2560, 512, dpl_hi, dpl_lo, 3072, 0, tot, 2048);
    tot = 3 * H_ * 1024;
    hipLaunchKernelGGL(split_plane_k, dim3((tot + 255) / 256), dim3(256), 0, stream,
                       dWhh, 1024, 0, dpl_hi, dpl_lo, 3072, 2048, tot, 1024);
    tot = V_ * 3584;
    hipLaunchKernelGGL(split_plane_k, dim3((tot + 255) / 256), dim3(256), 0, stream,
                       Wfc, 3584, 0, fc_hi, fc_lo, 3584, 0, tot, 3584);
    tot = H_ * 1024;
    hipLaunchKernelGGL(split_plane_k, dim3((tot + 255) / 256), dim3(256), 0, stream,
                       Wa, 3 * H_, 0, qa_hi, qa_lo, 1024, 0, tot, 1024);
    tot = H_ * 2048;
    hipLaunchKernelGGL(split_plane_h_k, dim3((tot + 255) / 256), dim3(256), 0, stream,
                       Wa, 3 * H_, 1024, wae_hi, wae_lo, 2048, tot, 2048);
  }

  GB Z{};

  // ---- token tables ----
  {
    GB t0 = Z, t1 = Z;
    t0.A = enc_emb; t0.lda = E_; t0.W = eWih_f; t0.ldw = E_;
    t0.C = Gi_f; t0.ldc = 3 * H_; t0.M = V_; t0.N = 3 * H_; t0.K = E_;
    t1 = t0; t1.W = eWih_b; t1.C = Gi_b;
    hipLaunchKernelGGL((gemm_k<0, 0>), dim3(48, 4, 2), dim3(256), 0, stream, t0, t1);
    GB t2 = Z;
    t2.A = dec_emb; t2.lda = E_; t2.W = dWih; t2.ldw = 2560;
    t2.C = Gd; t2.ldc = 3 * H_; t2.M = V_; t2.N = 3 * H_; t2.K = E_;
    hipLaunchKernelGGL((gemm_k<0, 0>), dim3(48, 4, 1), dim3(256), 0, stream, t2, t2);
  }

  // ---- encoder: 96 MFMA steps ----
  for (int t = 0; t < S_; ++t) {
    EM em{};
    em.gidx = src; em.goff0 = t; em.goff1 = S_ - 1 - t;
    em.Gt0 = Gi_f; em.Gt1 = Gi_b;
    if (t == 0) { em.h0 = zero_buf; em.h1 = zero_buf; em.ldh = 0; }
    else if (t & 1) { em.h0 = hfA; em.h1 = hbA; em.ldh = H_; }
    else            { em.h0 = hfB; em.h1 = hbB; em.ldh = H_; }
    em.whi = whh_hi; em.wlo = whh_lo;
    em.bih0 = ebih_f; em.bih1 = ebih_b; em.bhh0 = ebhh_f; em.bhh1 = ebhh_b;
    if (t & 1) { em.d0 = hfB; em.d1 = hbB; } else { em.d0 = hfA; em.d1 = hbA; }
    em.e0 = enc_out + (size_t)t * 2 * H_;
    em.e1 = enc_out + (size_t)(S_ - 1 - t) * 2 * H_ + H_;
    em.lde = S_ * 2 * H_;
    hipLaunchKernelGGL(enc_mfma_k, dim3(512), dim3(256), 0, stream, em);
  }
  float* hf_fin = hfB;   // t=95 (odd) wrote hfB/hbB
  float* hb_fin = hbB;

  // ---- enc_proj via fp16 MFMA ----
  hipLaunchKernelGGL(proj_mfma_k, dim3(6144), dim3(256), 0, stream,
                     enc_out, wae_hi, wae_lo, proj);

  // ---- dec_h0 ----
  {
    GB br = Z;
    br.W = Wbr; br.ldw = 2432; br.bias = bbr; br.C = h_d0; br.ldc = H_;
    br.M = B_; br.N = H_; br.K = 2432; br.act = 1;
    br.hf = hf_fin; br.hb = hb_fin; br.ldh = H_;
    br.mE = mode_E; br.tE = tense_E; br.pE = person_E;
    br.mi = mode_idx; br.ti = tense_idx; br.pi = person_idx;
    hipLaunchKernelGGL((gemm_k<2, 0>), dim3(16, 4, 1), dim3(256), 0, stream, br, br);
  }

  // ---- q(0) ----
  {
    GB qa = Z;
    qa.A = h_d0; qa.lda = H_; qa.W = Wa; qa.ldw = 3 * H_; qa.C = q; qa.ldc = H_;
    qa.M = B_; qa.N = H_; qa.K = H_;
    hipLaunchKernelGGL((gemm_k<0, 0>), dim3(16, 4, 1), dim3(256), 0, stream, qa, qa);
  }

  // ---- decoder: 39 steps x (attn1, ctx, dec_mfma[12-wave], prqa_mfma) ----
  float* hd[2] = { h_d0, h_d1 };
  for (int t = 0; t < T_ - 1; ++t) {
    hipLaunchKernelGGL(attn1_k, dim3(B_), dim3(512), 0, stream,
                       out, tgt, q, proj, va, src, dec_emb, predin, wts, tok, t);
    hipLaunchKernelGGL(ctx_k, dim3(4, B_), dim3(256), 0, stream, wts, enc_out, predin);

    DM dm{};
    dm.predin = predin;
    dm.h = hd[t & 1];
    dm.tok = tok; dm.Gd = Gd;
    dm.whi = dpl_hi; dm.wlo = dpl_lo;
    dm.bih = dbih; dm.bhh = dbhh;
    dm.d = hd[(t + 1) & 1];
    dm.predout = predin;
    hipLaunchKernelGGL(dec_mfma_k, dim3(256), dim3(768), 0, stream, dm);

    hipLaunchKernelGGL(prqa_mfma_k, dim3(512), dim3(256), 0, stream,
                       predin, fc_hi, fc_lo, bfc, hd[(t + 1) & 1], qa_hi, qa_lo,
                       out + (size_t)t * V_, q);
  }
}